// Round 2
// baseline (312.455 us; speedup 1.0000x reference)
//
#include <hip/hip_runtime.h>

#define N_NODES 100000
#define NBUCK   782      // ceil(100000/128) buckets of 128 nodes
#define P1TILE  8192     // edges per phase-1 block
#define MAXB    4096     // phase-2 LDS capacity (avg bucket = 2048 edges)

typedef __bf16 bf16x8 __attribute__((ext_vector_type(8)));
typedef float floatx4 __attribute__((ext_vector_type(4)));
typedef float floatx2 __attribute__((ext_vector_type(2)));

static __device__ __forceinline__ unsigned short f2bf(float f) {
  unsigned u = __float_as_uint(f);
  u += 0x7fff + ((u >> 16) & 1);   // round-to-nearest-even
  return (unsigned short)(u >> 16);
}

// ===========================================================================
// Step 1: bucket-level edge counts (LDS histogram; ~200k global atomics on
// 3 KB instead of 1.6M on 400 KB -> no scattered-line write amplification).
// ===========================================================================
__global__ __launch_bounds__(256) void bucket_count_kernel(
    const int* __restrict__ dst, int* __restrict__ bucket_cnt, int n_edges) {
  __shared__ int hist[NBUCK];
  for (int b = threadIdx.x; b < NBUCK; b += 256) hist[b] = 0;
  __syncthreads();
  int stride = gridDim.x * 256;
  for (int e = blockIdx.x * 256 + threadIdx.x; e < n_edges; e += stride)
    atomicAdd(&hist[dst[e] >> 7], 1);
  __syncthreads();
  for (int b = threadIdx.x; b < NBUCK; b += 256) {
    int c = hist[b];
    if (c) atomicAdd(&bucket_cnt[b], c);
  }
}

// Step 2: exclusive scan of 782 bucket counts -> bucket_base, init cursors.
__global__ __launch_bounds__(256) void bucket_scan_kernel(
    const int* __restrict__ bucket_cnt, int* __restrict__ bucket_base,
    int* __restrict__ bucket_cursor) {
  __shared__ int tmp[256];
  int t = threadIdx.x;
  int loc[4];
  int s = 0;
  #pragma unroll
  for (int j = 0; j < 4; ++j) {
    int idx = 4 * t + j;
    loc[j] = s;
    s += (idx < NBUCK) ? bucket_cnt[idx] : 0;
  }
  tmp[t] = s;
  __syncthreads();
  for (int off = 1; off < 256; off <<= 1) {
    int u = (t >= off) ? tmp[t - off] : 0;
    __syncthreads();
    tmp[t] += u;
    __syncthreads();
  }
  int excl = tmp[t] - s;
  #pragma unroll
  for (int j = 0; j < 4; ++j) {
    int idx = 4 * t + j;
    if (idx < NBUCK) {
      int v = excl + loc[j];
      bucket_base[idx] = v;
      bucket_cursor[idx] = v;
    }
  }
  if (t == 255) bucket_base[NBUCK] = tmp[255];
}

// ===========================================================================
// Step 3: partition (src,dst) pairs into dst-buckets.  LDS histogram + scan
// + reorder per tile so same-bucket pairs leave as contiguous runs.
// ===========================================================================
__global__ __launch_bounds__(256) void bucket_partition_kernel(
    const int* __restrict__ src, const int* __restrict__ dst,
    int* __restrict__ bucket_cursor, int2* __restrict__ pairs, int n_edges) {
  __shared__ int hist[NBUCK];
  __shared__ int scan_[NBUCK];
  __shared__ int gbase[NBUCK];
  __shared__ int tmp[256];
  __shared__ int2 sorted[P1TILE];
  int t = threadIdx.x;
  long e0 = (long)blockIdx.x * P1TILE;
  int n = (int)min((long)P1TILE, (long)n_edges - e0);

  for (int b = t; b < NBUCK; b += 256) hist[b] = 0;
  __syncthreads();
  for (int i = t; i < n; i += 256) atomicAdd(&hist[dst[e0 + i] >> 7], 1);
  __syncthreads();

  int loc[4];
  int s = 0;
  #pragma unroll
  for (int j = 0; j < 4; ++j) {
    int idx = 4 * t + j;
    loc[j] = s;
    s += (idx < NBUCK) ? hist[idx] : 0;
  }
  tmp[t] = s;
  __syncthreads();
  for (int off = 1; off < 256; off <<= 1) {
    int u = (t >= off) ? tmp[t - off] : 0;
    __syncthreads();
    tmp[t] += u;
    __syncthreads();
  }
  int excl = tmp[t] - s;
  #pragma unroll
  for (int j = 0; j < 4; ++j) {
    int idx = 4 * t + j;
    if (idx < NBUCK) scan_[idx] = excl + loc[j];
  }
  __syncthreads();

  for (int b = t; b < NBUCK; b += 256) {
    int c = hist[b];
    gbase[b] = c ? atomicAdd(&bucket_cursor[b], c) : 0;
    hist[b] = scan_[b];
  }
  __syncthreads();

  for (int i = t; i < n; i += 256) {
    int sv = src[e0 + i];
    int dv = dst[e0 + i];
    int r = atomicAdd(&hist[dv >> 7], 1);   // LDS atomic
    sorted[r] = make_int2(sv, dv);
  }
  __syncthreads();

  for (int i = t; i < n; i += 256) {
    int2 p = sorted[i];
    int b = p.y >> 7;
    pairs[gbase[b] + (i - scan_[b])] = p;
  }
}

// ===========================================================================
// Step 4 (merged): per bucket, build node-level CSR offsets from the bucket's
// own pairs (LDS histogram + 128-entry scan -> coalesced offsets write) and
// sort src values by node into src_sorted (LDS staging, coalesced stream-out).
// ===========================================================================
__global__ __launch_bounds__(256) void bucket_csr_kernel(
    const int2* __restrict__ pairs, const int* __restrict__ bucket_base,
    int* __restrict__ offsets, int* __restrict__ src_sorted,
    int n_nodes, int n_edges) {
  __shared__ int2 sp[MAXB];
  __shared__ int lout[MAXB];
  __shared__ int ndeg[128];
  __shared__ int nsc[128];
  int b = blockIdx.x;
  int node0 = b << 7;
  int t = threadIdx.x;
  int ebeg = bucket_base[b];
  int eend = bucket_base[b + 1];
  int m = eend - ebeg;
  bool fits = (m <= MAXB);
  if (t < 128) ndeg[t] = 0;
  __syncthreads();

  // histogram over the bucket's 128 nodes
  if (fits) {
    for (int i = t; i < m; i += 256) {
      int2 p = pairs[ebeg + i];
      sp[i] = p;
      atomicAdd(&ndeg[p.y & 127], 1);   // LDS atomic
    }
  } else {  // overflow fallback (statistically never: avg 2048, cap 4096)
    for (int i = t; i < m; i += 256)
      atomicAdd(&ndeg[pairs[ebeg + i].y & 127], 1);
  }
  __syncthreads();

  // exclusive scan of 128 node degrees
  if (t < 128) nsc[t] = ndeg[t];
  __syncthreads();
  for (int off = 1; off < 128; off <<= 1) {
    int u = 0;
    if (t < 128 && t >= off) u = nsc[t - off];
    __syncthreads();
    if (t < 128) nsc[t] += u;
    __syncthreads();
  }
  if (t < 128) {
    int excl = nsc[t] - ndeg[t];
    int node = node0 + t;
    if (node < n_nodes) offsets[node] = ebeg + excl;
    ndeg[t] = excl;   // repurpose as placement cursor
  }
  if (b == NBUCK - 1 && t == 0) offsets[n_nodes] = n_edges;
  __syncthreads();

  // place src values grouped by node, stream out coalesced
  if (fits) {
    for (int i = t; i < m; i += 256) {
      int2 p = sp[i];
      int r = atomicAdd(&ndeg[p.y & 127], 1);  // LDS atomic
      lout[r] = p.x;
    }
    __syncthreads();
    for (int i = t; i < m; i += 256) src_sorted[ebeg + i] = lout[i];
  } else {
    for (int i = t; i < m; i += 256) {
      int2 p = pairs[ebeg + i];
      int r = atomicAdd(&ndeg[p.y & 127], 1);
      src_sorted[ebeg + r] = p.x;
    }
  }
}

// ===========================================================================
// fp32 -> bf16 bulk convert (x -> xb), float4 in / ushort4 out.
// ===========================================================================
__global__ __launch_bounds__(256) void convert_bf16_kernel(
    const float* __restrict__ x, unsigned short* __restrict__ xb, int n4) {
  int i = blockIdx.x * 256 + threadIdx.x;
  if (i >= n4) return;
  float4 v = ((const float4*)x)[i];
  ushort4 o;
  o.x = f2bf(v.x); o.y = f2bf(v.y); o.z = f2bf(v.z); o.w = f2bf(v.w);
  ((ushort4*)xb)[i] = o;
}

// Transposed bf16 weights, n-major [128 n][128 k]:
//   Wt1[n][k] = n<64 ? w1_l[k][n] : w1_r[k][n-64]     (layer-1, K = in_dim)
//   Wt2[n][k] = k<64 ? w2_l[k][n] : w2_r[k-64][n]     (layer-2, K = [mean2|h])
__global__ __launch_bounds__(128) void prep_weights_kernel(
    const float* __restrict__ w1_l, const float* __restrict__ w1_r,
    const float* __restrict__ w2_l, const float* __restrict__ w2_r,
    unsigned short* __restrict__ Wt1, unsigned short* __restrict__ Wt2) {
  int n = blockIdx.x, k = threadIdx.x;
  float v1 = (n < 64) ? w1_l[k * 64 + n] : w1_r[k * 64 + (n - 64)];
  Wt1[n * 128 + k] = f2bf(v1);
  float v2 = (k < 64) ? w2_l[k * 128 + n] : w2_r[(k - 64) * 128 + n];
  Wt2[n * 128 + k] = f2bf(v2);
}

// ===========================================================================
// MFMA GEMM: Y[M][128] = A[M][128] @ Wt^T (+bias), A bf16, fp32 accum.
// Block: 256 thr = 4 waves, tile 64 rows x 128 cols; wave w owns cols
// [32w,32w+32).  A tile in LDS (row pad 128->136 bf16: 2-way alias = free).
// BIAS_MODE: 1 = bias[col-64] for col>=64 only (layer 1), 2 = bias[col].
// ===========================================================================
template <int BIAS_MODE, bool OUT_BF16>
__global__ __launch_bounds__(256) void mfma_gemm_kernel(
    const unsigned short* __restrict__ A, const unsigned short* __restrict__ Wt,
    const float* __restrict__ bias, void* __restrict__ Y, int M) {
  __shared__ unsigned short As[64 * 136];
  int node0 = blockIdx.x * 64;
  int t = threadIdx.x;
  #pragma unroll
  for (int i = 0; i < 4; ++i) {
    int c = t + i * 256;           // 1024 x 16B chunks
    int row = c >> 4, c8 = (c & 15) * 8;
    uint4 v = make_uint4(0u, 0u, 0u, 0u);
    if (node0 + row < M) v = *(const uint4*)&A[(long)(node0 + row) * 128 + c8];
    *(uint4*)&As[row * 136 + c8] = v;
  }
  __syncthreads();
  int w = t >> 6, lane = t & 63;
  int m = lane & 15, q = lane >> 4;
  int col0 = w * 32;
  floatx4 acc[4][2];
  #pragma unroll
  for (int rt = 0; rt < 4; ++rt)
    #pragma unroll
    for (int ct = 0; ct < 2; ++ct) acc[rt][ct] = (floatx4){0.f, 0.f, 0.f, 0.f};

  #pragma unroll
  for (int ks = 0; ks < 4; ++ks) {
    bf16x8 b0 = *(const bf16x8*)&Wt[(col0 + m) * 128 + ks * 32 + q * 8];
    bf16x8 b1 = *(const bf16x8*)&Wt[(col0 + 16 + m) * 128 + ks * 32 + q * 8];
    #pragma unroll
    for (int rt = 0; rt < 4; ++rt) {
      bf16x8 a = *(const bf16x8*)&As[(rt * 16 + m) * 136 + ks * 32 + q * 8];
      acc[rt][0] = __builtin_amdgcn_mfma_f32_16x16x32_bf16(a, b0, acc[rt][0], 0, 0, 0);
      acc[rt][1] = __builtin_amdgcn_mfma_f32_16x16x32_bf16(a, b1, acc[rt][1], 0, 0, 0);
    }
  }
  // C/D layout (m89-verified): col = lane&15, row = (lane>>4)*4 + reg
  #pragma unroll
  for (int ct = 0; ct < 2; ++ct) {
    int col = col0 + ct * 16 + m;
    float bv = 0.f;
    if (BIAS_MODE == 1) bv = (col >= 64) ? bias[col - 64] : 0.f;
    if (BIAS_MODE == 2) bv = bias[col];
    #pragma unroll
    for (int rt = 0; rt < 4; ++rt) {
      #pragma unroll
      for (int i = 0; i < 4; ++i) {
        int row = node0 + rt * 16 + q * 4 + i;
        if (row >= M) continue;
        float v = acc[rt][ct][i] + bv;
        if (OUT_BF16) ((unsigned short*)Y)[(long)row * 128 + col] = f2bf(v);
        else          ((float*)Y)[(long)row * 128 + col] = v;
      }
    }
  }
}

// ===========================================================================
// Gather-mean over bf16 rows (64 feats = 128 B).  One wave/node, 8 lanes x
// 16B per edge row -> 8 edges per dwordx4 gather.
//
// Latency structure: ONE coalesced 64-wide preload of src indices per wave
// (covers deg<=64; Poisson(16) tail -> fallback loop), distributed via
// __shfl (DS pipe, off the VMEM chain), plus a manual 2-deep pipeline so
// the next gather issues before the current one is consumed.
//
// CDNA shfl rule (round-1 bug): ds_bpermute reads UNDEFINED data from
// EXEC-disabled source lanes.  All __shfl calls below are executed by the
// FULL wave (conditions are wave-uniform); only loads/accumulates are
// predicated per-lane.
//
// Accumulators are float2 -> v_pk_add_f32.  Summation order and reduction
// tree are bit-identical to the round-0 passing version (group g owns
// edges beg+8k+g, increasing k).
//
// FUSE_RELU: out = relu(mean + zadd_row) (layer-1 epilogue), bf16 out.
// ===========================================================================
#define ACC_V(v)                                                               \
  do {                                                                         \
    a01 += (floatx2){__uint_as_float((v).x << 16),                             \
                     __uint_as_float((v).x & 0xffff0000u)};                    \
    a23 += (floatx2){__uint_as_float((v).y << 16),                             \
                     __uint_as_float((v).y & 0xffff0000u)};                    \
    a45 += (floatx2){__uint_as_float((v).z << 16),                             \
                     __uint_as_float((v).z & 0xffff0000u)};                    \
    a67 += (floatx2){__uint_as_float((v).w << 16),                             \
                     __uint_as_float((v).w & 0xffff0000u)};                    \
  } while (0)

template <bool FUSE_RELU>
__global__ __launch_bounds__(256) void aggregate_bf16_kernel(
    const unsigned short* __restrict__ gsrc, const unsigned short* __restrict__ zadd,
    unsigned short* __restrict__ outp, const int* __restrict__ offsets,
    const int* __restrict__ src_sorted, int n_nodes) {
  int wave = (blockIdx.x * 256 + threadIdx.x) >> 6;
  int lane = threadIdx.x & 63;
  if (wave >= n_nodes) return;
  int g = lane >> 3;    // edge slot 0..7
  int sl = lane & 7;    // 16B chunk within row
  int beg = offsets[wave], end = offsets[wave + 1];
  int deg = end - beg;
  int dcap = min(deg, 64);
  // one coalesced load grabs this wave's first 64 src indices
  int sidx = (lane < dcap) ? src_sorted[beg + lane] : 0;
  const unsigned short* base = gsrc + sl * 8;

  floatx2 a01 = {0.f, 0.f}, a23 = {0.f, 0.f}, a45 = {0.f, 0.f}, a67 = {0.f, 0.f};

  int nfull = dcap >> 3, rem = dcap & 7;   // wave-uniform
  if (nfull > 0) {
    // 2-deep pipeline: gather k+1 in flight while accumulating k
    int s = __shfl(sidx, g, 64);
    uint4 v = *(const uint4*)(base + (long)s * 128);
    for (int k = 1; k < nfull; ++k) {
      int s2 = __shfl(sidx, 8 * k + g, 64);
      uint4 v2 = *(const uint4*)(base + (long)s2 * 128);
      ACC_V(v);
      v = v2;
    }
    ACC_V(v);
  }
  if (rem) {  // wave-uniform branch; shfl by ALL lanes (source lanes active)
    int s = __shfl(sidx, 8 * nfull + g, 64);   // 8*nfull+g <= 63 when rem>0
    if (g < rem) {
      uint4 v = *(const uint4*)(base + (long)s * 128);
      ACC_V(v);
    }
  }
  // deg > 64 overflow (statistically never for Poisson(16), kept for correctness)
  for (int e = beg + 64 + g; e < end; e += 8) {
    int s = src_sorted[e];
    uint4 v = *(const uint4*)(base + (long)s * 128);
    ACC_V(v);
  }

  #pragma unroll
  for (int off = 8; off <= 32; off <<= 1) {
    a01.x += __shfl_xor(a01.x, off, 64); a01.y += __shfl_xor(a01.y, off, 64);
    a23.x += __shfl_xor(a23.x, off, 64); a23.y += __shfl_xor(a23.y, off, 64);
    a45.x += __shfl_xor(a45.x, off, 64); a45.y += __shfl_xor(a45.y, off, 64);
    a67.x += __shfl_xor(a67.x, off, 64); a67.y += __shfl_xor(a67.y, off, 64);
  }
  if (g == 0) {
    float inv = 1.f / fmaxf((float)deg, 1.f);
    float r[8];
    r[0] = a01.x * inv; r[1] = a01.y * inv;
    r[2] = a23.x * inv; r[3] = a23.y * inv;
    r[4] = a45.x * inv; r[5] = a45.y * inv;
    r[6] = a67.x * inv; r[7] = a67.y * inv;
    if (FUSE_RELU) {
      uint4 z = *(const uint4*)&zadd[(long)wave * 128 + sl * 8];
      r[0] = fmaxf(r[0] + __uint_as_float(z.x << 16), 0.f);
      r[1] = fmaxf(r[1] + __uint_as_float(z.x & 0xffff0000u), 0.f);
      r[2] = fmaxf(r[2] + __uint_as_float(z.y << 16), 0.f);
      r[3] = fmaxf(r[3] + __uint_as_float(z.y & 0xffff0000u), 0.f);
      r[4] = fmaxf(r[4] + __uint_as_float(z.z << 16), 0.f);
      r[5] = fmaxf(r[5] + __uint_as_float(z.z & 0xffff0000u), 0.f);
      r[6] = fmaxf(r[6] + __uint_as_float(z.w << 16), 0.f);
      r[7] = fmaxf(r[7] + __uint_as_float(z.w & 0xffff0000u), 0.f);
    }
    uint4 ov;
    ov.x = (unsigned)f2bf(r[0]) | ((unsigned)f2bf(r[1]) << 16);
    ov.y = (unsigned)f2bf(r[2]) | ((unsigned)f2bf(r[3]) << 16);
    ov.z = (unsigned)f2bf(r[4]) | ((unsigned)f2bf(r[5]) << 16);
    ov.w = (unsigned)f2bf(r[6]) | ((unsigned)f2bf(r[7]) << 16);
    *(uint4*)&outp[(long)wave * 128 + sl * 8] = ov;
  }
}
#undef ACC_V

extern "C" void kernel_launch(void* const* d_in, const int* in_sizes, int n_in,
                              void* d_out, int out_size, void* d_ws, size_t ws_size,
                              hipStream_t stream) {
  const float* x    = (const float*)d_in[0];
  const int*   ei   = (const int*)d_in[1];
  const float* w1_l = (const float*)d_in[2];
  const float* b1   = (const float*)d_in[3];
  const float* w1_r = (const float*)d_in[4];
  const float* w2_l = (const float*)d_in[5];
  const float* b2   = (const float*)d_in[6];
  const float* w2_r = (const float*)d_in[7];
  float* out = (float*)d_out;

  const int E = in_sizes[1] / 2;
  const int* src = ei;
  const int* dst = ei + E;

  // ---- workspace layout (~70.9 MB) ----
  unsigned short* ZB1 = (unsigned short*)d_ws;          // [N][128] bf16: y1|z1
  unsigned short* ZB2 = ZB1 + (long)N_NODES * 128;      // [N][128] bf16: xb, then mean2|h
  unsigned short* Wt1 = ZB2 + (long)N_NODES * 128;      // 128x128 bf16
  unsigned short* Wt2 = Wt1 + 16384;                    // 128x128 bf16
  int* bucket_cnt    = (int*)(Wt2 + 16384);             // 782 (even)
  int* bucket_base   = bucket_cnt + NBUCK;              // 784 (padded even)
  int* bucket_cursor = bucket_base + NBUCK + 2;         // 784 (padded even)
  int* offsets       = bucket_cursor + NBUCK + 2;       // N+2 (even)
  int* src_sorted    = offsets + N_NODES + 2;           // E (even)
  int2* pairs        = (int2*)(src_sorted + E);         // E int2 (8B-aligned)

  // ---- CSR build (bucketed; no node-level global atomics anywhere) ----
  hipMemsetAsync(bucket_cnt, 0, (size_t)NBUCK * sizeof(int), stream);
  bucket_count_kernel<<<512, 256, 0, stream>>>(dst, bucket_cnt, E);
  bucket_scan_kernel<<<1, 256, 0, stream>>>(bucket_cnt, bucket_base,
                                            bucket_cursor);
  bucket_partition_kernel<<<(E + P1TILE - 1) / P1TILE, 256, 0, stream>>>(
      src, dst, bucket_cursor, pairs, E);
  bucket_csr_kernel<<<NBUCK, 256, 0, stream>>>(pairs, bucket_base, offsets,
                                               src_sorted, N_NODES, E);

  // ---- bf16 prep ----
  convert_bf16_kernel<<<(N_NODES * 128 / 4 + 255) / 256, 256, 0, stream>>>(
      x, ZB2, N_NODES * 128 / 4);
  prep_weights_kernel<<<128, 128, 0, stream>>>(w1_l, w1_r, w2_l, w2_r, Wt1, Wt2);

  int gemm_blocks = (N_NODES + 63) / 64;
  int agg_blocks = (N_NODES + 3) / 4;

  // ---- Layer 1: ZB1 = [x@w1_l | x@w1_r + b1] (bf16) ----
  mfma_gemm_kernel<1, true><<<gemm_blocks, 256, 0, stream>>>(
      ZB2, Wt1, b1, ZB1, N_NODES);
  // h = relu(mean(y1) + z1) -> ZB2[:,64:128] (xb dead after GEMM1)
  aggregate_bf16_kernel<true><<<agg_blocks, 256, 0, stream>>>(
      ZB1, ZB1 + 64, ZB2 + 64, offsets, src_sorted, N_NODES);

  // ---- Layer 2: mean2 -> ZB2[:,0:64]; out = [mean2|h] @ Wt2^T + b2 ----
  aggregate_bf16_kernel<false><<<agg_blocks, 256, 0, stream>>>(
      ZB2 + 64, nullptr, ZB2, offsets, src_sorted, N_NODES);
  mfma_gemm_kernel<2, false><<<gemm_blocks, 256, 0, stream>>>(
      ZB2, Wt2, b2, out, N_NODES);
}

// Round 3
// 275.314 us; speedup vs baseline: 1.1349x; 1.1349x over previous
//
#include <hip/hip_runtime.h>

#define N_NODES 100000
#define NBUCK   782      // ceil(100000/128) buckets of 128 nodes
#define P1TILE  8192     // edges per phase-1 block
#define MAXB    4096     // phase-2 LDS capacity (avg bucket = 2048 edges)

typedef __bf16 bf16x8 __attribute__((ext_vector_type(8)));
typedef float floatx4 __attribute__((ext_vector_type(4)));
typedef float floatx2 __attribute__((ext_vector_type(2)));

static __device__ __forceinline__ unsigned short f2bf(float f) {
  unsigned u = __float_as_uint(f);
  u += 0x7fff + ((u >> 16) & 1);   // round-to-nearest-even
  return (unsigned short)(u >> 16);
}

// ===========================================================================
// Step 1: bucket-level edge counts (LDS histogram; ~200k global atomics on
// 3 KB instead of 1.6M on 400 KB -> no scattered-line write amplification).
// ===========================================================================
__global__ __launch_bounds__(256) void bucket_count_kernel(
    const int* __restrict__ dst, int* __restrict__ bucket_cnt, int n_edges) {
  __shared__ int hist[NBUCK];
  for (int b = threadIdx.x; b < NBUCK; b += 256) hist[b] = 0;
  __syncthreads();
  int stride = gridDim.x * 256;
  for (int e = blockIdx.x * 256 + threadIdx.x; e < n_edges; e += stride)
    atomicAdd(&hist[dst[e] >> 7], 1);
  __syncthreads();
  for (int b = threadIdx.x; b < NBUCK; b += 256) {
    int c = hist[b];
    if (c) atomicAdd(&bucket_cnt[b], c);
  }
}

// Step 2: exclusive scan of 782 bucket counts -> bucket_base, init cursors.
__global__ __launch_bounds__(256) void bucket_scan_kernel(
    const int* __restrict__ bucket_cnt, int* __restrict__ bucket_base,
    int* __restrict__ bucket_cursor) {
  __shared__ int tmp[256];
  int t = threadIdx.x;
  int loc[4];
  int s = 0;
  #pragma unroll
  for (int j = 0; j < 4; ++j) {
    int idx = 4 * t + j;
    loc[j] = s;
    s += (idx < NBUCK) ? bucket_cnt[idx] : 0;
  }
  tmp[t] = s;
  __syncthreads();
  for (int off = 1; off < 256; off <<= 1) {
    int u = (t >= off) ? tmp[t - off] : 0;
    __syncthreads();
    tmp[t] += u;
    __syncthreads();
  }
  int excl = tmp[t] - s;
  #pragma unroll
  for (int j = 0; j < 4; ++j) {
    int idx = 4 * t + j;
    if (idx < NBUCK) {
      int v = excl + loc[j];
      bucket_base[idx] = v;
      bucket_cursor[idx] = v;
    }
  }
  if (t == 255) bucket_base[NBUCK] = tmp[255];
}

// ===========================================================================
// Step 3: partition (src,dst) pairs into dst-buckets.  LDS histogram + scan
// + reorder per tile so same-bucket pairs leave as contiguous runs.
// Global output is PACKED 4B: src (17 bits) | dst&127 (bits 17..23) --
// halves the partition-write + csr-read traffic.
// ===========================================================================
__global__ __launch_bounds__(256) void bucket_partition_kernel(
    const int* __restrict__ src, const int* __restrict__ dst,
    int* __restrict__ bucket_cursor, unsigned* __restrict__ pairs,
    int n_edges) {
  __shared__ int hist[NBUCK];
  __shared__ int scan_[NBUCK];
  __shared__ int gbase[NBUCK];
  __shared__ int tmp[256];
  __shared__ int2 sorted[P1TILE];
  int t = threadIdx.x;
  long e0 = (long)blockIdx.x * P1TILE;
  int n = (int)min((long)P1TILE, (long)n_edges - e0);

  for (int b = t; b < NBUCK; b += 256) hist[b] = 0;
  __syncthreads();
  for (int i = t; i < n; i += 256) atomicAdd(&hist[dst[e0 + i] >> 7], 1);
  __syncthreads();

  int loc[4];
  int s = 0;
  #pragma unroll
  for (int j = 0; j < 4; ++j) {
    int idx = 4 * t + j;
    loc[j] = s;
    s += (idx < NBUCK) ? hist[idx] : 0;
  }
  tmp[t] = s;
  __syncthreads();
  for (int off = 1; off < 256; off <<= 1) {
    int u = (t >= off) ? tmp[t - off] : 0;
    __syncthreads();
    tmp[t] += u;
    __syncthreads();
  }
  int excl = tmp[t] - s;
  #pragma unroll
  for (int j = 0; j < 4; ++j) {
    int idx = 4 * t + j;
    if (idx < NBUCK) scan_[idx] = excl + loc[j];
  }
  __syncthreads();

  for (int b = t; b < NBUCK; b += 256) {
    int c = hist[b];
    gbase[b] = c ? atomicAdd(&bucket_cursor[b], c) : 0;
    hist[b] = scan_[b];
  }
  __syncthreads();

  for (int i = t; i < n; i += 256) {
    int sv = src[e0 + i];
    int dv = dst[e0 + i];
    int r = atomicAdd(&hist[dv >> 7], 1);   // LDS atomic
    sorted[r] = make_int2(sv, dv);
  }
  __syncthreads();

  for (int i = t; i < n; i += 256) {
    int2 p = sorted[i];
    int b = p.y >> 7;
    unsigned pk = (unsigned)p.x | ((unsigned)(p.y & 127) << 17);
    pairs[gbase[b] + (i - scan_[b])] = pk;
  }
}

// ===========================================================================
// Step 4 (merged): per bucket, build node-level CSR offsets from the bucket's
// own packed pairs (LDS histogram + 128-entry scan -> coalesced offsets
// write) and sort src values by node into src_sorted (LDS staging).
// ===========================================================================
__global__ __launch_bounds__(256) void bucket_csr_kernel(
    const unsigned* __restrict__ pairs, const int* __restrict__ bucket_base,
    int* __restrict__ offsets, int* __restrict__ src_sorted,
    int n_nodes, int n_edges) {
  __shared__ unsigned sp[MAXB];
  __shared__ int lout[MAXB];
  __shared__ int ndeg[128];
  __shared__ int nsc[128];
  int b = blockIdx.x;
  int node0 = b << 7;
  int t = threadIdx.x;
  int ebeg = bucket_base[b];
  int eend = bucket_base[b + 1];
  int m = eend - ebeg;
  bool fits = (m <= MAXB);
  if (t < 128) ndeg[t] = 0;
  __syncthreads();

  // histogram over the bucket's 128 nodes
  if (fits) {
    for (int i = t; i < m; i += 256) {
      unsigned p = pairs[ebeg + i];
      sp[i] = p;
      atomicAdd(&ndeg[p >> 17], 1);   // LDS atomic
    }
  } else {  // overflow fallback (statistically never: avg 2048, cap 4096)
    for (int i = t; i < m; i += 256)
      atomicAdd(&ndeg[pairs[ebeg + i] >> 17], 1);
  }
  __syncthreads();

  // exclusive scan of 128 node degrees
  if (t < 128) nsc[t] = ndeg[t];
  __syncthreads();
  for (int off = 1; off < 128; off <<= 1) {
    int u = 0;
    if (t < 128 && t >= off) u = nsc[t - off];
    __syncthreads();
    if (t < 128) nsc[t] += u;
    __syncthreads();
  }
  if (t < 128) {
    int excl = nsc[t] - ndeg[t];
    int node = node0 + t;
    if (node < n_nodes) offsets[node] = ebeg + excl;
    ndeg[t] = excl;   // repurpose as placement cursor
  }
  if (b == NBUCK - 1 && t == 0) offsets[n_nodes] = n_edges;
  __syncthreads();

  // place src values grouped by node, stream out coalesced
  if (fits) {
    for (int i = t; i < m; i += 256) {
      unsigned p = sp[i];
      int r = atomicAdd(&ndeg[p >> 17], 1);  // LDS atomic
      lout[r] = (int)(p & 0x1FFFFu);
    }
    __syncthreads();
    for (int i = t; i < m; i += 256) src_sorted[ebeg + i] = lout[i];
  } else {
    for (int i = t; i < m; i += 256) {
      unsigned p = pairs[ebeg + i];
      int r = atomicAdd(&ndeg[p >> 17], 1);
      src_sorted[ebeg + r] = (int)(p & 0x1FFFFu);
    }
  }
}

// Transposed bf16 weights, n-major [128 n][128 k]:
//   Wt1[n][k] = n<64 ? w1_l[k][n] : w1_r[k][n-64]     (layer-1, K = in_dim)
//   Wt2[n][k] = k<64 ? w2_l[k][n] : w2_r[k-64][n]     (layer-2, K = [mean2|h])
__global__ __launch_bounds__(128) void prep_weights_kernel(
    const float* __restrict__ w1_l, const float* __restrict__ w1_r,
    const float* __restrict__ w2_l, const float* __restrict__ w2_r,
    unsigned short* __restrict__ Wt1, unsigned short* __restrict__ Wt2) {
  int n = blockIdx.x, k = threadIdx.x;
  float v1 = (n < 64) ? w1_l[k * 64 + n] : w1_r[k * 64 + (n - 64)];
  Wt1[n * 128 + k] = f2bf(v1);
  float v2 = (k < 64) ? w2_l[k * 128 + n] : w2_r[(k - 64) * 128 + n];
  Wt2[n * 128 + k] = f2bf(v2);
}

// ===========================================================================
// MFMA GEMM: Y[M][128] = A[M][128] @ Wt^T (+bias), fp32 accum.
// A_F32: A is fp32 in global, converted to bf16 while staging into LDS
// (fuses the old convert kernel into GEMM1 -> saves 77MB of traffic).
// Block: 256 thr = 4 waves, tile 64 rows x 128 cols; wave w owns cols
// [32w,32w+32).  A tile in LDS (row pad 128->136 bf16: 2-way alias = free).
// BIAS_MODE: 1 = bias[col-64] for col>=64 only (layer 1), 2 = bias[col].
// ===========================================================================
template <int BIAS_MODE, bool OUT_BF16, bool A_F32>
__global__ __launch_bounds__(256) void mfma_gemm_kernel(
    const void* __restrict__ Av, const unsigned short* __restrict__ Wt,
    const float* __restrict__ bias, void* __restrict__ Y, int M) {
  __shared__ unsigned short As[64 * 136];
  int node0 = blockIdx.x * 64;
  int t = threadIdx.x;
  if (A_F32) {
    const float* A = (const float*)Av;
    #pragma unroll
    for (int i = 0; i < 8; ++i) {
      int c = t + i * 256;           // 2048 x 16B fp32 chunks (4 floats)
      int row = c >> 5, c4 = (c & 31) * 4;
      float4 v = make_float4(0.f, 0.f, 0.f, 0.f);
      if (node0 + row < M) v = *(const float4*)&A[(long)(node0 + row) * 128 + c4];
      ushort4 o;
      o.x = f2bf(v.x); o.y = f2bf(v.y); o.z = f2bf(v.z); o.w = f2bf(v.w);
      *(ushort4*)&As[row * 136 + c4] = o;
    }
  } else {
    const unsigned short* A = (const unsigned short*)Av;
    #pragma unroll
    for (int i = 0; i < 4; ++i) {
      int c = t + i * 256;           // 1024 x 16B bf16 chunks
      int row = c >> 4, c8 = (c & 15) * 8;
      uint4 v = make_uint4(0u, 0u, 0u, 0u);
      if (node0 + row < M) v = *(const uint4*)&A[(long)(node0 + row) * 128 + c8];
      *(uint4*)&As[row * 136 + c8] = v;
    }
  }
  __syncthreads();
  int w = t >> 6, lane = t & 63;
  int m = lane & 15, q = lane >> 4;
  int col0 = w * 32;
  floatx4 acc[4][2];
  #pragma unroll
  for (int rt = 0; rt < 4; ++rt)
    #pragma unroll
    for (int ct = 0; ct < 2; ++ct) acc[rt][ct] = (floatx4){0.f, 0.f, 0.f, 0.f};

  #pragma unroll
  for (int ks = 0; ks < 4; ++ks) {
    bf16x8 b0 = *(const bf16x8*)&Wt[(col0 + m) * 128 + ks * 32 + q * 8];
    bf16x8 b1 = *(const bf16x8*)&Wt[(col0 + 16 + m) * 128 + ks * 32 + q * 8];
    #pragma unroll
    for (int rt = 0; rt < 4; ++rt) {
      bf16x8 a = *(const bf16x8*)&As[(rt * 16 + m) * 136 + ks * 32 + q * 8];
      acc[rt][0] = __builtin_amdgcn_mfma_f32_16x16x32_bf16(a, b0, acc[rt][0], 0, 0, 0);
      acc[rt][1] = __builtin_amdgcn_mfma_f32_16x16x32_bf16(a, b1, acc[rt][1], 0, 0, 0);
    }
  }
  // C/D layout (m89-verified): col = lane&15, row = (lane>>4)*4 + reg
  #pragma unroll
  for (int ct = 0; ct < 2; ++ct) {
    int col = col0 + ct * 16 + m;
    float bv = 0.f;
    if (BIAS_MODE == 1) bv = (col >= 64) ? bias[col - 64] : 0.f;
    if (BIAS_MODE == 2) bv = bias[col];
    #pragma unroll
    for (int rt = 0; rt < 4; ++rt) {
      #pragma unroll
      for (int i = 0; i < 4; ++i) {
        int row = node0 + rt * 16 + q * 4 + i;
        if (row >= M) continue;
        float v = acc[rt][ct][i] + bv;
        if (OUT_BF16) ((unsigned short*)Y)[(long)row * 128 + col] = f2bf(v);
        else          ((float*)Y)[(long)row * 128 + col] = v;
      }
    }
  }
}

// ===========================================================================
// Gather-mean over bf16 rows (64 feats = 128 B).
//
// Structure (round-3): EIGHT nodes per wave, 8 lanes per node (sub=lane>>3),
// each lane owns 8 feats (16B) of its node's output -> NO cross-lane
// reduction at all.  Per node the 8-lane group walks its edge list
// sequentially; the unrolled 8-wide inner loop gives ~8 independent gathers
// in flight per lane (8 KB/wave MLP, 4x the old 2-deep pipeline), and the
// fixed per-wave latency chain (idx load -> shfl -> gather -> store) is
// amortized over 8 nodes instead of 1.
//
// Indices stream in batches of 8 per node via one coalesced 64-wide load,
// double-buffered ahead of the inner loop.  All __shfl calls execute
// full-wave (round-1 lesson: ds_bpermute from EXEC-disabled lanes is
// undefined); only loads/accumulates are exec-masked.
//
// FUSE_RELU: out = relu(mean + zadd_row) (layer-1 epilogue), bf16 out.
// ===========================================================================
#define ACC_V(v)                                                               \
  do {                                                                         \
    a01 += (floatx2){__uint_as_float((v).x << 16),                             \
                     __uint_as_float((v).x & 0xffff0000u)};                    \
    a23 += (floatx2){__uint_as_float((v).y << 16),                             \
                     __uint_as_float((v).y & 0xffff0000u)};                    \
    a45 += (floatx2){__uint_as_float((v).z << 16),                             \
                     __uint_as_float((v).z & 0xffff0000u)};                    \
    a67 += (floatx2){__uint_as_float((v).w << 16),                             \
                     __uint_as_float((v).w & 0xffff0000u)};                    \
  } while (0)

template <bool FUSE_RELU>
__global__ __launch_bounds__(256) void aggregate_bf16_kernel(
    const unsigned short* __restrict__ gsrc, const unsigned short* __restrict__ zadd,
    unsigned short* __restrict__ outp, const int* __restrict__ offsets,
    const int* __restrict__ src_sorted, int n_nodes) {
  int wid = (blockIdx.x * 256 + threadIdx.x) >> 6;
  int lane = threadIdx.x & 63;
  int node8 = wid << 3;
  if (node8 >= n_nodes) return;
  int sub = lane >> 3;    // node slot 0..7
  int sl  = lane & 7;     // 16B chunk within row
  int node = node8 + sub;
  bool nvalid = (node < n_nodes);
  int beg = nvalid ? offsets[node] : 0;
  int end = nvalid ? offsets[node + 1] : 0;
  int deg = end - beg;    // uniform within each 8-lane group

  // wave-max degree (loop bound; full-wave shfl_xor max, 3 steps)
  int R = deg;
  R = max(R, __shfl_xor(R, 8, 64));
  R = max(R, __shfl_xor(R, 16, 64));
  R = max(R, __shfl_xor(R, 32, 64));

  const unsigned short* base = gsrc + sl * 8;
  floatx2 a01 = {0.f, 0.f}, a23 = {0.f, 0.f}, a45 = {0.f, 0.f}, a67 = {0.f, 0.f};

  // first index batch: positions 0..7 of this node's edge list
  int sidx = (sl < deg) ? src_sorted[beg + sl] : 0;
  int srcl = (lane & 56);   // group base lane for shfl sources

  for (int b = 0; b * 8 < R; ++b) {
    // prefetch next index batch (wave-uniform condition; coalesced)
    int sidx_nxt = 0;
    int nb = (b + 1) * 8;
    if (nb < R) {
      int p = nb + sl;
      if (p < deg) sidx_nxt = src_sorted[beg + p];
    }
    int k0 = b * 8;
    #pragma unroll
    for (int j = 0; j < 8; ++j) {
      int s = __shfl(sidx, srcl | j, 64);   // full-wave; source lanes active
      if (k0 + j < deg) {
        uint4 v = *(const uint4*)(base + (long)s * 128);
        ACC_V(v);
      }
    }
    sidx = sidx_nxt;
  }

  if (nvalid) {
    float inv = 1.f / fmaxf((float)deg, 1.f);
    float r[8];
    r[0] = a01.x * inv; r[1] = a01.y * inv;
    r[2] = a23.x * inv; r[3] = a23.y * inv;
    r[4] = a45.x * inv; r[5] = a45.y * inv;
    r[6] = a67.x * inv; r[7] = a67.y * inv;
    if (FUSE_RELU) {
      uint4 z = *(const uint4*)&zadd[(long)node * 128 + sl * 8];
      r[0] = fmaxf(r[0] + __uint_as_float(z.x << 16), 0.f);
      r[1] = fmaxf(r[1] + __uint_as_float(z.x & 0xffff0000u), 0.f);
      r[2] = fmaxf(r[2] + __uint_as_float(z.y << 16), 0.f);
      r[3] = fmaxf(r[3] + __uint_as_float(z.y & 0xffff0000u), 0.f);
      r[4] = fmaxf(r[4] + __uint_as_float(z.z << 16), 0.f);
      r[5] = fmaxf(r[5] + __uint_as_float(z.z & 0xffff0000u), 0.f);
      r[6] = fmaxf(r[6] + __uint_as_float(z.w << 16), 0.f);
      r[7] = fmaxf(r[7] + __uint_as_float(z.w & 0xffff0000u), 0.f);
    }
    uint4 ov;
    ov.x = (unsigned)f2bf(r[0]) | ((unsigned)f2bf(r[1]) << 16);
    ov.y = (unsigned)f2bf(r[2]) | ((unsigned)f2bf(r[3]) << 16);
    ov.z = (unsigned)f2bf(r[4]) | ((unsigned)f2bf(r[5]) << 16);
    ov.w = (unsigned)f2bf(r[6]) | ((unsigned)f2bf(r[7]) << 16);
    *(uint4*)&outp[(long)node * 128 + sl * 8] = ov;
  }
}
#undef ACC_V

extern "C" void kernel_launch(void* const* d_in, const int* in_sizes, int n_in,
                              void* d_out, int out_size, void* d_ws, size_t ws_size,
                              hipStream_t stream) {
  const float* x    = (const float*)d_in[0];
  const int*   ei   = (const int*)d_in[1];
  const float* w1_l = (const float*)d_in[2];
  const float* b1   = (const float*)d_in[3];
  const float* w1_r = (const float*)d_in[4];
  const float* w2_l = (const float*)d_in[5];
  const float* b2   = (const float*)d_in[6];
  const float* w2_r = (const float*)d_in[7];
  float* out = (float*)d_out;

  const int E = in_sizes[1] / 2;
  const int* src = ei;
  const int* dst = ei + E;

  // ---- workspace layout ----
  unsigned short* ZB1 = (unsigned short*)d_ws;          // [N][128] bf16: y1|z1
  unsigned short* ZB2 = ZB1 + (long)N_NODES * 128;      // [N][128] bf16: mean2|h
  unsigned short* Wt1 = ZB2 + (long)N_NODES * 128;      // 128x128 bf16
  unsigned short* Wt2 = Wt1 + 16384;                    // 128x128 bf16
  int* bucket_cnt    = (int*)(Wt2 + 16384);             // 782 (even)
  int* bucket_base   = bucket_cnt + NBUCK;              // 784 (padded even)
  int* bucket_cursor = bucket_base + NBUCK + 2;         // 784 (padded even)
  int* offsets       = bucket_cursor + NBUCK + 2;       // N+2 (even)
  int* src_sorted    = offsets + N_NODES + 2;           // E (even)
  unsigned* pairs    = (unsigned*)(src_sorted + E);     // E packed 4B

  // ---- CSR build (bucketed; no node-level global atomics anywhere) ----
  hipMemsetAsync(bucket_cnt, 0, (size_t)NBUCK * sizeof(int), stream);
  bucket_count_kernel<<<512, 256, 0, stream>>>(dst, bucket_cnt, E);
  bucket_scan_kernel<<<1, 256, 0, stream>>>(bucket_cnt, bucket_base,
                                            bucket_cursor);
  bucket_partition_kernel<<<(E + P1TILE - 1) / P1TILE, 256, 0, stream>>>(
      src, dst, bucket_cursor, pairs, E);
  bucket_csr_kernel<<<NBUCK, 256, 0, stream>>>(pairs, bucket_base, offsets,
                                               src_sorted, N_NODES, E);

  // ---- weights prep (convert kernel deleted: GEMM1 reads x fp32) ----
  prep_weights_kernel<<<128, 128, 0, stream>>>(w1_l, w1_r, w2_l, w2_r, Wt1, Wt2);

  int gemm_blocks = (N_NODES + 63) / 64;
  int agg_blocks = (N_NODES + 31) / 32;   // 8 nodes/wave, 4 waves/block

  // ---- Layer 1: ZB1 = [x@w1_l | x@w1_r + b1] (bf16), fused fp32->bf16 ----
  mfma_gemm_kernel<1, true, true><<<gemm_blocks, 256, 0, stream>>>(
      x, Wt1, b1, ZB1, N_NODES);
  // h = relu(mean(y1) + z1) -> ZB2[:,64:128]
  aggregate_bf16_kernel<true><<<agg_blocks, 256, 0, stream>>>(
      ZB1, ZB1 + 64, ZB2 + 64, offsets, src_sorted, N_NODES);

  // ---- Layer 2: mean2 -> ZB2[:,0:64]; out = [mean2|h] @ Wt2^T + b2 ----
  aggregate_bf16_kernel<false><<<agg_blocks, 256, 0, stream>>>(
      ZB2 + 64, nullptr, ZB2, offsets, src_sorted, N_NODES);
  mfma_gemm_kernel<2, false, false><<<gemm_blocks, 256, 0, stream>>>(
      ZB2, Wt2, b2, out, N_NODES);
}

// Round 4
// 267.057 us; speedup vs baseline: 1.1700x; 1.0309x over previous
//
#include <hip/hip_runtime.h>

#define N_NODES 100000
#define NBUCK   782      // ceil(100000/128) buckets of 128 nodes
#define P1TILE  8192     // edges per phase-1 block
#define MAXB    4096     // phase-2 LDS capacity (avg bucket = 2048 edges)
#define AGG_CAP 512      // staged edge indices per wave (mean 128, Poisson(128))

typedef __bf16 bf16x8 __attribute__((ext_vector_type(8)));
typedef float floatx4 __attribute__((ext_vector_type(4)));
typedef float floatx2 __attribute__((ext_vector_type(2)));

static __device__ __forceinline__ unsigned short f2bf(float f) {
  unsigned u = __float_as_uint(f);
  u += 0x7fff + ((u >> 16) & 1);   // round-to-nearest-even
  return (unsigned short)(u >> 16);
}

// ===========================================================================
// Step 1: bucket-level edge counts (LDS histogram; ~200k global atomics on
// 3 KB instead of 1.6M on 400 KB -> no scattered-line write amplification).
// ===========================================================================
__global__ __launch_bounds__(256) void bucket_count_kernel(
    const int* __restrict__ dst, int* __restrict__ bucket_cnt, int n_edges) {
  __shared__ int hist[NBUCK];
  for (int b = threadIdx.x; b < NBUCK; b += 256) hist[b] = 0;
  __syncthreads();
  int stride = gridDim.x * 256;
  for (int e = blockIdx.x * 256 + threadIdx.x; e < n_edges; e += stride)
    atomicAdd(&hist[dst[e] >> 7], 1);
  __syncthreads();
  for (int b = threadIdx.x; b < NBUCK; b += 256) {
    int c = hist[b];
    if (c) atomicAdd(&bucket_cnt[b], c);
  }
}

// Step 2: exclusive scan of 782 bucket counts -> bucket_base, init cursors.
__global__ __launch_bounds__(256) void bucket_scan_kernel(
    const int* __restrict__ bucket_cnt, int* __restrict__ bucket_base,
    int* __restrict__ bucket_cursor) {
  __shared__ int tmp[256];
  int t = threadIdx.x;
  int loc[4];
  int s = 0;
  #pragma unroll
  for (int j = 0; j < 4; ++j) {
    int idx = 4 * t + j;
    loc[j] = s;
    s += (idx < NBUCK) ? bucket_cnt[idx] : 0;
  }
  tmp[t] = s;
  __syncthreads();
  for (int off = 1; off < 256; off <<= 1) {
    int u = (t >= off) ? tmp[t - off] : 0;
    __syncthreads();
    tmp[t] += u;
    __syncthreads();
  }
  int excl = tmp[t] - s;
  #pragma unroll
  for (int j = 0; j < 4; ++j) {
    int idx = 4 * t + j;
    if (idx < NBUCK) {
      int v = excl + loc[j];
      bucket_base[idx] = v;
      bucket_cursor[idx] = v;
    }
  }
  if (t == 255) bucket_base[NBUCK] = tmp[255];
}

// ===========================================================================
// Step 3: partition (src,dst) pairs into dst-buckets.  LDS histogram + scan
// + reorder per tile so same-bucket pairs leave as contiguous runs.
// Global output is PACKED 4B: src (17 bits) | dst&127 (bits 17..23) --
// halves the partition-write + csr-read traffic.
// ===========================================================================
__global__ __launch_bounds__(256) void bucket_partition_kernel(
    const int* __restrict__ src, const int* __restrict__ dst,
    int* __restrict__ bucket_cursor, unsigned* __restrict__ pairs,
    int n_edges) {
  __shared__ int hist[NBUCK];
  __shared__ int scan_[NBUCK];
  __shared__ int gbase[NBUCK];
  __shared__ int tmp[256];
  __shared__ int2 sorted[P1TILE];
  int t = threadIdx.x;
  long e0 = (long)blockIdx.x * P1TILE;
  int n = (int)min((long)P1TILE, (long)n_edges - e0);

  for (int b = t; b < NBUCK; b += 256) hist[b] = 0;
  __syncthreads();
  for (int i = t; i < n; i += 256) atomicAdd(&hist[dst[e0 + i] >> 7], 1);
  __syncthreads();

  int loc[4];
  int s = 0;
  #pragma unroll
  for (int j = 0; j < 4; ++j) {
    int idx = 4 * t + j;
    loc[j] = s;
    s += (idx < NBUCK) ? hist[idx] : 0;
  }
  tmp[t] = s;
  __syncthreads();
  for (int off = 1; off < 256; off <<= 1) {
    int u = (t >= off) ? tmp[t - off] : 0;
    __syncthreads();
    tmp[t] += u;
    __syncthreads();
  }
  int excl = tmp[t] - s;
  #pragma unroll
  for (int j = 0; j < 4; ++j) {
    int idx = 4 * t + j;
    if (idx < NBUCK) scan_[idx] = excl + loc[j];
  }
  __syncthreads();

  for (int b = t; b < NBUCK; b += 256) {
    int c = hist[b];
    gbase[b] = c ? atomicAdd(&bucket_cursor[b], c) : 0;
    hist[b] = scan_[b];
  }
  __syncthreads();

  for (int i = t; i < n; i += 256) {
    int sv = src[e0 + i];
    int dv = dst[e0 + i];
    int r = atomicAdd(&hist[dv >> 7], 1);   // LDS atomic
    sorted[r] = make_int2(sv, dv);
  }
  __syncthreads();

  for (int i = t; i < n; i += 256) {
    int2 p = sorted[i];
    int b = p.y >> 7;
    unsigned pk = (unsigned)p.x | ((unsigned)(p.y & 127) << 17);
    pairs[gbase[b] + (i - scan_[b])] = pk;
  }
}

// ===========================================================================
// Step 4 (merged): per bucket, build node-level CSR offsets from the bucket's
// own packed pairs (LDS histogram + 128-entry scan -> coalesced offsets
// write) and sort src values by node into src_sorted (LDS staging).
// ===========================================================================
__global__ __launch_bounds__(256) void bucket_csr_kernel(
    const unsigned* __restrict__ pairs, const int* __restrict__ bucket_base,
    int* __restrict__ offsets, int* __restrict__ src_sorted,
    int n_nodes, int n_edges) {
  __shared__ unsigned sp[MAXB];
  __shared__ int lout[MAXB];
  __shared__ int ndeg[128];
  __shared__ int nsc[128];
  int b = blockIdx.x;
  int node0 = b << 7;
  int t = threadIdx.x;
  int ebeg = bucket_base[b];
  int eend = bucket_base[b + 1];
  int m = eend - ebeg;
  bool fits = (m <= MAXB);
  if (t < 128) ndeg[t] = 0;
  __syncthreads();

  // histogram over the bucket's 128 nodes
  if (fits) {
    for (int i = t; i < m; i += 256) {
      unsigned p = pairs[ebeg + i];
      sp[i] = p;
      atomicAdd(&ndeg[p >> 17], 1);   // LDS atomic
    }
  } else {  // overflow fallback (statistically never: avg 2048, cap 4096)
    for (int i = t; i < m; i += 256)
      atomicAdd(&ndeg[pairs[ebeg + i] >> 17], 1);
  }
  __syncthreads();

  // exclusive scan of 128 node degrees
  if (t < 128) nsc[t] = ndeg[t];
  __syncthreads();
  for (int off = 1; off < 128; off <<= 1) {
    int u = 0;
    if (t < 128 && t >= off) u = nsc[t - off];
    __syncthreads();
    if (t < 128) nsc[t] += u;
    __syncthreads();
  }
  if (t < 128) {
    int excl = nsc[t] - ndeg[t];
    int node = node0 + t;
    if (node < n_nodes) offsets[node] = ebeg + excl;
    ndeg[t] = excl;   // repurpose as placement cursor
  }
  if (b == NBUCK - 1 && t == 0) offsets[n_nodes] = n_edges;
  __syncthreads();

  // place src values grouped by node, stream out coalesced
  if (fits) {
    for (int i = t; i < m; i += 256) {
      unsigned p = sp[i];
      int r = atomicAdd(&ndeg[p >> 17], 1);  // LDS atomic
      lout[r] = (int)(p & 0x1FFFFu);
    }
    __syncthreads();
    for (int i = t; i < m; i += 256) src_sorted[ebeg + i] = lout[i];
  } else {
    for (int i = t; i < m; i += 256) {
      unsigned p = pairs[ebeg + i];
      int r = atomicAdd(&ndeg[p >> 17], 1);
      src_sorted[ebeg + r] = (int)(p & 0x1FFFFu);
    }
  }
}

// Transposed bf16 weights, n-major [128 n][128 k]:
//   Wt1[n][k] = n<64 ? w1_l[k][n] : w1_r[k][n-64]     (layer-1, K = in_dim)
//   Wt2[n][k] = k<64 ? w2_l[k][n] : w2_r[k-64][n]     (layer-2, K = [mean2|h])
__global__ __launch_bounds__(128) void prep_weights_kernel(
    const float* __restrict__ w1_l, const float* __restrict__ w1_r,
    const float* __restrict__ w2_l, const float* __restrict__ w2_r,
    unsigned short* __restrict__ Wt1, unsigned short* __restrict__ Wt2) {
  int n = blockIdx.x, k = threadIdx.x;
  float v1 = (n < 64) ? w1_l[k * 64 + n] : w1_r[k * 64 + (n - 64)];
  Wt1[n * 128 + k] = f2bf(v1);
  float v2 = (k < 64) ? w2_l[k * 128 + n] : w2_r[(k - 64) * 128 + n];
  Wt2[n * 128 + k] = f2bf(v2);
}

// ===========================================================================
// MFMA GEMM: Y[M][128] = A[M][128] @ Wt^T (+bias), fp32 accum.
// A_F32: A is fp32 in global, converted to bf16 while staging into LDS
// (fuses the old convert kernel into GEMM1 -> saves 77MB of traffic).
// Block: 256 thr = 4 waves, tile 64 rows x 128 cols; wave w owns cols
// [32w,32w+32).  A tile in LDS (row pad 128->136 bf16: 2-way alias = free).
// BIAS_MODE: 1 = bias[col-64] for col>=64 only (layer 1), 2 = bias[col].
// ===========================================================================
template <int BIAS_MODE, bool OUT_BF16, bool A_F32>
__global__ __launch_bounds__(256) void mfma_gemm_kernel(
    const void* __restrict__ Av, const unsigned short* __restrict__ Wt,
    const float* __restrict__ bias, void* __restrict__ Y, int M) {
  __shared__ unsigned short As[64 * 136];
  int node0 = blockIdx.x * 64;
  int t = threadIdx.x;
  if (A_F32) {
    const float* A = (const float*)Av;
    #pragma unroll
    for (int i = 0; i < 8; ++i) {
      int c = t + i * 256;           // 2048 x 16B fp32 chunks (4 floats)
      int row = c >> 5, c4 = (c & 31) * 4;
      float4 v = make_float4(0.f, 0.f, 0.f, 0.f);
      if (node0 + row < M) v = *(const float4*)&A[(long)(node0 + row) * 128 + c4];
      ushort4 o;
      o.x = f2bf(v.x); o.y = f2bf(v.y); o.z = f2bf(v.z); o.w = f2bf(v.w);
      *(ushort4*)&As[row * 136 + c4] = o;
    }
  } else {
    const unsigned short* A = (const unsigned short*)Av;
    #pragma unroll
    for (int i = 0; i < 4; ++i) {
      int c = t + i * 256;           // 1024 x 16B bf16 chunks
      int row = c >> 4, c8 = (c & 15) * 8;
      uint4 v = make_uint4(0u, 0u, 0u, 0u);
      if (node0 + row < M) v = *(const uint4*)&A[(long)(node0 + row) * 128 + c8];
      *(uint4*)&As[row * 136 + c8] = v;
    }
  }
  __syncthreads();
  int w = t >> 6, lane = t & 63;
  int m = lane & 15, q = lane >> 4;
  int col0 = w * 32;
  floatx4 acc[4][2];
  #pragma unroll
  for (int rt = 0; rt < 4; ++rt)
    #pragma unroll
    for (int ct = 0; ct < 2; ++ct) acc[rt][ct] = (floatx4){0.f, 0.f, 0.f, 0.f};

  #pragma unroll
  for (int ks = 0; ks < 4; ++ks) {
    bf16x8 b0 = *(const bf16x8*)&Wt[(col0 + m) * 128 + ks * 32 + q * 8];
    bf16x8 b1 = *(const bf16x8*)&Wt[(col0 + 16 + m) * 128 + ks * 32 + q * 8];
    #pragma unroll
    for (int rt = 0; rt < 4; ++rt) {
      bf16x8 a = *(const bf16x8*)&As[(rt * 16 + m) * 136 + ks * 32 + q * 8];
      acc[rt][0] = __builtin_amdgcn_mfma_f32_16x16x32_bf16(a, b0, acc[rt][0], 0, 0, 0);
      acc[rt][1] = __builtin_amdgcn_mfma_f32_16x16x32_bf16(a, b1, acc[rt][1], 0, 0, 0);
    }
  }
  // C/D layout (m89-verified): col = lane&15, row = (lane>>4)*4 + reg
  #pragma unroll
  for (int ct = 0; ct < 2; ++ct) {
    int col = col0 + ct * 16 + m;
    float bv = 0.f;
    if (BIAS_MODE == 1) bv = (col >= 64) ? bias[col - 64] : 0.f;
    if (BIAS_MODE == 2) bv = bias[col];
    #pragma unroll
    for (int rt = 0; rt < 4; ++rt) {
      #pragma unroll
      for (int i = 0; i < 4; ++i) {
        int row = node0 + rt * 16 + q * 4 + i;
        if (row >= M) continue;
        float v = acc[rt][ct][i] + bv;
        if (OUT_BF16) ((unsigned short*)Y)[(long)row * 128 + col] = f2bf(v);
        else          ((float*)Y)[(long)row * 128 + col] = v;
      }
    }
  }
}

// ===========================================================================
// Gather-mean over bf16 rows (64 feats = 128 B).
//
// Round-4 structure: 8 nodes/wave, 8 lanes/node (sub=lane>>3), each lane owns
// 8 feats (16B) of its node's output -> no cross-lane reduction.  The wave's
// 8 nodes cover a CONTIGUOUS CSR edge range [wbeg,wend); stage all its src
// indices into wave-private LDS once (coalesced, cap 512, Poisson(128) never
// exceeds it; global fallback kept).  Each group then loops over ITS OWN
// degree reading indices via broadcast ds_read (8 lanes same address =
// conflict-free) -- no shfl, no wave-max bound, no per-chunk predication.
//
// Inner loop unrolled x4 with FOUR NAMED accumulator chains + uint4 regs:
// forces 4 independent gathers in flight (round-3's VGPR=20 allocation
// collapsed the intended pipeline to ~1).  fp32 reassociation across the 4
// chains is ~1e-7 relative -- output is bf16-quantized, 4x margin on the
// absmax threshold.
//
// FUSE_RELU: out = relu(mean + zadd_row) (layer-1 epilogue), bf16 out.
// ===========================================================================
#define ACC_P(A, v)                                                            \
  do {                                                                         \
    A[0] += (floatx2){__uint_as_float((v).x << 16),                            \
                      __uint_as_float((v).x & 0xffff0000u)};                   \
    A[1] += (floatx2){__uint_as_float((v).y << 16),                            \
                      __uint_as_float((v).y & 0xffff0000u)};                   \
    A[2] += (floatx2){__uint_as_float((v).z << 16),                            \
                      __uint_as_float((v).z & 0xffff0000u)};                   \
    A[3] += (floatx2){__uint_as_float((v).w << 16),                            \
                      __uint_as_float((v).w & 0xffff0000u)};                   \
  } while (0)

template <bool FUSE_RELU>
__global__ __launch_bounds__(256) void aggregate_bf16_kernel(
    const unsigned short* __restrict__ gsrc, const unsigned short* __restrict__ zadd,
    unsigned short* __restrict__ outp, const int* __restrict__ offsets,
    const int* __restrict__ src_sorted, int n_nodes) {
  __shared__ int stage[4 * AGG_CAP];
  int wv = threadIdx.x >> 6;             // wave in block 0..3
  int lane = threadIdx.x & 63;
  int wid = (blockIdx.x << 2) | wv;
  int node8 = wid << 3;
  int sub = lane >> 3;    // node slot 0..7
  int sl  = lane & 7;     // 16B chunk within row
  int node = node8 + sub;
  bool wvalid = (node8 < n_nodes);
  bool nvalid = wvalid && (node < n_nodes);

  int wbeg = 0, wend = 0, beg = 0, end = 0;
  if (wvalid) {
    wbeg = offsets[node8];
    wend = offsets[min(node8 + 8, n_nodes)];
  }
  if (nvalid) {
    beg = offsets[node];
    end = offsets[node + 1];
  }
  int deg = end - beg;
  int cnt = wend - wbeg;                 // wave-uniform
  int* my = &stage[wv * AGG_CAP];
  bool staged = wvalid && (cnt <= AGG_CAP);
  if (staged) {
    for (int i = lane; i < cnt; i += 64) my[i] = src_sorted[wbeg + i];
  }
  __syncthreads();   // executed by ALL threads (no early returns above)

  const unsigned short* base = gsrc + sl * 8;
  floatx2 A0[4], A1[4], A2[4], A3[4];
  #pragma unroll
  for (int i = 0; i < 4; ++i) {
    A0[i] = (floatx2){0.f, 0.f}; A1[i] = (floatx2){0.f, 0.f};
    A2[i] = (floatx2){0.f, 0.f}; A3[i] = (floatx2){0.f, 0.f};
  }

  if (staged) {
    int lb = beg - wbeg;                 // local base in staged indices
    int e = 0;
    for (; e + 4 <= deg; e += 4) {
      int s0 = my[lb + e];
      int s1 = my[lb + e + 1];
      int s2 = my[lb + e + 2];
      int s3 = my[lb + e + 3];
      uint4 v0 = *(const uint4*)(base + (long)s0 * 128);
      uint4 v1 = *(const uint4*)(base + (long)s1 * 128);
      uint4 v2 = *(const uint4*)(base + (long)s2 * 128);
      uint4 v3 = *(const uint4*)(base + (long)s3 * 128);
      ACC_P(A0, v0); ACC_P(A1, v1); ACC_P(A2, v2); ACC_P(A3, v3);
    }
    for (; e < deg; ++e) {
      int s0 = my[lb + e];
      uint4 v0 = *(const uint4*)(base + (long)s0 * 128);
      ACC_P(A0, v0);
    }
  } else if (nvalid) {  // overflow fallback (statistically never)
    for (int e = beg; e < end; ++e) {
      int s0 = src_sorted[e];
      uint4 v0 = *(const uint4*)(base + (long)s0 * 128);
      ACC_P(A0, v0);
    }
  }
  #pragma unroll
  for (int i = 0; i < 4; ++i) A0[i] = (A0[i] + A1[i]) + (A2[i] + A3[i]);

  if (nvalid) {
    float inv = 1.f / fmaxf((float)deg, 1.f);
    float r[8];
    r[0] = A0[0].x * inv; r[1] = A0[0].y * inv;
    r[2] = A0[1].x * inv; r[3] = A0[1].y * inv;
    r[4] = A0[2].x * inv; r[5] = A0[2].y * inv;
    r[6] = A0[3].x * inv; r[7] = A0[3].y * inv;
    if (FUSE_RELU) {
      uint4 z = *(const uint4*)&zadd[(long)node * 128 + sl * 8];
      r[0] = fmaxf(r[0] + __uint_as_float(z.x << 16), 0.f);
      r[1] = fmaxf(r[1] + __uint_as_float(z.x & 0xffff0000u), 0.f);
      r[2] = fmaxf(r[2] + __uint_as_float(z.y << 16), 0.f);
      r[3] = fmaxf(r[3] + __uint_as_float(z.y & 0xffff0000u), 0.f);
      r[4] = fmaxf(r[4] + __uint_as_float(z.z << 16), 0.f);
      r[5] = fmaxf(r[5] + __uint_as_float(z.z & 0xffff0000u), 0.f);
      r[6] = fmaxf(r[6] + __uint_as_float(z.w << 16), 0.f);
      r[7] = fmaxf(r[7] + __uint_as_float(z.w & 0xffff0000u), 0.f);
    }
    uint4 ov;
    ov.x = (unsigned)f2bf(r[0]) | ((unsigned)f2bf(r[1]) << 16);
    ov.y = (unsigned)f2bf(r[2]) | ((unsigned)f2bf(r[3]) << 16);
    ov.z = (unsigned)f2bf(r[4]) | ((unsigned)f2bf(r[5]) << 16);
    ov.w = (unsigned)f2bf(r[6]) | ((unsigned)f2bf(r[7]) << 16);
    *(uint4*)&outp[(long)node * 128 + sl * 8] = ov;
  }
}
#undef ACC_P

extern "C" void kernel_launch(void* const* d_in, const int* in_sizes, int n_in,
                              void* d_out, int out_size, void* d_ws, size_t ws_size,
                              hipStream_t stream) {
  const float* x    = (const float*)d_in[0];
  const int*   ei   = (const int*)d_in[1];
  const float* w1_l = (const float*)d_in[2];
  const float* b1   = (const float*)d_in[3];
  const float* w1_r = (const float*)d_in[4];
  const float* w2_l = (const float*)d_in[5];
  const float* b2   = (const float*)d_in[6];
  const float* w2_r = (const float*)d_in[7];
  float* out = (float*)d_out;

  const int E = in_sizes[1] / 2;
  const int* src = ei;
  const int* dst = ei + E;

  // ---- workspace layout ----
  unsigned short* ZB1 = (unsigned short*)d_ws;          // [N][128] bf16: y1|z1
  unsigned short* ZB2 = ZB1 + (long)N_NODES * 128;      // [N][128] bf16: mean2|h
  unsigned short* Wt1 = ZB2 + (long)N_NODES * 128;      // 128x128 bf16
  unsigned short* Wt2 = Wt1 + 16384;                    // 128x128 bf16
  int* bucket_cnt    = (int*)(Wt2 + 16384);             // 782 (even)
  int* bucket_base   = bucket_cnt + NBUCK;              // 784 (padded even)
  int* bucket_cursor = bucket_base + NBUCK + 2;         // 784 (padded even)
  int* offsets       = bucket_cursor + NBUCK + 2;       // N+2 (even)
  int* src_sorted    = offsets + N_NODES + 2;           // E (even)
  unsigned* pairs    = (unsigned*)(src_sorted + E);     // E packed 4B

  // ---- CSR build (bucketed; no node-level global atomics anywhere) ----
  hipMemsetAsync(bucket_cnt, 0, (size_t)NBUCK * sizeof(int), stream);
  bucket_count_kernel<<<512, 256, 0, stream>>>(dst, bucket_cnt, E);
  bucket_scan_kernel<<<1, 256, 0, stream>>>(bucket_cnt, bucket_base,
                                            bucket_cursor);
  bucket_partition_kernel<<<(E + P1TILE - 1) / P1TILE, 256, 0, stream>>>(
      src, dst, bucket_cursor, pairs, E);
  bucket_csr_kernel<<<NBUCK, 256, 0, stream>>>(pairs, bucket_base, offsets,
                                               src_sorted, N_NODES, E);

  // ---- weights prep (convert kernel deleted: GEMM1 reads x fp32) ----
  prep_weights_kernel<<<128, 128, 0, stream>>>(w1_l, w1_r, w2_l, w2_r, Wt1, Wt2);

  int gemm_blocks = (N_NODES + 63) / 64;
  int agg_blocks = (N_NODES + 31) / 32;   // 8 nodes/wave, 4 waves/block

  // ---- Layer 1: ZB1 = [x@w1_l | x@w1_r + b1] (bf16), fused fp32->bf16 ----
  mfma_gemm_kernel<1, true, true><<<gemm_blocks, 256, 0, stream>>>(
      x, Wt1, b1, ZB1, N_NODES);
  // h = relu(mean(y1) + z1) -> ZB2[:,64:128]
  aggregate_bf16_kernel<true><<<agg_blocks, 256, 0, stream>>>(
      ZB1, ZB1 + 64, ZB2 + 64, offsets, src_sorted, N_NODES);

  // ---- Layer 2: mean2 -> ZB2[:,0:64]; out = [mean2|h] @ Wt2^T + b2 ----
  aggregate_bf16_kernel<false><<<agg_blocks, 256, 0, stream>>>(
      ZB2 + 64, nullptr, ZB2, offsets, src_sorted, N_NODES);
  mfma_gemm_kernel<2, false, false><<<gemm_blocks, 256, 0, stream>>>(
      ZB2, Wt2, b2, out, N_NODES);
}

// Round 5
// 260.789 us; speedup vs baseline: 1.1981x; 1.0240x over previous
//
#include <hip/hip_runtime.h>

#define N_NODES 100000
#define NBUCK   782      // ceil(100000/128) buckets of 128 nodes
#define P1TILE  8192     // edges per phase-1 block
#define MAXB    4096     // bucket slab capacity (avg 2048, +45 sigma)
#define SLAB    4096
#define AGG_CAP 512      // staged edge indices per agg wave (mean 128)
#define G2CAP   1536     // staged edge indices per gemm2 block (mean 1024)

typedef __bf16 bf16x8 __attribute__((ext_vector_type(8)));
typedef float floatx4 __attribute__((ext_vector_type(4)));
typedef float floatx2 __attribute__((ext_vector_type(2)));

static __device__ __forceinline__ unsigned short f2bf(float f) {
  unsigned u = __float_as_uint(f);
  u += 0x7fff + ((u >> 16) & 1);   // round-to-nearest-even
  return (unsigned short)(u >> 16);
}

// ===========================================================================
// Step 1: partition (src,dst) pairs into per-bucket SLABS (fixed stride).
// LDS histogram + scan + reorder per tile -> contiguous runs; run base
// reserved with one global atomicAdd per (tile,bucket) on zeroed cursors.
// No count pre-pass needed (round-5: deletes a full 6.4MB edge read).
// Packed 4B: src (17 bits) | dst&127 (bits 17..23).
// ===========================================================================
__global__ __launch_bounds__(256) void bucket_partition_kernel(
    const int* __restrict__ src, const int* __restrict__ dst,
    int* __restrict__ bucket_cursor, unsigned* __restrict__ pairs,
    int n_edges) {
  __shared__ int hist[NBUCK];
  __shared__ int scan_[NBUCK];
  __shared__ int gbase[NBUCK];
  __shared__ int tmp[256];
  __shared__ int2 sorted[P1TILE];
  int t = threadIdx.x;
  long e0 = (long)blockIdx.x * P1TILE;
  int n = (int)min((long)P1TILE, (long)n_edges - e0);

  for (int b = t; b < NBUCK; b += 256) hist[b] = 0;
  __syncthreads();
  for (int i = t; i < n; i += 256) atomicAdd(&hist[dst[e0 + i] >> 7], 1);
  __syncthreads();

  int loc[4];
  int s = 0;
  #pragma unroll
  for (int j = 0; j < 4; ++j) {
    int idx = 4 * t + j;
    loc[j] = s;
    s += (idx < NBUCK) ? hist[idx] : 0;
  }
  tmp[t] = s;
  __syncthreads();
  for (int off = 1; off < 256; off <<= 1) {
    int u = (t >= off) ? tmp[t - off] : 0;
    __syncthreads();
    tmp[t] += u;
    __syncthreads();
  }
  int excl = tmp[t] - s;
  #pragma unroll
  for (int j = 0; j < 4; ++j) {
    int idx = 4 * t + j;
    if (idx < NBUCK) scan_[idx] = excl + loc[j];
  }
  __syncthreads();

  for (int b = t; b < NBUCK; b += 256) {
    int c = hist[b];
    gbase[b] = c ? atomicAdd(&bucket_cursor[b], c) : 0;   // slab-local base
    hist[b] = scan_[b];
  }
  __syncthreads();

  for (int i = t; i < n; i += 256) {
    int sv = src[e0 + i];
    int dv = dst[e0 + i];
    int r = atomicAdd(&hist[dv >> 7], 1);   // LDS atomic
    sorted[r] = make_int2(sv, dv);
  }
  __syncthreads();

  for (int i = t; i < n; i += 256) {
    int2 p = sorted[i];
    int b = p.y >> 7;
    int pos = gbase[b] + (i - scan_[b]);
    if (pos < SLAB) {   // statistically never exceeded (+45 sigma)
      unsigned pk = (unsigned)p.x | ((unsigned)(p.y & 127) << 17);
      pairs[(long)b * SLAB + pos] = pk;
    }
  }
}

// Step 2: exclusive scan of bucket counts (cursor values) -> compact bases.
__global__ __launch_bounds__(256) void bucket_scan_kernel(
    const int* __restrict__ bucket_cnt, int* __restrict__ bucket_base) {
  __shared__ int tmp[256];
  int t = threadIdx.x;
  int loc[4];
  int s = 0;
  #pragma unroll
  for (int j = 0; j < 4; ++j) {
    int idx = 4 * t + j;
    loc[j] = s;
    s += (idx < NBUCK) ? min(bucket_cnt[idx], SLAB) : 0;
  }
  tmp[t] = s;
  __syncthreads();
  for (int off = 1; off < 256; off <<= 1) {
    int u = (t >= off) ? tmp[t - off] : 0;
    __syncthreads();
    tmp[t] += u;
    __syncthreads();
  }
  int excl = tmp[t] - s;
  #pragma unroll
  for (int j = 0; j < 4; ++j) {
    int idx = 4 * t + j;
    if (idx < NBUCK) bucket_base[idx] = excl + loc[j];
  }
  if (t == 255) bucket_base[NBUCK] = tmp[255];
}

// ===========================================================================
// Step 3: per bucket, node-level CSR offsets (LDS histogram + 128 scan) and
// node-sorted src stream-out (compact), reading from the bucket's slab.
// ===========================================================================
__global__ __launch_bounds__(256) void bucket_csr_kernel(
    const unsigned* __restrict__ pairs, const int* __restrict__ bucket_cnt,
    const int* __restrict__ bucket_base, int* __restrict__ offsets,
    int* __restrict__ src_sorted, int n_nodes, int n_edges) {
  __shared__ unsigned sp[MAXB];
  __shared__ int lout[MAXB];
  __shared__ int ndeg[128];
  __shared__ int nsc[128];
  int b = blockIdx.x;
  int node0 = b << 7;
  int t = threadIdx.x;
  long sbeg = (long)b * SLAB;          // slab read base
  int obase = bucket_base[b];          // compact write base
  int m = min(bucket_cnt[b], SLAB);    // SLAB == MAXB: always fits LDS
  if (t < 128) ndeg[t] = 0;
  __syncthreads();

  for (int i = t; i < m; i += 256) {
    unsigned p = pairs[sbeg + i];
    sp[i] = p;
    atomicAdd(&ndeg[p >> 17], 1);   // LDS atomic
  }
  __syncthreads();

  // exclusive scan of 128 node degrees
  if (t < 128) nsc[t] = ndeg[t];
  __syncthreads();
  for (int off = 1; off < 128; off <<= 1) {
    int u = 0;
    if (t < 128 && t >= off) u = nsc[t - off];
    __syncthreads();
    if (t < 128) nsc[t] += u;
    __syncthreads();
  }
  if (t < 128) {
    int excl = nsc[t] - ndeg[t];
    int node = node0 + t;
    if (node < n_nodes) offsets[node] = obase + excl;
    ndeg[t] = excl;   // repurpose as placement cursor
  }
  if (b == NBUCK - 1 && t == 0) offsets[n_nodes] = n_edges;
  __syncthreads();

  // place src values grouped by node, stream out coalesced
  for (int i = t; i < m; i += 256) {
    unsigned p = sp[i];
    int r = atomicAdd(&ndeg[p >> 17], 1);  // LDS atomic
    lout[r] = (int)(p & 0x1FFFFu);
  }
  __syncthreads();
  for (int i = t; i < m; i += 256) src_sorted[obase + i] = lout[i];
}

// Transposed bf16 weights, n-major [128 n][128 k]:
//   Wt1[n][k] = n<64 ? w1_l[k][n] : w1_r[k][n-64]     (layer-1, K = in_dim)
//   Wt2[n][k] = k<64 ? w2_l[k][n] : w2_r[k-64][n]     (layer-2, K = [mean2|h])
__global__ __launch_bounds__(128) void prep_weights_kernel(
    const float* __restrict__ w1_l, const float* __restrict__ w1_r,
    const float* __restrict__ w2_l, const float* __restrict__ w2_r,
    unsigned short* __restrict__ Wt1, unsigned short* __restrict__ Wt2) {
  int n = blockIdx.x, k = threadIdx.x;
  float v1 = (n < 64) ? w1_l[k * 64 + n] : w1_r[k * 64 + (n - 64)];
  Wt1[n * 128 + k] = f2bf(v1);
  float v2 = (k < 64) ? w2_l[k * 128 + n] : w2_r[(k - 64) * 128 + n];
  Wt2[n * 128 + k] = f2bf(v2);
}

// ===========================================================================
// MFMA GEMM (layer 1): ZB1[M][128] = bf16(x)[M][128] @ Wt1^T (+b1 on cols
// >=64).  A is fp32 in global, converted to bf16 while staging into LDS.
// Block: 256 thr = 4 waves, tile 64 rows x 128 cols; wave w owns cols
// [32w,32w+32).  A tile in LDS (row pad 128->136 bf16: 2-way alias = free).
// ===========================================================================
__global__ __launch_bounds__(256) void mfma_gemm1_kernel(
    const float* __restrict__ A, const unsigned short* __restrict__ Wt,
    const float* __restrict__ bias, unsigned short* __restrict__ Y, int M) {
  __shared__ unsigned short As[64 * 136];
  int node0 = blockIdx.x * 64;
  int t = threadIdx.x;
  #pragma unroll
  for (int i = 0; i < 8; ++i) {
    int c = t + i * 256;           // 2048 x 16B fp32 chunks (4 floats)
    int row = c >> 5, c4 = (c & 31) * 4;
    float4 v = make_float4(0.f, 0.f, 0.f, 0.f);
    if (node0 + row < M) v = *(const float4*)&A[(long)(node0 + row) * 128 + c4];
    ushort4 o;
    o.x = f2bf(v.x); o.y = f2bf(v.y); o.z = f2bf(v.z); o.w = f2bf(v.w);
    *(ushort4*)&As[row * 136 + c4] = o;
  }
  __syncthreads();
  int w = t >> 6, lane = t & 63;
  int m = lane & 15, q = lane >> 4;
  int col0 = w * 32;
  floatx4 acc[4][2];
  #pragma unroll
  for (int rt = 0; rt < 4; ++rt)
    #pragma unroll
    for (int ct = 0; ct < 2; ++ct) acc[rt][ct] = (floatx4){0.f, 0.f, 0.f, 0.f};

  #pragma unroll
  for (int ks = 0; ks < 4; ++ks) {
    bf16x8 b0 = *(const bf16x8*)&Wt[(col0 + m) * 128 + ks * 32 + q * 8];
    bf16x8 b1 = *(const bf16x8*)&Wt[(col0 + 16 + m) * 128 + ks * 32 + q * 8];
    #pragma unroll
    for (int rt = 0; rt < 4; ++rt) {
      bf16x8 a = *(const bf16x8*)&As[(rt * 16 + m) * 136 + ks * 32 + q * 8];
      acc[rt][0] = __builtin_amdgcn_mfma_f32_16x16x32_bf16(a, b0, acc[rt][0], 0, 0, 0);
      acc[rt][1] = __builtin_amdgcn_mfma_f32_16x16x32_bf16(a, b1, acc[rt][1], 0, 0, 0);
    }
  }
  // C/D layout (m89-verified): col = lane&15, row = (lane>>4)*4 + reg
  #pragma unroll
  for (int ct = 0; ct < 2; ++ct) {
    int col = col0 + ct * 16 + m;
    float bv = (col >= 64) ? bias[col - 64] : 0.f;
    #pragma unroll
    for (int rt = 0; rt < 4; ++rt) {
      #pragma unroll
      for (int i = 0; i < 4; ++i) {
        int row = node0 + rt * 16 + q * 4 + i;
        if (row >= M) continue;
        Y[(long)row * 128 + col] = f2bf(acc[rt][ct][i] + bv);
      }
    }
  }
}

#define ACC_P(A, v)                                                            \
  do {                                                                         \
    A[0] += (floatx2){__uint_as_float((v).x << 16),                            \
                      __uint_as_float((v).x & 0xffff0000u)};                   \
    A[1] += (floatx2){__uint_as_float((v).y << 16),                            \
                      __uint_as_float((v).y & 0xffff0000u)};                   \
    A[2] += (floatx2){__uint_as_float((v).z << 16),                            \
                      __uint_as_float((v).z & 0xffff0000u)};                   \
    A[3] += (floatx2){__uint_as_float((v).w << 16),                            \
                      __uint_as_float((v).w & 0xffff0000u)};                   \
  } while (0)

// ===========================================================================
// Layer-1 aggregate: h = relu(mean(y1[neighbors]) + z1) -> ZB2[:,64:128].
// 8 nodes/wave, 8 lanes/node, lane owns 16B of output; wave's contiguous
// CSR index range staged in LDS once; 4 named accumulator chains keep 4
// gathers in flight (round-4 structure, verified).
// ===========================================================================
__global__ __launch_bounds__(256) void aggregate_bf16_kernel(
    const unsigned short* __restrict__ gsrc, const unsigned short* __restrict__ zadd,
    unsigned short* __restrict__ outp, const int* __restrict__ offsets,
    const int* __restrict__ src_sorted, int n_nodes) {
  __shared__ int stage[4 * AGG_CAP];
  int wv = threadIdx.x >> 6;             // wave in block 0..3
  int lane = threadIdx.x & 63;
  int wid = (blockIdx.x << 2) | wv;
  int node8 = wid << 3;
  int sub = lane >> 3;    // node slot 0..7
  int sl  = lane & 7;     // 16B chunk within row
  int node = node8 + sub;
  bool wvalid = (node8 < n_nodes);
  bool nvalid = wvalid && (node < n_nodes);

  int wbeg = 0, wend = 0, beg = 0, end = 0;
  if (wvalid) {
    wbeg = offsets[node8];
    wend = offsets[min(node8 + 8, n_nodes)];
  }
  if (nvalid) {
    beg = offsets[node];
    end = offsets[node + 1];
  }
  int deg = end - beg;
  int cnt = wend - wbeg;                 // wave-uniform
  int* my = &stage[wv * AGG_CAP];
  bool staged = wvalid && (cnt <= AGG_CAP);
  if (staged) {
    for (int i = lane; i < cnt; i += 64) my[i] = src_sorted[wbeg + i];
  }
  __syncthreads();   // executed by ALL threads (no early returns above)

  const unsigned short* base = gsrc + sl * 8;
  floatx2 A0[4], A1[4], A2[4], A3[4];
  #pragma unroll
  for (int i = 0; i < 4; ++i) {
    A0[i] = (floatx2){0.f, 0.f}; A1[i] = (floatx2){0.f, 0.f};
    A2[i] = (floatx2){0.f, 0.f}; A3[i] = (floatx2){0.f, 0.f};
  }

  if (staged) {
    int lb = beg - wbeg;                 // local base in staged indices
    int e = 0;
    for (; e + 4 <= deg; e += 4) {
      int s0 = my[lb + e];
      int s1 = my[lb + e + 1];
      int s2 = my[lb + e + 2];
      int s3 = my[lb + e + 3];
      uint4 v0 = *(const uint4*)(base + (long)s0 * 128);
      uint4 v1 = *(const uint4*)(base + (long)s1 * 128);
      uint4 v2 = *(const uint4*)(base + (long)s2 * 128);
      uint4 v3 = *(const uint4*)(base + (long)s3 * 128);
      ACC_P(A0, v0); ACC_P(A1, v1); ACC_P(A2, v2); ACC_P(A3, v3);
    }
    for (; e < deg; ++e) {
      int s0 = my[lb + e];
      uint4 v0 = *(const uint4*)(base + (long)s0 * 128);
      ACC_P(A0, v0);
    }
  } else if (nvalid) {  // overflow fallback (statistically never)
    for (int e = beg; e < end; ++e) {
      int s0 = src_sorted[e];
      uint4 v0 = *(const uint4*)(base + (long)s0 * 128);
      ACC_P(A0, v0);
    }
  }
  #pragma unroll
  for (int i = 0; i < 4; ++i) A0[i] = (A0[i] + A1[i]) + (A2[i] + A3[i]);

  if (nvalid) {
    float inv = 1.f / fmaxf((float)deg, 1.f);
    float r[8];
    r[0] = A0[0].x * inv; r[1] = A0[0].y * inv;
    r[2] = A0[1].x * inv; r[3] = A0[1].y * inv;
    r[4] = A0[2].x * inv; r[5] = A0[2].y * inv;
    r[6] = A0[3].x * inv; r[7] = A0[3].y * inv;
    uint4 z = *(const uint4*)&zadd[(long)node * 128 + sl * 8];
    r[0] = fmaxf(r[0] + __uint_as_float(z.x << 16), 0.f);
    r[1] = fmaxf(r[1] + __uint_as_float(z.x & 0xffff0000u), 0.f);
    r[2] = fmaxf(r[2] + __uint_as_float(z.y << 16), 0.f);
    r[3] = fmaxf(r[3] + __uint_as_float(z.y & 0xffff0000u), 0.f);
    r[4] = fmaxf(r[4] + __uint_as_float(z.z << 16), 0.f);
    r[5] = fmaxf(r[5] + __uint_as_float(z.z & 0xffff0000u), 0.f);
    r[6] = fmaxf(r[6] + __uint_as_float(z.w << 16), 0.f);
    r[7] = fmaxf(r[7] + __uint_as_float(z.w & 0xffff0000u), 0.f);
    uint4 ov;
    ov.x = (unsigned)f2bf(r[0]) | ((unsigned)f2bf(r[1]) << 16);
    ov.y = (unsigned)f2bf(r[2]) | ((unsigned)f2bf(r[3]) << 16);
    ov.z = (unsigned)f2bf(r[4]) | ((unsigned)f2bf(r[5]) << 16);
    ov.w = (unsigned)f2bf(r[6]) | ((unsigned)f2bf(r[7]) << 16);
    *(uint4*)&outp[(long)node * 128 + sl * 8] = ov;
  }
}

// ===========================================================================
// Layer-2 FUSED aggregate+GEMM: out[M][128] fp32 = [mean2 | h] @ Wt2^T + b2.
// Per block (64 nodes): stage h rows into As[:, 64:128]; gather-mean
// neighbor h rows directly into As[:, 0:64] (bf16, same 4-chain numerics as
// the old standalone aggregate -> bit-identical); then standard MFMA.
// Deletes the mean2 materialization (25.6MB round-trip) and one launch.
// ===========================================================================
__global__ __launch_bounds__(256) void gemm2_fused_kernel(
    const unsigned short* __restrict__ ZB2, const unsigned short* __restrict__ Wt,
    const float* __restrict__ bias, float* __restrict__ Y,
    const int* __restrict__ offsets, const int* __restrict__ src_sorted,
    int M) {
  __shared__ unsigned short As[64 * 136];
  __shared__ int sidx[G2CAP];
  int node0 = blockIdx.x * 64;
  int t = threadIdx.x;

  int blkbeg = offsets[node0];
  int blkend = offsets[min(node0 + 64, M)];
  int cnt = blkend - blkbeg;
  bool staged = (cnt <= G2CAP);
  if (staged) {
    for (int i = t; i < cnt; i += 256) sidx[i] = src_sorted[blkbeg + i];
  }
  // stage h rows: As[row][64:128] <- ZB2[node][64:128]  (512 x 16B chunks)
  #pragma unroll
  for (int i = 0; i < 2; ++i) {
    int c = t + i * 256;
    int row = c >> 3, c8 = (c & 7) * 8;
    uint4 v = make_uint4(0u, 0u, 0u, 0u);
    if (node0 + row < M)
      v = *(const uint4*)&ZB2[(long)(node0 + row) * 128 + 64 + c8];
    *(uint4*)&As[row * 136 + 64 + c8] = v;
  }
  __syncthreads();

  // gather-mean phase: 32 groups x 8 lanes; group handles rows {gid, gid+32}
  {
    int gid = t >> 3;
    int sl = t & 7;
    const unsigned short* base = ZB2 + 64 + sl * 8;   // h half, 256B row stride
    #pragma unroll
    for (int half = 0; half < 2; ++half) {
      int row = gid + half * 32;
      int node = node0 + row;
      int beg = 0, end = 0;
      if (node < M) { beg = offsets[node]; end = offsets[node + 1]; }
      int deg = end - beg;
      floatx2 A0[4], A1[4], A2[4], A3[4];
      #pragma unroll
      for (int i = 0; i < 4; ++i) {
        A0[i] = (floatx2){0.f, 0.f}; A1[i] = (floatx2){0.f, 0.f};
        A2[i] = (floatx2){0.f, 0.f}; A3[i] = (floatx2){0.f, 0.f};
      }
      if (staged) {
        int lb = beg - blkbeg;
        int e = 0;
        for (; e + 4 <= deg; e += 4) {
          int s0 = sidx[lb + e];
          int s1 = sidx[lb + e + 1];
          int s2 = sidx[lb + e + 2];
          int s3 = sidx[lb + e + 3];
          uint4 v0 = *(const uint4*)(base + (long)s0 * 128);
          uint4 v1 = *(const uint4*)(base + (long)s1 * 128);
          uint4 v2 = *(const uint4*)(base + (long)s2 * 128);
          uint4 v3 = *(const uint4*)(base + (long)s3 * 128);
          ACC_P(A0, v0); ACC_P(A1, v1); ACC_P(A2, v2); ACC_P(A3, v3);
        }
        for (; e < deg; ++e) {
          int s0 = sidx[lb + e];
          uint4 v0 = *(const uint4*)(base + (long)s0 * 128);
          ACC_P(A0, v0);
        }
      } else {
        for (int e = beg; e < end; ++e) {
          int s0 = src_sorted[e];
          uint4 v0 = *(const uint4*)(base + (long)s0 * 128);
          ACC_P(A0, v0);
        }
      }
      #pragma unroll
      for (int i = 0; i < 4; ++i) A0[i] = (A0[i] + A1[i]) + (A2[i] + A3[i]);
      float inv = 1.f / fmaxf((float)deg, 1.f);
      ushort4 o;
      o.x = f2bf(A0[0].x * inv); o.y = f2bf(A0[0].y * inv);
      o.z = f2bf(A0[1].x * inv); o.w = f2bf(A0[1].y * inv);
      ushort4 o2;
      o2.x = f2bf(A0[2].x * inv); o2.y = f2bf(A0[2].y * inv);
      o2.z = f2bf(A0[3].x * inv); o2.w = f2bf(A0[3].y * inv);
      *(ushort4*)&As[row * 136 + sl * 8] = make_ushort4(o.x, o.y, o.z, o.w);
      *(ushort4*)&As[row * 136 + sl * 8 + 4] = o2;
    }
  }
  __syncthreads();

  // MFMA: identical to layer-1 structure
  int w = t >> 6, lane = t & 63;
  int m = lane & 15, q = lane >> 4;
  int col0 = w * 32;
  floatx4 acc[4][2];
  #pragma unroll
  for (int rt = 0; rt < 4; ++rt)
    #pragma unroll
    for (int ct = 0; ct < 2; ++ct) acc[rt][ct] = (floatx4){0.f, 0.f, 0.f, 0.f};

  #pragma unroll
  for (int ks = 0; ks < 4; ++ks) {
    bf16x8 b0 = *(const bf16x8*)&Wt[(col0 + m) * 128 + ks * 32 + q * 8];
    bf16x8 b1 = *(const bf16x8*)&Wt[(col0 + 16 + m) * 128 + ks * 32 + q * 8];
    #pragma unroll
    for (int rt = 0; rt < 4; ++rt) {
      bf16x8 a = *(const bf16x8*)&As[(rt * 16 + m) * 136 + ks * 32 + q * 8];
      acc[rt][0] = __builtin_amdgcn_mfma_f32_16x16x32_bf16(a, b0, acc[rt][0], 0, 0, 0);
      acc[rt][1] = __builtin_amdgcn_mfma_f32_16x16x32_bf16(a, b1, acc[rt][1], 0, 0, 0);
    }
  }
  #pragma unroll
  for (int ct = 0; ct < 2; ++ct) {
    int col = col0 + ct * 16 + m;
    float bv = bias[col];
    #pragma unroll
    for (int rt = 0; rt < 4; ++rt) {
      #pragma unroll
      for (int i = 0; i < 4; ++i) {
        int row = node0 + rt * 16 + q * 4 + i;
        if (row >= M) continue;
        Y[(long)row * 128 + col] = acc[rt][ct][i] + bv;
      }
    }
  }
}
#undef ACC_P

extern "C" void kernel_launch(void* const* d_in, const int* in_sizes, int n_in,
                              void* d_out, int out_size, void* d_ws, size_t ws_size,
                              hipStream_t stream) {
  const float* x    = (const float*)d_in[0];
  const int*   ei   = (const int*)d_in[1];
  const float* w1_l = (const float*)d_in[2];
  const float* b1   = (const float*)d_in[3];
  const float* w1_r = (const float*)d_in[4];
  const float* w2_l = (const float*)d_in[5];
  const float* b2   = (const float*)d_in[6];
  const float* w2_r = (const float*)d_in[7];
  float* out = (float*)d_out;

  const int E = in_sizes[1] / 2;
  const int* src = ei;
  const int* dst = ei + E;

  // ---- workspace layout (~70.9 MB) ----
  unsigned short* ZB1 = (unsigned short*)d_ws;          // [N][128] bf16: y1|z1
  unsigned short* ZB2 = ZB1 + (long)N_NODES * 128;      // [N][128] bf16: -|h
  unsigned short* Wt1 = ZB2 + (long)N_NODES * 128;      // 128x128 bf16
  unsigned short* Wt2 = Wt1 + 16384;                    // 128x128 bf16
  int* bucket_cursor = (int*)(Wt2 + 16384);             // 782 (counts after partition)
  int* bucket_base   = bucket_cursor + NBUCK;           // 784 (padded even)
  int* offsets       = bucket_base + NBUCK + 2;         // N+2 (even)
  int* src_sorted    = offsets + N_NODES + 2;           // E (even)
  unsigned* pairs    = (unsigned*)(src_sorted + E);     // NBUCK*SLAB packed 4B (12.8MB)

  // ---- CSR build: partition (slab) -> scan -> csr.  No count pre-pass. ----
  hipMemsetAsync(bucket_cursor, 0, (size_t)NBUCK * sizeof(int), stream);
  bucket_partition_kernel<<<(E + P1TILE - 1) / P1TILE, 256, 0, stream>>>(
      src, dst, bucket_cursor, pairs, E);
  bucket_scan_kernel<<<1, 256, 0, stream>>>(bucket_cursor, bucket_base);
  bucket_csr_kernel<<<NBUCK, 256, 0, stream>>>(pairs, bucket_cursor,
                                               bucket_base, offsets,
                                               src_sorted, N_NODES, E);

  // ---- weights prep ----
  prep_weights_kernel<<<128, 128, 0, stream>>>(w1_l, w1_r, w2_l, w2_r, Wt1, Wt2);

  int gemm_blocks = (N_NODES + 63) / 64;
  int agg_blocks = (N_NODES + 31) / 32;   // 8 nodes/wave, 4 waves/block

  // ---- Layer 1: ZB1 = [x@w1_l | x@w1_r + b1] (bf16), fused fp32->bf16 ----
  mfma_gemm1_kernel<<<gemm_blocks, 256, 0, stream>>>(x, Wt1, b1, ZB1, N_NODES);
  // h = relu(mean(y1) + z1) -> ZB2[:,64:128]
  aggregate_bf16_kernel<<<agg_blocks, 256, 0, stream>>>(
      ZB1, ZB1 + 64, ZB2 + 64, offsets, src_sorted, N_NODES);

  // ---- Layer 2 (fused): out = [mean(h) | h] @ Wt2^T + b2 ----
  gemm2_fused_kernel<<<gemm_blocks, 256, 0, stream>>>(
      ZB2, Wt2, b2, out, offsets, src_sorted, N_NODES);
}

// Round 6
// 250.803 us; speedup vs baseline: 1.2458x; 1.0398x over previous
//
#include <hip/hip_runtime.h>

#define N_NODES 100000
#define NBUCK   782      // ceil(100000/128) buckets of 128 nodes
#define P1TILE  4096     // edges per partition block (43KB LDS -> 3 blocks/CU)
#define SLAB    4096     // bucket slab capacity (avg 2048, +45 sigma)
#define AGG_CAP 512      // staged edge indices per agg wave (mean 128)

typedef __bf16 bf16x8 __attribute__((ext_vector_type(8)));
typedef float floatx4 __attribute__((ext_vector_type(4)));
typedef float floatx2 __attribute__((ext_vector_type(2)));

static __device__ __forceinline__ unsigned short f2bf(float f) {
  unsigned u = __float_as_uint(f);
  u += 0x7fff + ((u >> 16) & 1);   // round-to-nearest-even
  return (unsigned short)(u >> 16);
}

// ===========================================================================
// Step 1: partition (src,dst) pairs into per-bucket SLABS (fixed stride).
// LDS histogram + scan + reorder per tile -> contiguous runs; run base
// reserved with one global atomicAdd per (tile,bucket) on zeroed cursors.
// Packed 4B: src (17 bits) | dst&127 (bits 17..23).
// ===========================================================================
__global__ __launch_bounds__(256) void bucket_partition_kernel(
    const int* __restrict__ src, const int* __restrict__ dst,
    int* __restrict__ bucket_cursor, unsigned* __restrict__ pairs,
    int n_edges) {
  __shared__ int hist[NBUCK];
  __shared__ int scan_[NBUCK];
  __shared__ int gbase[NBUCK];
  __shared__ int tmp[256];
  __shared__ int2 sorted[P1TILE];
  int t = threadIdx.x;
  long e0 = (long)blockIdx.x * P1TILE;
  int n = (int)min((long)P1TILE, (long)n_edges - e0);

  for (int b = t; b < NBUCK; b += 256) hist[b] = 0;
  __syncthreads();
  for (int i = t; i < n; i += 256) atomicAdd(&hist[dst[e0 + i] >> 7], 1);
  __syncthreads();

  int loc[4];
  int s = 0;
  #pragma unroll
  for (int j = 0; j < 4; ++j) {
    int idx = 4 * t + j;
    loc[j] = s;
    s += (idx < NBUCK) ? hist[idx] : 0;
  }
  tmp[t] = s;
  __syncthreads();
  for (int off = 1; off < 256; off <<= 1) {
    int u = (t >= off) ? tmp[t - off] : 0;
    __syncthreads();
    tmp[t] += u;
    __syncthreads();
  }
  int excl = tmp[t] - s;
  #pragma unroll
  for (int j = 0; j < 4; ++j) {
    int idx = 4 * t + j;
    if (idx < NBUCK) scan_[idx] = excl + loc[j];
  }
  __syncthreads();

  for (int b = t; b < NBUCK; b += 256) {
    int c = hist[b];
    gbase[b] = c ? atomicAdd(&bucket_cursor[b], c) : 0;   // slab-local base
    hist[b] = scan_[b];
  }
  __syncthreads();

  for (int i = t; i < n; i += 256) {
    int sv = src[e0 + i];
    int dv = dst[e0 + i];
    int r = atomicAdd(&hist[dv >> 7], 1);   // LDS atomic
    sorted[r] = make_int2(sv, dv);
  }
  __syncthreads();

  for (int i = t; i < n; i += 256) {
    int2 p = sorted[i];
    int b = p.y >> 7;
    int pos = gbase[b] + (i - scan_[b]);
    if (pos < SLAB) {   // statistically never exceeded (+45 sigma)
      unsigned pk = (unsigned)p.x | ((unsigned)(p.y & 127) << 17);
      pairs[(long)b * SLAB + pos] = pk;
    }
  }
}

// ===========================================================================
// Step 2: per bucket, node-level CSR {beg,end} (absolute slab positions;
// no cross-bucket scan needed since 128 | every consumer's node range) and
// node-sorted src stream-out into the bucket's own slab.
// ===========================================================================
__global__ __launch_bounds__(256) void bucket_csr_kernel(
    const unsigned* __restrict__ pairs, const int* __restrict__ bucket_cnt,
    int2* __restrict__ offsets2, int* __restrict__ src_sorted, int n_nodes) {
  __shared__ unsigned sp[SLAB];
  __shared__ int lout[SLAB];
  __shared__ int ndeg[128];
  __shared__ int nsc[128];
  int b = blockIdx.x;
  int node0 = b << 7;
  int t = threadIdx.x;
  long sbeg = (long)b * SLAB;          // slab base (read and write)
  int m = min(bucket_cnt[b], SLAB);    // always fits LDS (SLAB entries)
  if (t < 128) ndeg[t] = 0;
  __syncthreads();

  for (int i = t; i < m; i += 256) {
    unsigned p = pairs[sbeg + i];
    sp[i] = p;
    atomicAdd(&ndeg[p >> 17], 1);   // LDS atomic
  }
  __syncthreads();

  // exclusive scan of 128 node degrees
  if (t < 128) nsc[t] = ndeg[t];
  __syncthreads();
  for (int off = 1; off < 128; off <<= 1) {
    int u = 0;
    if (t < 128 && t >= off) u = nsc[t - off];
    __syncthreads();
    if (t < 128) nsc[t] += u;
    __syncthreads();
  }
  if (t < 128) {
    int excl = nsc[t] - ndeg[t];
    int node = node0 + t;
    if (node < n_nodes)
      offsets2[node] = make_int2((int)sbeg + excl, (int)sbeg + nsc[t]);
    ndeg[t] = excl;   // repurpose as placement cursor
  }
  __syncthreads();

  // place src values grouped by node, stream out coalesced
  for (int i = t; i < m; i += 256) {
    unsigned p = sp[i];
    int r = atomicAdd(&ndeg[p >> 17], 1);  // LDS atomic
    lout[r] = (int)(p & 0x1FFFFu);
  }
  __syncthreads();
  for (int i = t; i < m; i += 256) src_sorted[sbeg + i] = lout[i];
}

// Transposed bf16 weights, n-major [128 n][128 k]:
//   Wt1[n][k] = n<64 ? w1_l[k][n] : w1_r[k][n-64]     (layer-1, K = in_dim)
//   Wt2[n][k] = k<64 ? w2_l[k][n] : w2_r[k-64][n]     (layer-2, K = [mean2|h])
__global__ __launch_bounds__(128) void prep_weights_kernel(
    const float* __restrict__ w1_l, const float* __restrict__ w1_r,
    const float* __restrict__ w2_l, const float* __restrict__ w2_r,
    unsigned short* __restrict__ Wt1, unsigned short* __restrict__ Wt2) {
  int n = blockIdx.x, k = threadIdx.x;
  float v1 = (n < 64) ? w1_l[k * 64 + n] : w1_r[k * 64 + (n - 64)];
  Wt1[n * 128 + k] = f2bf(v1);
  float v2 = (k < 64) ? w2_l[k * 128 + n] : w2_r[(k - 64) * 128 + n];
  Wt2[n * 128 + k] = f2bf(v2);
}

// ===========================================================================
// MFMA GEMM: Y[M][128] = A[M][128] @ Wt^T (+bias), fp32 accum.
// A_F32: A is fp32 in global, converted to bf16 while staging into LDS.
// Block: 256 thr = 4 waves, tile 64 rows x 128 cols; wave w owns cols
// [32w,32w+32).  A tile in LDS (row pad 128->136 bf16: 2-way alias = free).
// BIAS_MODE: 1 = bias[col-64] for col>=64 only (layer 1), 2 = bias[col].
// ===========================================================================
template <int BIAS_MODE, bool OUT_BF16, bool A_F32>
__global__ __launch_bounds__(256) void mfma_gemm_kernel(
    const void* __restrict__ Av, const unsigned short* __restrict__ Wt,
    const float* __restrict__ bias, void* __restrict__ Y, int M) {
  __shared__ unsigned short As[64 * 136];
  int node0 = blockIdx.x * 64;
  int t = threadIdx.x;
  if (A_F32) {
    const float* A = (const float*)Av;
    #pragma unroll
    for (int i = 0; i < 8; ++i) {
      int c = t + i * 256;           // 2048 x 16B fp32 chunks (4 floats)
      int row = c >> 5, c4 = (c & 31) * 4;
      float4 v = make_float4(0.f, 0.f, 0.f, 0.f);
      if (node0 + row < M) v = *(const float4*)&A[(long)(node0 + row) * 128 + c4];
      ushort4 o;
      o.x = f2bf(v.x); o.y = f2bf(v.y); o.z = f2bf(v.z); o.w = f2bf(v.w);
      *(ushort4*)&As[row * 136 + c4] = o;
    }
  } else {
    const unsigned short* A = (const unsigned short*)Av;
    #pragma unroll
    for (int i = 0; i < 4; ++i) {
      int c = t + i * 256;           // 1024 x 16B bf16 chunks
      int row = c >> 4, c8 = (c & 15) * 8;
      uint4 v = make_uint4(0u, 0u, 0u, 0u);
      if (node0 + row < M) v = *(const uint4*)&A[(long)(node0 + row) * 128 + c8];
      *(uint4*)&As[row * 136 + c8] = v;
    }
  }
  __syncthreads();
  int w = t >> 6, lane = t & 63;
  int m = lane & 15, q = lane >> 4;
  int col0 = w * 32;
  floatx4 acc[4][2];
  #pragma unroll
  for (int rt = 0; rt < 4; ++rt)
    #pragma unroll
    for (int ct = 0; ct < 2; ++ct) acc[rt][ct] = (floatx4){0.f, 0.f, 0.f, 0.f};

  #pragma unroll
  for (int ks = 0; ks < 4; ++ks) {
    bf16x8 b0 = *(const bf16x8*)&Wt[(col0 + m) * 128 + ks * 32 + q * 8];
    bf16x8 b1 = *(const bf16x8*)&Wt[(col0 + 16 + m) * 128 + ks * 32 + q * 8];
    #pragma unroll
    for (int rt = 0; rt < 4; ++rt) {
      bf16x8 a = *(const bf16x8*)&As[(rt * 16 + m) * 136 + ks * 32 + q * 8];
      acc[rt][0] = __builtin_amdgcn_mfma_f32_16x16x32_bf16(a, b0, acc[rt][0], 0, 0, 0);
      acc[rt][1] = __builtin_amdgcn_mfma_f32_16x16x32_bf16(a, b1, acc[rt][1], 0, 0, 0);
    }
  }
  // C/D layout (m89-verified): col = lane&15, row = (lane>>4)*4 + reg
  #pragma unroll
  for (int ct = 0; ct < 2; ++ct) {
    int col = col0 + ct * 16 + m;
    float bv = 0.f;
    if (BIAS_MODE == 1) bv = (col >= 64) ? bias[col - 64] : 0.f;
    if (BIAS_MODE == 2) bv = bias[col];
    #pragma unroll
    for (int rt = 0; rt < 4; ++rt) {
      #pragma unroll
      for (int i = 0; i < 4; ++i) {
        int row = node0 + rt * 16 + q * 4 + i;
        if (row >= M) continue;
        float v = acc[rt][ct][i] + bv;
        if (OUT_BF16) ((unsigned short*)Y)[(long)row * 128 + col] = f2bf(v);
        else          ((float*)Y)[(long)row * 128 + col] = v;
      }
    }
  }
}

#define ACC_P(A, v)                                                            \
  do {                                                                         \
    A[0] += (floatx2){__uint_as_float((v).x << 16),                            \
                      __uint_as_float((v).x & 0xffff0000u)};                   \
    A[1] += (floatx2){__uint_as_float((v).y << 16),                            \
                      __uint_as_float((v).y & 0xffff0000u)};                   \
    A[2] += (floatx2){__uint_as_float((v).z << 16),                            \
                      __uint_as_float((v).z & 0xffff0000u)};                   \
    A[3] += (floatx2){__uint_as_float((v).w << 16),                            \
                      __uint_as_float((v).w & 0xffff0000u)};                   \
  } while (0)

// ===========================================================================
// Gather-mean over bf16 rows (64 feats = 128 B).  8 nodes/wave, 8 lanes/node
// (sub=lane>>3), each lane owns 16B of its node's output -> no cross-lane
// reduction.  Wave's contiguous slab index range staged in LDS once; 4 named
// accumulator chains keep 4 gathers in flight (round-4 structure, verified).
// Per-node {beg,end} come from offsets2 (absolute slab positions); node
// ranges never cross a bucket boundary (128 | 8), so the range is contiguous.
// FUSE_RELU: out = relu(mean + zadd_row) (layer-1 epilogue), bf16 out.
// ===========================================================================
template <bool FUSE_RELU>
__global__ __launch_bounds__(256) void aggregate_bf16_kernel(
    const unsigned short* __restrict__ gsrc, const unsigned short* __restrict__ zadd,
    unsigned short* __restrict__ outp, const int2* __restrict__ offsets2,
    const int* __restrict__ src_sorted, int n_nodes) {
  __shared__ int stage[4 * AGG_CAP];
  int wv = threadIdx.x >> 6;             // wave in block 0..3
  int lane = threadIdx.x & 63;
  int wid = (blockIdx.x << 2) | wv;
  int node8 = wid << 3;
  int sub = lane >> 3;    // node slot 0..7
  int sl  = lane & 7;     // 16B chunk within row
  int node = node8 + sub;
  bool wvalid = (node8 < n_nodes);
  bool nvalid = wvalid && (node < n_nodes);

  int wbeg = 0, wend = 0, beg = 0, end = 0;
  if (wvalid) {
    wbeg = offsets2[node8].x;
    wend = offsets2[min(node8 + 8, n_nodes) - 1].y;
  }
  if (nvalid) {
    int2 o = offsets2[node];
    beg = o.x; end = o.y;
  }
  int deg = end - beg;
  int cnt = wend - wbeg;                 // wave-uniform
  int* my = &stage[wv * AGG_CAP];
  bool staged = wvalid && (cnt <= AGG_CAP);
  if (staged) {
    for (int i = lane; i < cnt; i += 64) my[i] = src_sorted[wbeg + i];
  }
  __syncthreads();   // executed by ALL threads (no early returns above)

  const unsigned short* base = gsrc + sl * 8;
  floatx2 A0[4], A1[4], A2[4], A3[4];
  #pragma unroll
  for (int i = 0; i < 4; ++i) {
    A0[i] = (floatx2){0.f, 0.f}; A1[i] = (floatx2){0.f, 0.f};
    A2[i] = (floatx2){0.f, 0.f}; A3[i] = (floatx2){0.f, 0.f};
  }

  if (staged) {
    int lb = beg - wbeg;                 // local base in staged indices
    int e = 0;
    for (; e + 4 <= deg; e += 4) {
      int s0 = my[lb + e];
      int s1 = my[lb + e + 1];
      int s2 = my[lb + e + 2];
      int s3 = my[lb + e + 3];
      uint4 v0 = *(const uint4*)(base + (long)s0 * 128);
      uint4 v1 = *(const uint4*)(base + (long)s1 * 128);
      uint4 v2 = *(const uint4*)(base + (long)s2 * 128);
      uint4 v3 = *(const uint4*)(base + (long)s3 * 128);
      ACC_P(A0, v0); ACC_P(A1, v1); ACC_P(A2, v2); ACC_P(A3, v3);
    }
    for (; e < deg; ++e) {
      int s0 = my[lb + e];
      uint4 v0 = *(const uint4*)(base + (long)s0 * 128);
      ACC_P(A0, v0);
    }
  } else if (nvalid) {  // overflow fallback (statistically never)
    for (int e = beg; e < end; ++e) {
      int s0 = src_sorted[e];
      uint4 v0 = *(const uint4*)(base + (long)s0 * 128);
      ACC_P(A0, v0);
    }
  }
  #pragma unroll
  for (int i = 0; i < 4; ++i) A0[i] = (A0[i] + A1[i]) + (A2[i] + A3[i]);

  if (nvalid) {
    float inv = 1.f / fmaxf((float)deg, 1.f);
    float r[8];
    r[0] = A0[0].x * inv; r[1] = A0[0].y * inv;
    r[2] = A0[1].x * inv; r[3] = A0[1].y * inv;
    r[4] = A0[2].x * inv; r[5] = A0[2].y * inv;
    r[6] = A0[3].x * inv; r[7] = A0[3].y * inv;
    if (FUSE_RELU) {
      uint4 z = *(const uint4*)&zadd[(long)node * 128 + sl * 8];
      r[0] = fmaxf(r[0] + __uint_as_float(z.x << 16), 0.f);
      r[1] = fmaxf(r[1] + __uint_as_float(z.x & 0xffff0000u), 0.f);
      r[2] = fmaxf(r[2] + __uint_as_float(z.y << 16), 0.f);
      r[3] = fmaxf(r[3] + __uint_as_float(z.y & 0xffff0000u), 0.f);
      r[4] = fmaxf(r[4] + __uint_as_float(z.z << 16), 0.f);
      r[5] = fmaxf(r[5] + __uint_as_float(z.z & 0xffff0000u), 0.f);
      r[6] = fmaxf(r[6] + __uint_as_float(z.w << 16), 0.f);
      r[7] = fmaxf(r[7] + __uint_as_float(z.w & 0xffff0000u), 0.f);
    }
    uint4 ov;
    ov.x = (unsigned)f2bf(r[0]) | ((unsigned)f2bf(r[1]) << 16);
    ov.y = (unsigned)f2bf(r[2]) | ((unsigned)f2bf(r[3]) << 16);
    ov.z = (unsigned)f2bf(r[4]) | ((unsigned)f2bf(r[5]) << 16);
    ov.w = (unsigned)f2bf(r[6]) | ((unsigned)f2bf(r[7]) << 16);
    *(uint4*)&outp[(long)node * 128 + sl * 8] = ov;
  }
}
#undef ACC_P

extern "C" void kernel_launch(void* const* d_in, const int* in_sizes, int n_in,
                              void* d_out, int out_size, void* d_ws, size_t ws_size,
                              hipStream_t stream) {
  const float* x    = (const float*)d_in[0];
  const int*   ei   = (const int*)d_in[1];
  const float* w1_l = (const float*)d_in[2];
  const float* b1   = (const float*)d_in[3];
  const float* w1_r = (const float*)d_in[4];
  const float* w2_l = (const float*)d_in[5];
  const float* b2   = (const float*)d_in[6];
  const float* w2_r = (const float*)d_in[7];
  float* out = (float*)d_out;

  const int E = in_sizes[1] / 2;
  const int* src = ei;
  const int* dst = ei + E;

  // ---- workspace layout (~65 MB) ----
  // pairs (12.8MB) aliases ZB1: dead before gemm1 writes ZB1 (stream order).
  unsigned short* ZB1 = (unsigned short*)d_ws;          // [N][128] bf16: y1|z1
  unsigned*       pairs = (unsigned*)d_ws;              // NBUCK*SLAB packed 4B
  unsigned short* ZB2 = ZB1 + (long)N_NODES * 128;      // [N][128] bf16: mean2|h
  unsigned short* Wt1 = ZB2 + (long)N_NODES * 128;      // 128x128 bf16
  unsigned short* Wt2 = Wt1 + 16384;                    // 128x128 bf16
  int* bucket_cursor = (int*)(Wt2 + 16384);             // 782 (+pad)
  int2* offsets2     = (int2*)(bucket_cursor + NBUCK + 2);  // N int2 (8B align)
  int* src_sorted    = (int*)(offsets2 + N_NODES);      // NBUCK*SLAB slab-strided

  // ---- CSR build: partition (slab) -> per-bucket csr.  No scans between. ----
  hipMemsetAsync(bucket_cursor, 0, (size_t)NBUCK * sizeof(int), stream);
  bucket_partition_kernel<<<(E + P1TILE - 1) / P1TILE, 256, 0, stream>>>(
      src, dst, bucket_cursor, pairs, E);
  bucket_csr_kernel<<<NBUCK, 256, 0, stream>>>(pairs, bucket_cursor,
                                               offsets2, src_sorted, N_NODES);

  // ---- weights prep ----
  prep_weights_kernel<<<128, 128, 0, stream>>>(w1_l, w1_r, w2_l, w2_r, Wt1, Wt2);

  int gemm_blocks = (N_NODES + 63) / 64;
  int agg_blocks = (N_NODES + 31) / 32;   // 8 nodes/wave, 4 waves/block

  // ---- Layer 1: ZB1 = [x@w1_l | x@w1_r + b1] (bf16), fused fp32->bf16 ----
  mfma_gemm_kernel<1, true, true><<<gemm_blocks, 256, 0, stream>>>(
      x, Wt1, b1, ZB1, N_NODES);
  // h = relu(mean(y1) + z1) -> ZB2[:,64:128]
  aggregate_bf16_kernel<true><<<agg_blocks, 256, 0, stream>>>(
      ZB1, ZB1 + 64, ZB2 + 64, offsets2, src_sorted, N_NODES);

  // ---- Layer 2: mean2 -> ZB2[:,0:64]; out = [mean2|h] @ Wt2^T + b2 ----
  aggregate_bf16_kernel<false><<<agg_blocks, 256, 0, stream>>>(
      ZB2 + 64, nullptr, ZB2, offsets2, src_sorted, N_NODES);
  mfma_gemm_kernel<2, false, false><<<gemm_blocks, 256, 0, stream>>>(
      ZB2, Wt2, b2, out, N_NODES);
}

// Round 7
// 250.544 us; speedup vs baseline: 1.2471x; 1.0010x over previous
//
#include <hip/hip_runtime.h>

#define N_NODES 100000
#define NBUCK   782      // ceil(100000/128) buckets of 128 nodes
#define P1TILE  4096     // edges per partition block
#define SLAB    4096     // bucket slab capacity (avg 2048, +45 sigma)
#define AGG_CAP 512      // staged edge indices per agg wave (mean 128)

typedef __bf16 bf16x8 __attribute__((ext_vector_type(8)));
typedef float floatx4 __attribute__((ext_vector_type(4)));
typedef float floatx2 __attribute__((ext_vector_type(2)));

static __device__ __forceinline__ unsigned short f2bf(float f) {
  unsigned u = __float_as_uint(f);
  u += 0x7fff + ((u >> 16) & 1);   // round-to-nearest-even
  return (unsigned short)(u >> 16);
}

// ===========================================================================
// Step 1: partition (src,dst) pairs into per-bucket SLABS (fixed stride).
// LDS histogram + scan + reorder per tile -> contiguous runs; run base
// reserved with one global atomicAdd per (tile,bucket) on zeroed cursors.
// Packed 4B: src (17 bits) | dst&127 (bits 17..23).
// Blocks >= nb_part instead run the (tiny) weight-prep transpose: fusing it
// here deletes one launch.
// ===========================================================================
__global__ __launch_bounds__(256) void bucket_partition_kernel(
    const int* __restrict__ src, const int* __restrict__ dst,
    int* __restrict__ bucket_cursor, unsigned* __restrict__ pairs,
    int n_edges, int nb_part,
    const float* __restrict__ w1_l, const float* __restrict__ w1_r,
    const float* __restrict__ w2_l, const float* __restrict__ w2_r,
    unsigned short* __restrict__ Wt1, unsigned short* __restrict__ Wt2) {
  __shared__ int hist[NBUCK];
  __shared__ int scan_[NBUCK];
  __shared__ int gbase[NBUCK];
  __shared__ int tmp[256];
  __shared__ int2 sorted[P1TILE];
  int t = threadIdx.x;

  if ((int)blockIdx.x >= nb_part) {
    // weight-prep role: 64 blocks, 2 output rows each (n-major [128][128])
    int b2 = (int)blockIdx.x - nb_part;     // 0..63
    int n = (b2 << 1) | (t >> 7);           // 0..127
    int k = t & 127;
    float v1 = (n < 64) ? w1_l[k * 64 + n] : w1_r[k * 64 + (n - 64)];
    Wt1[n * 128 + k] = f2bf(v1);
    float v2 = (k < 64) ? w2_l[k * 128 + n] : w2_r[(k - 64) * 128 + n];
    Wt2[n * 128 + k] = f2bf(v2);
    return;
  }

  long e0 = (long)blockIdx.x * P1TILE;
  int n = (int)min((long)P1TILE, (long)n_edges - e0);

  for (int b = t; b < NBUCK; b += 256) hist[b] = 0;
  __syncthreads();
  for (int i = t; i < n; i += 256) atomicAdd(&hist[dst[e0 + i] >> 7], 1);
  __syncthreads();

  int loc[4];
  int s = 0;
  #pragma unroll
  for (int j = 0; j < 4; ++j) {
    int idx = 4 * t + j;
    loc[j] = s;
    s += (idx < NBUCK) ? hist[idx] : 0;
  }
  tmp[t] = s;
  __syncthreads();
  for (int off = 1; off < 256; off <<= 1) {
    int u = (t >= off) ? tmp[t - off] : 0;
    __syncthreads();
    tmp[t] += u;
    __syncthreads();
  }
  int excl = tmp[t] - s;
  #pragma unroll
  for (int j = 0; j < 4; ++j) {
    int idx = 4 * t + j;
    if (idx < NBUCK) scan_[idx] = excl + loc[j];
  }
  __syncthreads();

  for (int b = t; b < NBUCK; b += 256) {
    int c = hist[b];
    gbase[b] = c ? atomicAdd(&bucket_cursor[b], c) : 0;   // slab-local base
    hist[b] = scan_[b];
  }
  __syncthreads();

  for (int i = t; i < n; i += 256) {
    int sv = src[e0 + i];
    int dv = dst[e0 + i];
    int r = atomicAdd(&hist[dv >> 7], 1);   // LDS atomic
    sorted[r] = make_int2(sv, dv);
  }
  __syncthreads();

  for (int i = t; i < n; i += 256) {
    int2 p = sorted[i];
    int b = p.y >> 7;
    int pos = gbase[b] + (i - scan_[b]);
    if (pos < SLAB) {   // statistically never exceeded (+45 sigma)
      unsigned pk = (unsigned)p.x | ((unsigned)(p.y & 127) << 17);
      pairs[(long)b * SLAB + pos] = pk;
    }
  }
}

// ===========================================================================
// Step 2: per bucket, node-level CSR {beg,end} (absolute slab positions;
// no cross-bucket scan needed since 128 | every consumer's node range) and
// node-sorted src stream-out into the bucket's own slab.
// ===========================================================================
__global__ __launch_bounds__(256) void bucket_csr_kernel(
    const unsigned* __restrict__ pairs, const int* __restrict__ bucket_cnt,
    int2* __restrict__ offsets2, int* __restrict__ src_sorted, int n_nodes) {
  __shared__ unsigned sp[SLAB];
  __shared__ int lout[SLAB];
  __shared__ int ndeg[128];
  __shared__ int nsc[128];
  int b = blockIdx.x;
  int node0 = b << 7;
  int t = threadIdx.x;
  long sbeg = (long)b * SLAB;          // slab base (read and write)
  int m = min(bucket_cnt[b], SLAB);    // always fits LDS (SLAB entries)
  if (t < 128) ndeg[t] = 0;
  __syncthreads();

  for (int i = t; i < m; i += 256) {
    unsigned p = pairs[sbeg + i];
    sp[i] = p;
    atomicAdd(&ndeg[p >> 17], 1);   // LDS atomic
  }
  __syncthreads();

  // exclusive scan of 128 node degrees
  if (t < 128) nsc[t] = ndeg[t];
  __syncthreads();
  for (int off = 1; off < 128; off <<= 1) {
    int u = 0;
    if (t < 128 && t >= off) u = nsc[t - off];
    __syncthreads();
    if (t < 128) nsc[t] += u;
    __syncthreads();
  }
  if (t < 128) {
    int excl = nsc[t] - ndeg[t];
    int node = node0 + t;
    if (node < n_nodes)
      offsets2[node] = make_int2((int)sbeg + excl, (int)sbeg + nsc[t]);
    ndeg[t] = excl;   // repurpose as placement cursor
  }
  __syncthreads();

  // place src values grouped by node, stream out coalesced
  for (int i = t; i < m; i += 256) {
    unsigned p = sp[i];
    int r = atomicAdd(&ndeg[p >> 17], 1);  // LDS atomic
    lout[r] = (int)(p & 0x1FFFFu);
  }
  __syncthreads();
  for (int i = t; i < m; i += 256) src_sorted[sbeg + i] = lout[i];
}

// ===========================================================================
// MFMA GEMM: Y[M][128] = A[M][128] @ Wt^T (+bias), fp32 accum.
// A_F32: A is fp32 in global, converted to bf16 while staging into LDS.
// Block: 256 thr = 4 waves, tile 64 rows x 128 cols; wave w owns cols
// [32w,32w+32).  A tile in LDS (row pad 128->136 bf16: 2-way alias = free).
// BIAS_MODE: 1 = bias[col-64] for col>=64 only (layer 1), 2 = bias[col].
// ===========================================================================
template <int BIAS_MODE, bool OUT_BF16, bool A_F32>
__global__ __launch_bounds__(256) void mfma_gemm_kernel(
    const void* __restrict__ Av, const unsigned short* __restrict__ Wt,
    const float* __restrict__ bias, void* __restrict__ Y, int M) {
  __shared__ unsigned short As[64 * 136];
  int node0 = blockIdx.x * 64;
  int t = threadIdx.x;
  if (A_F32) {
    const float* A = (const float*)Av;
    #pragma unroll
    for (int i = 0; i < 8; ++i) {
      int c = t + i * 256;           // 2048 x 16B fp32 chunks (4 floats)
      int row = c >> 5, c4 = (c & 31) * 4;
      float4 v = make_float4(0.f, 0.f, 0.f, 0.f);
      if (node0 + row < M) v = *(const float4*)&A[(long)(node0 + row) * 128 + c4];
      ushort4 o;
      o.x = f2bf(v.x); o.y = f2bf(v.y); o.z = f2bf(v.z); o.w = f2bf(v.w);
      *(ushort4*)&As[row * 136 + c4] = o;
    }
  } else {
    const unsigned short* A = (const unsigned short*)Av;
    #pragma unroll
    for (int i = 0; i < 4; ++i) {
      int c = t + i * 256;           // 1024 x 16B bf16 chunks
      int row = c >> 4, c8 = (c & 15) * 8;
      uint4 v = make_uint4(0u, 0u, 0u, 0u);
      if (node0 + row < M) v = *(const uint4*)&A[(long)(node0 + row) * 128 + c8];
      *(uint4*)&As[row * 136 + c8] = v;
    }
  }
  __syncthreads();
  int w = t >> 6, lane = t & 63;
  int m = lane & 15, q = lane >> 4;
  int col0 = w * 32;
  floatx4 acc[4][2];
  #pragma unroll
  for (int rt = 0; rt < 4; ++rt)
    #pragma unroll
    for (int ct = 0; ct < 2; ++ct) acc[rt][ct] = (floatx4){0.f, 0.f, 0.f, 0.f};

  #pragma unroll
  for (int ks = 0; ks < 4; ++ks) {
    bf16x8 b0 = *(const bf16x8*)&Wt[(col0 + m) * 128 + ks * 32 + q * 8];
    bf16x8 b1 = *(const bf16x8*)&Wt[(col0 + 16 + m) * 128 + ks * 32 + q * 8];
    #pragma unroll
    for (int rt = 0; rt < 4; ++rt) {
      bf16x8 a = *(const bf16x8*)&As[(rt * 16 + m) * 136 + ks * 32 + q * 8];
      acc[rt][0] = __builtin_amdgcn_mfma_f32_16x16x32_bf16(a, b0, acc[rt][0], 0, 0, 0);
      acc[rt][1] = __builtin_amdgcn_mfma_f32_16x16x32_bf16(a, b1, acc[rt][1], 0, 0, 0);
    }
  }
  // C/D layout (m89-verified): col = lane&15, row = (lane>>4)*4 + reg
  #pragma unroll
  for (int ct = 0; ct < 2; ++ct) {
    int col = col0 + ct * 16 + m;
    float bv = 0.f;
    if (BIAS_MODE == 1) bv = (col >= 64) ? bias[col - 64] : 0.f;
    if (BIAS_MODE == 2) bv = bias[col];
    #pragma unroll
    for (int rt = 0; rt < 4; ++rt) {
      #pragma unroll
      for (int i = 0; i < 4; ++i) {
        int row = node0 + rt * 16 + q * 4 + i;
        if (row >= M) continue;
        float v = acc[rt][ct][i] + bv;
        if (OUT_BF16) ((unsigned short*)Y)[(long)row * 128 + col] = f2bf(v);
        else          ((float*)Y)[(long)row * 128 + col] = v;
      }
    }
  }
}

#define ACC_P(A, v)                                                            \
  do {                                                                         \
    A[0] += (floatx2){__uint_as_float((v).x << 16),                            \
                      __uint_as_float((v).x & 0xffff0000u)};                   \
    A[1] += (floatx2){__uint_as_float((v).y << 16),                            \
                      __uint_as_float((v).y & 0xffff0000u)};                   \
    A[2] += (floatx2){__uint_as_float((v).z << 16),                            \
                      __uint_as_float((v).z & 0xffff0000u)};                   \
    A[3] += (floatx2){__uint_as_float((v).w << 16),                            \
                      __uint_as_float((v).w & 0xffff0000u)};                   \
  } while (0)

// ===========================================================================
// Gather-mean over bf16 rows (64 feats = 128 B).  8 nodes/wave, 8 lanes/node
// (sub=lane>>3), each lane owns 16B of its node's output -> no cross-lane
// reduction.  Wave's contiguous slab index range staged in LDS once.
//
// Round-7: 8-deep gather pipeline.  The main loop is unrolled 8-wide with 8
// NAMED uint4 registers (all loads issued before first consume), folding
// into the SAME 4 accumulator chains in the SAME order as round-6's 4-wide
// loop (chain j&3 receives e then e+4 -> bit-identical numerics).  Little's
// law at ~400cy L2/L3 latency needs ~40 loads in flight per CU; depth 8 at
// ~6 waves/SIMD supplies 48 vs round-6's 32.
//
// FUSE_RELU: out = relu(mean + zadd_row) (layer-1 epilogue), bf16 out.
// ===========================================================================
template <bool FUSE_RELU>
__global__ __launch_bounds__(256) void aggregate_bf16_kernel(
    const unsigned short* __restrict__ gsrc, const unsigned short* __restrict__ zadd,
    unsigned short* __restrict__ outp, const int2* __restrict__ offsets2,
    const int* __restrict__ src_sorted, int n_nodes) {
  __shared__ int stage[4 * AGG_CAP];
  int wv = threadIdx.x >> 6;             // wave in block 0..3
  int lane = threadIdx.x & 63;
  int wid = (blockIdx.x << 2) | wv;
  int node8 = wid << 3;
  int sub = lane >> 3;    // node slot 0..7
  int sl  = lane & 7;     // 16B chunk within row
  int node = node8 + sub;
  bool wvalid = (node8 < n_nodes);
  bool nvalid = wvalid && (node < n_nodes);

  int wbeg = 0, wend = 0, beg = 0, end = 0;
  if (wvalid) {
    wbeg = offsets2[node8].x;
    wend = offsets2[min(node8 + 8, n_nodes) - 1].y;
  }
  if (nvalid) {
    int2 o = offsets2[node];
    beg = o.x; end = o.y;
  }
  int deg = end - beg;
  int cnt = wend - wbeg;                 // wave-uniform
  int* my = &stage[wv * AGG_CAP];
  bool staged = wvalid && (cnt <= AGG_CAP);
  if (staged) {
    for (int i = lane; i < cnt; i += 64) my[i] = src_sorted[wbeg + i];
  }
  __syncthreads();   // executed by ALL threads (no early returns above)

  const unsigned short* base = gsrc + sl * 8;
  floatx2 A0[4], A1[4], A2[4], A3[4];
  #pragma unroll
  for (int i = 0; i < 4; ++i) {
    A0[i] = (floatx2){0.f, 0.f}; A1[i] = (floatx2){0.f, 0.f};
    A2[i] = (floatx2){0.f, 0.f}; A3[i] = (floatx2){0.f, 0.f};
  }

  if (staged) {
    int lb = beg - wbeg;                 // local base in staged indices
    int e = 0;
    for (; e + 8 <= deg; e += 8) {       // 8 loads in flight
      int s0 = my[lb + e];
      int s1 = my[lb + e + 1];
      int s2 = my[lb + e + 2];
      int s3 = my[lb + e + 3];
      int s4 = my[lb + e + 4];
      int s5 = my[lb + e + 5];
      int s6 = my[lb + e + 6];
      int s7 = my[lb + e + 7];
      uint4 v0 = *(const uint4*)(base + (long)s0 * 128);
      uint4 v1 = *(const uint4*)(base + (long)s1 * 128);
      uint4 v2 = *(const uint4*)(base + (long)s2 * 128);
      uint4 v3 = *(const uint4*)(base + (long)s3 * 128);
      uint4 v4 = *(const uint4*)(base + (long)s4 * 128);
      uint4 v5 = *(const uint4*)(base + (long)s5 * 128);
      uint4 v6 = *(const uint4*)(base + (long)s6 * 128);
      uint4 v7 = *(const uint4*)(base + (long)s7 * 128);
      ACC_P(A0, v0); ACC_P(A1, v1); ACC_P(A2, v2); ACC_P(A3, v3);
      ACC_P(A0, v4); ACC_P(A1, v5); ACC_P(A2, v6); ACC_P(A3, v7);
    }
    if (e + 4 <= deg) {
      int s0 = my[lb + e];
      int s1 = my[lb + e + 1];
      int s2 = my[lb + e + 2];
      int s3 = my[lb + e + 3];
      uint4 v0 = *(const uint4*)(base + (long)s0 * 128);
      uint4 v1 = *(const uint4*)(base + (long)s1 * 128);
      uint4 v2 = *(const uint4*)(base + (long)s2 * 128);
      uint4 v3 = *(const uint4*)(base + (long)s3 * 128);
      ACC_P(A0, v0); ACC_P(A1, v1); ACC_P(A2, v2); ACC_P(A3, v3);
      e += 4;
    }
    for (; e < deg; ++e) {
      int s0 = my[lb + e];
      uint4 v0 = *(const uint4*)(base + (long)s0 * 128);
      ACC_P(A0, v0);
    }
  } else if (nvalid) {  // overflow fallback (statistically never)
    for (int e = beg; e < end; ++e) {
      int s0 = src_sorted[e];
      uint4 v0 = *(const uint4*)(base + (long)s0 * 128);
      ACC_P(A0, v0);
    }
  }
  #pragma unroll
  for (int i = 0; i < 4; ++i) A0[i] = (A0[i] + A1[i]) + (A2[i] + A3[i]);

  if (nvalid) {
    float inv = 1.f / fmaxf((float)deg, 1.f);
    float r[8];
    r[0] = A0[0].x * inv; r[1] = A0[0].y * inv;
    r[2] = A0[1].x * inv; r[3] = A0[1].y * inv;
    r[4] = A0[2].x * inv; r[5] = A0[2].y * inv;
    r[6] = A0[3].x * inv; r[7] = A0[3].y * inv;
    if (FUSE_RELU) {
      uint4 z = *(const uint4*)&zadd[(long)node * 128 + sl * 8];
      r[0] = fmaxf(r[0] + __uint_as_float(z.x << 16), 0.f);
      r[1] = fmaxf(r[1] + __uint_as_float(z.x & 0xffff0000u), 0.f);
      r[2] = fmaxf(r[2] + __uint_as_float(z.y << 16), 0.f);
      r[3] = fmaxf(r[3] + __uint_as_float(z.y & 0xffff0000u), 0.f);
      r[4] = fmaxf(r[4] + __uint_as_float(z.z << 16), 0.f);
      r[5] = fmaxf(r[5] + __uint_as_float(z.z & 0xffff0000u), 0.f);
      r[6] = fmaxf(r[6] + __uint_as_float(z.w << 16), 0.f);
      r[7] = fmaxf(r[7] + __uint_as_float(z.w & 0xffff0000u), 0.f);
    }
    uint4 ov;
    ov.x = (unsigned)f2bf(r[0]) | ((unsigned)f2bf(r[1]) << 16);
    ov.y = (unsigned)f2bf(r[2]) | ((unsigned)f2bf(r[3]) << 16);
    ov.z = (unsigned)f2bf(r[4]) | ((unsigned)f2bf(r[5]) << 16);
    ov.w = (unsigned)f2bf(r[6]) | ((unsigned)f2bf(r[7]) << 16);
    *(uint4*)&outp[(long)node * 128 + sl * 8] = ov;
  }
}
#undef ACC_P

extern "C" void kernel_launch(void* const* d_in, const int* in_sizes, int n_in,
                              void* d_out, int out_size, void* d_ws, size_t ws_size,
                              hipStream_t stream) {
  const float* x    = (const float*)d_in[0];
  const int*   ei   = (const int*)d_in[1];
  const float* w1_l = (const float*)d_in[2];
  const float* b1   = (const float*)d_in[3];
  const float* w1_r = (const float*)d_in[4];
  const float* w2_l = (const float*)d_in[5];
  const float* b2   = (const float*)d_in[6];
  const float* w2_r = (const float*)d_in[7];
  float* out = (float*)d_out;

  const int E = in_sizes[1] / 2;
  const int* src = ei;
  const int* dst = ei + E;

  // ---- workspace layout (~65 MB) ----
  // pairs (12.8MB) aliases ZB1: dead before gemm1 writes ZB1 (stream order).
  unsigned short* ZB1 = (unsigned short*)d_ws;          // [N][128] bf16: y1|z1
  unsigned*       pairs = (unsigned*)d_ws;              // NBUCK*SLAB packed 4B
  unsigned short* ZB2 = ZB1 + (long)N_NODES * 128;      // [N][128] bf16: mean2|h
  unsigned short* Wt1 = ZB2 + (long)N_NODES * 128;      // 128x128 bf16
  unsigned short* Wt2 = Wt1 + 16384;                    // 128x128 bf16
  int* bucket_cursor = (int*)(Wt2 + 16384);             // 782 (+pad)
  int2* offsets2     = (int2*)(bucket_cursor + NBUCK + 2);  // N int2 (8B align)
  int* src_sorted    = (int*)(offsets2 + N_NODES);      // NBUCK*SLAB slab-strided

  // ---- CSR build: partition (slab, + fused weight prep) -> per-bucket csr ----
  hipMemsetAsync(bucket_cursor, 0, (size_t)NBUCK * sizeof(int), stream);
  int nb_part = (E + P1TILE - 1) / P1TILE;
  bucket_partition_kernel<<<nb_part + 64, 256, 0, stream>>>(
      src, dst, bucket_cursor, pairs, E, nb_part,
      w1_l, w1_r, w2_l, w2_r, Wt1, Wt2);
  bucket_csr_kernel<<<NBUCK, 256, 0, stream>>>(pairs, bucket_cursor,
                                               offsets2, src_sorted, N_NODES);

  int gemm_blocks = (N_NODES + 63) / 64;
  int agg_blocks = (N_NODES + 31) / 32;   // 8 nodes/wave, 4 waves/block

  // ---- Layer 1: ZB1 = [x@w1_l | x@w1_r + b1] (bf16), fused fp32->bf16 ----
  mfma_gemm_kernel<1, true, true><<<gemm_blocks, 256, 0, stream>>>(
      x, Wt1, b1, ZB1, N_NODES);
  // h = relu(mean(y1) + z1) -> ZB2[:,64:128]
  aggregate_bf16_kernel<true><<<agg_blocks, 256, 0, stream>>>(
      ZB1, ZB1 + 64, ZB2 + 64, offsets2, src_sorted, N_NODES);

  // ---- Layer 2: mean2 -> ZB2[:,0:64]; out = [mean2|h] @ Wt2^T + b2 ----
  aggregate_bf16_kernel<false><<<agg_blocks, 256, 0, stream>>>(
      ZB2 + 64, nullptr, ZB2, offsets2, src_sorted, N_NODES);
  mfma_gemm_kernel<2, false, false><<<gemm_blocks, 256, 0, stream>>>(
      ZB2, Wt2, b2, out, N_NODES);
}

// Round 8
// 244.153 us; speedup vs baseline: 1.2798x; 1.0262x over previous
//
#include <hip/hip_runtime.h>

#define N_NODES 100000
#define NBUCK   782      // ceil(100000/128) buckets of 128 nodes
#define P1TILE  4096     // edges per partition block
#define SLAB    4096     // bucket slab capacity (avg 2048, +45 sigma)

typedef __bf16 bf16x8 __attribute__((ext_vector_type(8)));
typedef float floatx4 __attribute__((ext_vector_type(4)));
typedef float floatx2 __attribute__((ext_vector_type(2)));

static __device__ __forceinline__ unsigned short f2bf(float f) {
  unsigned u = __float_as_uint(f);
  u += 0x7fff + ((u >> 16) & 1);   // round-to-nearest-even
  return (unsigned short)(u >> 16);
}

// ===========================================================================
// Step 1: partition (src,dst) pairs into per-bucket SLABS (fixed stride).
// 512 threads (round-8): the per-block serial phases (hist, scan, rank) are
// thread-parallelism-bound, not memory-bound -- 2x issue width through them.
// LDS histogram + scan + reorder per tile -> contiguous runs; run base
// reserved with one global atomicAdd per (tile,bucket) on zeroed cursors.
// Packed 4B: src (17 bits) | dst&127 (bits 17..23).
// Blocks >= nb_part run the weight-prep transpose (4 rows each, 32 blocks).
// ===========================================================================
__global__ __launch_bounds__(512) void bucket_partition_kernel(
    const int* __restrict__ src, const int* __restrict__ dst,
    int* __restrict__ bucket_cursor, unsigned* __restrict__ pairs,
    int n_edges, int nb_part,
    const float* __restrict__ w1_l, const float* __restrict__ w1_r,
    const float* __restrict__ w2_l, const float* __restrict__ w2_r,
    unsigned short* __restrict__ Wt1, unsigned short* __restrict__ Wt2) {
  __shared__ int hist[NBUCK];
  __shared__ int scan_[NBUCK];
  __shared__ int gbase[NBUCK];
  __shared__ int tmp[512];
  __shared__ int2 sorted[P1TILE];
  int t = threadIdx.x;

  if ((int)blockIdx.x >= nb_part) {
    // weight-prep role: 32 blocks, 4 output rows each (n-major [128][128])
    int b2 = (int)blockIdx.x - nb_part;     // 0..31
    int n = (b2 << 2) | (t >> 7);           // 0..127
    int k = t & 127;
    float v1 = (n < 64) ? w1_l[k * 64 + n] : w1_r[k * 64 + (n - 64)];
    Wt1[n * 128 + k] = f2bf(v1);
    float v2 = (k < 64) ? w2_l[k * 128 + n] : w2_r[(k - 64) * 128 + n];
    Wt2[n * 128 + k] = f2bf(v2);
    return;
  }

  long e0 = (long)blockIdx.x * P1TILE;
  int n = (int)min((long)P1TILE, (long)n_edges - e0);

  for (int b = t; b < NBUCK; b += 512) hist[b] = 0;
  __syncthreads();
  for (int i = t; i < n; i += 512) atomicAdd(&hist[dst[e0 + i] >> 7], 1);
  __syncthreads();

  // exclusive scan of 782 bucket counts: 512 threads x 2 buckets each
  int loc[2];
  int s = 0;
  #pragma unroll
  for (int j = 0; j < 2; ++j) {
    int idx = 2 * t + j;
    loc[j] = s;
    s += (idx < NBUCK) ? hist[idx] : 0;
  }
  tmp[t] = s;
  __syncthreads();
  for (int off = 1; off < 512; off <<= 1) {
    int u = (t >= off) ? tmp[t - off] : 0;
    __syncthreads();
    tmp[t] += u;
    __syncthreads();
  }
  int excl = tmp[t] - s;
  #pragma unroll
  for (int j = 0; j < 2; ++j) {
    int idx = 2 * t + j;
    if (idx < NBUCK) scan_[idx] = excl + loc[j];
  }
  __syncthreads();

  for (int b = t; b < NBUCK; b += 512) {
    int c = hist[b];
    gbase[b] = c ? atomicAdd(&bucket_cursor[b], c) : 0;   // slab-local base
    hist[b] = scan_[b];
  }
  __syncthreads();

  for (int i = t; i < n; i += 512) {
    int sv = src[e0 + i];
    int dv = dst[e0 + i];
    int r = atomicAdd(&hist[dv >> 7], 1);   // LDS atomic
    sorted[r] = make_int2(sv, dv);
  }
  __syncthreads();

  for (int i = t; i < n; i += 512) {
    int2 p = sorted[i];
    int b = p.y >> 7;
    int pos = gbase[b] + (i - scan_[b]);
    if (pos < SLAB) {   // statistically never exceeded (+45 sigma)
      unsigned pk = (unsigned)p.x | ((unsigned)(p.y & 127) << 17);
      pairs[(long)b * SLAB + pos] = pk;
    }
  }
}

// ===========================================================================
// Step 2: per bucket, node-level CSR {beg,end} (absolute slab positions) and
// node-sorted src stream-out into the bucket's own slab.  512 threads
// (round-8): histogram/rank LDS-atomic phases get 2x issue width.
// ===========================================================================
__global__ __launch_bounds__(512) void bucket_csr_kernel(
    const unsigned* __restrict__ pairs, const int* __restrict__ bucket_cnt,
    int2* __restrict__ offsets2, int* __restrict__ src_sorted, int n_nodes) {
  __shared__ unsigned sp[SLAB];
  __shared__ int lout[SLAB];
  __shared__ int ndeg[128];
  __shared__ int nsc[128];
  int b = blockIdx.x;
  int node0 = b << 7;
  int t = threadIdx.x;
  long sbeg = (long)b * SLAB;          // slab base (read and write)
  int m = min(bucket_cnt[b], SLAB);    // always fits LDS (SLAB entries)
  if (t < 128) ndeg[t] = 0;
  __syncthreads();

  for (int i = t; i < m; i += 512) {
    unsigned p = pairs[sbeg + i];
    sp[i] = p;
    atomicAdd(&ndeg[p >> 17], 1);   // LDS atomic
  }
  __syncthreads();

  // exclusive scan of 128 node degrees
  if (t < 128) nsc[t] = ndeg[t];
  __syncthreads();
  for (int off = 1; off < 128; off <<= 1) {
    int u = 0;
    if (t < 128 && t >= off) u = nsc[t - off];
    __syncthreads();
    if (t < 128) nsc[t] += u;
    __syncthreads();
  }
  if (t < 128) {
    int excl = nsc[t] - ndeg[t];
    int node = node0 + t;
    if (node < n_nodes)
      offsets2[node] = make_int2((int)sbeg + excl, (int)sbeg + nsc[t]);
    ndeg[t] = excl;   // repurpose as placement cursor
  }
  __syncthreads();

  // place src values grouped by node, stream out coalesced
  for (int i = t; i < m; i += 512) {
    unsigned p = sp[i];
    int r = atomicAdd(&ndeg[p >> 17], 1);  // LDS atomic
    lout[r] = (int)(p & 0x1FFFFu);
  }
  __syncthreads();
  for (int i = t; i < m; i += 512) src_sorted[sbeg + i] = lout[i];
}

// ===========================================================================
// MFMA GEMM: Y[M][128] = A[M][128] @ Wt^T (+bias), fp32 accum.
// A_F32: A is fp32 in global, converted to bf16 while staging into LDS.
// Block: 256 thr = 4 waves, tile 64 rows x 128 cols; wave w owns cols
// [32w,32w+32).  A tile in LDS (row pad 128->136 bf16: 2-way alias = free).
// BIAS_MODE: 1 = bias[col-64] for col>=64 only (layer 1), 2 = bias[col].
// ===========================================================================
template <int BIAS_MODE, bool OUT_BF16, bool A_F32>
__global__ __launch_bounds__(256) void mfma_gemm_kernel(
    const void* __restrict__ Av, const unsigned short* __restrict__ Wt,
    const float* __restrict__ bias, void* __restrict__ Y, int M) {
  __shared__ unsigned short As[64 * 136];
  int node0 = blockIdx.x * 64;
  int t = threadIdx.x;
  if (A_F32) {
    const float* A = (const float*)Av;
    #pragma unroll
    for (int i = 0; i < 8; ++i) {
      int c = t + i * 256;           // 2048 x 16B fp32 chunks (4 floats)
      int row = c >> 5, c4 = (c & 31) * 4;
      float4 v = make_float4(0.f, 0.f, 0.f, 0.f);
      if (node0 + row < M) v = *(const float4*)&A[(long)(node0 + row) * 128 + c4];
      ushort4 o;
      o.x = f2bf(v.x); o.y = f2bf(v.y); o.z = f2bf(v.z); o.w = f2bf(v.w);
      *(ushort4*)&As[row * 136 + c4] = o;
    }
  } else {
    const unsigned short* A = (const unsigned short*)Av;
    #pragma unroll
    for (int i = 0; i < 4; ++i) {
      int c = t + i * 256;           // 1024 x 16B bf16 chunks
      int row = c >> 4, c8 = (c & 15) * 8;
      uint4 v = make_uint4(0u, 0u, 0u, 0u);
      if (node0 + row < M) v = *(const uint4*)&A[(long)(node0 + row) * 128 + c8];
      *(uint4*)&As[row * 136 + c8] = v;
    }
  }
  __syncthreads();
  int w = t >> 6, lane = t & 63;
  int m = lane & 15, q = lane >> 4;
  int col0 = w * 32;
  floatx4 acc[4][2];
  #pragma unroll
  for (int rt = 0; rt < 4; ++rt)
    #pragma unroll
    for (int ct = 0; ct < 2; ++ct) acc[rt][ct] = (floatx4){0.f, 0.f, 0.f, 0.f};

  #pragma unroll
  for (int ks = 0; ks < 4; ++ks) {
    bf16x8 b0 = *(const bf16x8*)&Wt[(col0 + m) * 128 + ks * 32 + q * 8];
    bf16x8 b1 = *(const bf16x8*)&Wt[(col0 + 16 + m) * 128 + ks * 32 + q * 8];
    #pragma unroll
    for (int rt = 0; rt < 4; ++rt) {
      bf16x8 a = *(const bf16x8*)&As[(rt * 16 + m) * 136 + ks * 32 + q * 8];
      acc[rt][0] = __builtin_amdgcn_mfma_f32_16x16x32_bf16(a, b0, acc[rt][0], 0, 0, 0);
      acc[rt][1] = __builtin_amdgcn_mfma_f32_16x16x32_bf16(a, b1, acc[rt][1], 0, 0, 0);
    }
  }
  // C/D layout (m89-verified): col = lane&15, row = (lane>>4)*4 + reg
  #pragma unroll
  for (int ct = 0; ct < 2; ++ct) {
    int col = col0 + ct * 16 + m;
    float bv = 0.f;
    if (BIAS_MODE == 1) bv = (col >= 64) ? bias[col - 64] : 0.f;
    if (BIAS_MODE == 2) bv = bias[col];
    #pragma unroll
    for (int rt = 0; rt < 4; ++rt) {
      #pragma unroll
      for (int i = 0; i < 4; ++i) {
        int row = node0 + rt * 16 + q * 4 + i;
        if (row >= M) continue;
        float v = acc[rt][ct][i] + bv;
        if (OUT_BF16) ((unsigned short*)Y)[(long)row * 128 + col] = f2bf(v);
        else          ((float*)Y)[(long)row * 128 + col] = v;
      }
    }
  }
}

#define ACC_P(A, v)                                                            \
  do {                                                                         \
    A[0] += (floatx2){__uint_as_float((v).x << 16),                            \
                      __uint_as_float((v).x & 0xffff0000u)};                   \
    A[1] += (floatx2){__uint_as_float((v).y << 16),                            \
                      __uint_as_float((v).y & 0xffff0000u)};                   \
    A[2] += (floatx2){__uint_as_float((v).z << 16),                            \
                      __uint_as_float((v).z & 0xffff0000u)};                   \
    A[3] += (floatx2){__uint_as_float((v).w << 16),                            \
                      __uint_as_float((v).w & 0xffff0000u)};                   \
  } while (0)

// ===========================================================================
// Gather-mean over bf16 rows (64 feats = 128 B).  8 nodes/wave, 8 lanes/node
// (sub=lane>>3), each lane owns 16B of its node's output -> no cross-lane
// reduction.  Wave's contiguous slab index range staged in LDS once; 8-deep
// gather pipeline (round-7) folding into 4 accumulator chains (bit-identical
// to the 4-wide order).  At the composite memory wall (~87MB L2-miss per
// dispatch) -- kept as-is.
// FUSE_RELU: out = relu(mean + zadd_row) (layer-1 epilogue), bf16 out.
// ===========================================================================
#define AGG_CAP 512
template <bool FUSE_RELU>
__global__ __launch_bounds__(256) void aggregate_bf16_kernel(
    const unsigned short* __restrict__ gsrc, const unsigned short* __restrict__ zadd,
    unsigned short* __restrict__ outp, const int2* __restrict__ offsets2,
    const int* __restrict__ src_sorted, int n_nodes) {
  __shared__ int stage[4 * AGG_CAP];
  int wv = threadIdx.x >> 6;             // wave in block 0..3
  int lane = threadIdx.x & 63;
  int wid = (blockIdx.x << 2) | wv;
  int node8 = wid << 3;
  int sub = lane >> 3;    // node slot 0..7
  int sl  = lane & 7;     // 16B chunk within row
  int node = node8 + sub;
  bool wvalid = (node8 < n_nodes);
  bool nvalid = wvalid && (node < n_nodes);

  int wbeg = 0, wend = 0, beg = 0, end = 0;
  if (wvalid) {
    wbeg = offsets2[node8].x;
    wend = offsets2[min(node8 + 8, n_nodes) - 1].y;
  }
  if (nvalid) {
    int2 o = offsets2[node];
    beg = o.x; end = o.y;
  }
  int deg = end - beg;
  int cnt = wend - wbeg;                 // wave-uniform
  int* my = &stage[wv * AGG_CAP];
  bool staged = wvalid && (cnt <= AGG_CAP);
  if (staged) {
    for (int i = lane; i < cnt; i += 64) my[i] = src_sorted[wbeg + i];
  }
  __syncthreads();   // executed by ALL threads (no early returns above)

  const unsigned short* base = gsrc + sl * 8;
  floatx2 A0[4], A1[4], A2[4], A3[4];
  #pragma unroll
  for (int i = 0; i < 4; ++i) {
    A0[i] = (floatx2){0.f, 0.f}; A1[i] = (floatx2){0.f, 0.f};
    A2[i] = (floatx2){0.f, 0.f}; A3[i] = (floatx2){0.f, 0.f};
  }

  if (staged) {
    int lb = beg - wbeg;                 // local base in staged indices
    int e = 0;
    for (; e + 8 <= deg; e += 8) {       // 8 loads in flight
      int s0 = my[lb + e];
      int s1 = my[lb + e + 1];
      int s2 = my[lb + e + 2];
      int s3 = my[lb + e + 3];
      int s4 = my[lb + e + 4];
      int s5 = my[lb + e + 5];
      int s6 = my[lb + e + 6];
      int s7 = my[lb + e + 7];
      uint4 v0 = *(const uint4*)(base + (long)s0 * 128);
      uint4 v1 = *(const uint4*)(base + (long)s1 * 128);
      uint4 v2 = *(const uint4*)(base + (long)s2 * 128);
      uint4 v3 = *(const uint4*)(base + (long)s3 * 128);
      uint4 v4 = *(const uint4*)(base + (long)s4 * 128);
      uint4 v5 = *(const uint4*)(base + (long)s5 * 128);
      uint4 v6 = *(const uint4*)(base + (long)s6 * 128);
      uint4 v7 = *(const uint4*)(base + (long)s7 * 128);
      ACC_P(A0, v0); ACC_P(A1, v1); ACC_P(A2, v2); ACC_P(A3, v3);
      ACC_P(A0, v4); ACC_P(A1, v5); ACC_P(A2, v6); ACC_P(A3, v7);
    }
    if (e + 4 <= deg) {
      int s0 = my[lb + e];
      int s1 = my[lb + e + 1];
      int s2 = my[lb + e + 2];
      int s3 = my[lb + e + 3];
      uint4 v0 = *(const uint4*)(base + (long)s0 * 128);
      uint4 v1 = *(const uint4*)(base + (long)s1 * 128);
      uint4 v2 = *(const uint4*)(base + (long)s2 * 128);
      uint4 v3 = *(const uint4*)(base + (long)s3 * 128);
      ACC_P(A0, v0); ACC_P(A1, v1); ACC_P(A2, v2); ACC_P(A3, v3);
      e += 4;
    }
    for (; e < deg; ++e) {
      int s0 = my[lb + e];
      uint4 v0 = *(const uint4*)(base + (long)s0 * 128);
      ACC_P(A0, v0);
    }
  } else if (nvalid) {  // overflow fallback (statistically never)
    for (int e = beg; e < end; ++e) {
      int s0 = src_sorted[e];
      uint4 v0 = *(const uint4*)(base + (long)s0 * 128);
      ACC_P(A0, v0);
    }
  }
  #pragma unroll
  for (int i = 0; i < 4; ++i) A0[i] = (A0[i] + A1[i]) + (A2[i] + A3[i]);

  if (nvalid) {
    float inv = 1.f / fmaxf((float)deg, 1.f);
    float r[8];
    r[0] = A0[0].x * inv; r[1] = A0[0].y * inv;
    r[2] = A0[1].x * inv; r[3] = A0[1].y * inv;
    r[4] = A0[2].x * inv; r[5] = A0[2].y * inv;
    r[6] = A0[3].x * inv; r[7] = A0[3].y * inv;
    if (FUSE_RELU) {
      uint4 z = *(const uint4*)&zadd[(long)node * 128 + sl * 8];
      r[0] = fmaxf(r[0] + __uint_as_float(z.x << 16), 0.f);
      r[1] = fmaxf(r[1] + __uint_as_float(z.x & 0xffff0000u), 0.f);
      r[2] = fmaxf(r[2] + __uint_as_float(z.y << 16), 0.f);
      r[3] = fmaxf(r[3] + __uint_as_float(z.y & 0xffff0000u), 0.f);
      r[4] = fmaxf(r[4] + __uint_as_float(z.z << 16), 0.f);
      r[5] = fmaxf(r[5] + __uint_as_float(z.z & 0xffff0000u), 0.f);
      r[6] = fmaxf(r[6] + __uint_as_float(z.w << 16), 0.f);
      r[7] = fmaxf(r[7] + __uint_as_float(z.w & 0xffff0000u), 0.f);
    }
    uint4 ov;
    ov.x = (unsigned)f2bf(r[0]) | ((unsigned)f2bf(r[1]) << 16);
    ov.y = (unsigned)f2bf(r[2]) | ((unsigned)f2bf(r[3]) << 16);
    ov.z = (unsigned)f2bf(r[4]) | ((unsigned)f2bf(r[5]) << 16);
    ov.w = (unsigned)f2bf(r[6]) | ((unsigned)f2bf(r[7]) << 16);
    *(uint4*)&outp[(long)node * 128 + sl * 8] = ov;
  }
}
#undef ACC_P

extern "C" void kernel_launch(void* const* d_in, const int* in_sizes, int n_in,
                              void* d_out, int out_size, void* d_ws, size_t ws_size,
                              hipStream_t stream) {
  const float* x    = (const float*)d_in[0];
  const int*   ei   = (const int*)d_in[1];
  const float* w1_l = (const float*)d_in[2];
  const float* b1   = (const float*)d_in[3];
  const float* w1_r = (const float*)d_in[4];
  const float* w2_l = (const float*)d_in[5];
  const float* b2   = (const float*)d_in[6];
  const float* w2_r = (const float*)d_in[7];
  float* out = (float*)d_out;

  const int E = in_sizes[1] / 2;
  const int* src = ei;
  const int* dst = ei + E;

  // ---- workspace layout (~65 MB) ----
  // pairs (12.8MB) aliases ZB1: dead before gemm1 writes ZB1 (stream order).
  unsigned short* ZB1 = (unsigned short*)d_ws;          // [N][128] bf16: y1|z1
  unsigned*       pairs = (unsigned*)d_ws;              // NBUCK*SLAB packed 4B
  unsigned short* ZB2 = ZB1 + (long)N_NODES * 128;      // [N][128] bf16: mean2|h
  unsigned short* Wt1 = ZB2 + (long)N_NODES * 128;      // 128x128 bf16
  unsigned short* Wt2 = Wt1 + 16384;                    // 128x128 bf16
  int* bucket_cursor = (int*)(Wt2 + 16384);             // 782 (+pad)
  int2* offsets2     = (int2*)(bucket_cursor + NBUCK + 2);  // N int2 (8B align)
  int* src_sorted    = (int*)(offsets2 + N_NODES);      // NBUCK*SLAB slab-strided

  // ---- CSR build: partition (slab, + fused weight prep) -> per-bucket csr ----
  hipMemsetAsync(bucket_cursor, 0, (size_t)NBUCK * sizeof(int), stream);
  int nb_part = (E + P1TILE - 1) / P1TILE;
  bucket_partition_kernel<<<nb_part + 32, 512, 0, stream>>>(
      src, dst, bucket_cursor, pairs, E, nb_part,
      w1_l, w1_r, w2_l, w2_r, Wt1, Wt2);
  bucket_csr_kernel<<<NBUCK, 512, 0, stream>>>(pairs, bucket_cursor,
                                               offsets2, src_sorted, N_NODES);

  int gemm_blocks = (N_NODES + 63) / 64;
  int agg_blocks = (N_NODES + 31) / 32;   // 8 nodes/wave, 4 waves/block

  // ---- Layer 1: ZB1 = [x@w1_l | x@w1_r + b1] (bf16), fused fp32->bf16 ----
  mfma_gemm_kernel<1, true, true><<<gemm_blocks, 256, 0, stream>>>(
      x, Wt1, b1, ZB1, N_NODES);
  // h = relu(mean(y1) + z1) -> ZB2[:,64:128]
  aggregate_bf16_kernel<true><<<agg_blocks, 256, 0, stream>>>(
      ZB1, ZB1 + 64, ZB2 + 64, offsets2, src_sorted, N_NODES);

  // ---- Layer 2: mean2 -> ZB2[:,0:64]; out = [mean2|h] @ Wt2^T + b2 ----
  aggregate_bf16_kernel<false><<<agg_blocks, 256, 0, stream>>>(
      ZB2 + 64, nullptr, ZB2, offsets2, src_sorted, N_NODES);
  mfma_gemm_kernel<2, false, false><<<gemm_blocks, 256, 0, stream>>>(
      ZB2, Wt2, b2, out, N_NODES);
}

// Round 9
// 237.684 us; speedup vs baseline: 1.3146x; 1.0272x over previous
//
#include <hip/hip_runtime.h>

#define N_NODES 100000
#define NBUCK   782      // ceil(100000/128) buckets of 128 nodes
#define P1TILE  4096     // edges per partition block
#define SLAB    4096     // bucket slab capacity (avg 2048, +45 sigma)
#define AGG_CAP 512      // staged edge indices per agg wave (mean 128)

typedef __bf16 bf16x8 __attribute__((ext_vector_type(8)));
typedef float floatx4 __attribute__((ext_vector_type(4)));
typedef float floatx2 __attribute__((ext_vector_type(2)));

static __device__ __forceinline__ unsigned short f2bf(float f) {
  unsigned u = __float_as_uint(f);
  u += 0x7fff + ((u >> 16) & 1);   // round-to-nearest-even
  return (unsigned short)(u >> 16);
}

// ===========================================================================
// Step 0: init -- zero bucket cursors + transposed bf16 weight prep.
// Replaces hipMemsetAsync + the prep role (one launch, ~16k threads).
//   Wt1[n][k] = n<64 ? w1_l[k][n] : w1_r[k][n-64]
//   Wt2[n][k] = k<64 ? w2_l[k][n] : w2_r[k-64][n]
// ===========================================================================
__global__ __launch_bounds__(256) void init_kernel(
    int* __restrict__ bucket_cursor,
    const float* __restrict__ w1_l, const float* __restrict__ w1_r,
    const float* __restrict__ w2_l, const float* __restrict__ w2_r,
    unsigned short* __restrict__ Wt1, unsigned short* __restrict__ Wt2) {
  int gid = blockIdx.x * 256 + threadIdx.x;   // 64*256 = 16384 threads
  if (gid < NBUCK + 2) bucket_cursor[gid] = 0;
  int n = gid >> 7, k = gid & 127;            // covers all 128x128
  float v1 = (n < 64) ? w1_l[k * 64 + n] : w1_r[k * 64 + (n - 64)];
  Wt1[n * 128 + k] = f2bf(v1);
  float v2 = (k < 64) ? w2_l[k * 128 + n] : w2_r[(k - 64) * 128 + n];
  Wt2[n * 128 + k] = f2bf(v2);
}

// ===========================================================================
// Step 1 (combined): blocks < nb_part partition (src,dst) into per-bucket
// SLABS (round-8 512-thread structure, unchanged numerics); remaining 782
// blocks run layer-1 GEMM on a 128-row tile (512 thr = 8 waves; waves 0-3
// rows 0-63, waves 4-7 rows 64-127; per-row MFMA sequence identical to the
// 256-thr version -> bit-identical ZB1).  gemm1 and partition are DAG-
// independent and resource-complementary (LDS/VALU vs MFMA/HBM) -- one
// launch overlaps them.  LDS: union'd static block (44.2KB partition /
// 34.8KB gemm -> 3 blocks/CU).
// NOTE: pairs must NOT alias ZB1 here (both written concurrently).
// ===========================================================================
__global__ __launch_bounds__(512) void part_gemm1_kernel(
    const int* __restrict__ src, const int* __restrict__ dst,
    int* __restrict__ bucket_cursor, unsigned* __restrict__ pairs,
    int n_edges, int nb_part,
    const float* __restrict__ x, const unsigned short* __restrict__ Wt1,
    const float* __restrict__ b1, unsigned short* __restrict__ ZB1, int M) {
  __shared__ __align__(16) char smem[44224];
  int t = threadIdx.x;

  if ((int)blockIdx.x >= nb_part) {
    // ---------------- gemm1 role: 128-row tile ----------------
    unsigned short* As = (unsigned short*)smem;    // [128][136] bf16
    int node0 = ((int)blockIdx.x - nb_part) * 128;
    #pragma unroll
    for (int i = 0; i < 8; ++i) {
      int c = t + i * 512;           // 4096 x 16B fp32 chunks (4 floats)
      int row = c >> 5, c4 = (c & 31) * 4;
      float4 v = make_float4(0.f, 0.f, 0.f, 0.f);
      if (node0 + row < M) v = *(const float4*)&x[(long)(node0 + row) * 128 + c4];
      ushort4 o;
      o.x = f2bf(v.x); o.y = f2bf(v.y); o.z = f2bf(v.z); o.w = f2bf(v.w);
      *(ushort4*)&As[row * 136 + c4] = o;
    }
    __syncthreads();
    int w8 = t >> 6, lane = t & 63;
    int m = lane & 15, q = lane >> 4;
    int w = w8 & 3, half = w8 >> 2;
    int col0 = w * 32, rowbase = half * 64;
    floatx4 acc[4][2];
    #pragma unroll
    for (int rt = 0; rt < 4; ++rt)
      #pragma unroll
      for (int ct = 0; ct < 2; ++ct) acc[rt][ct] = (floatx4){0.f, 0.f, 0.f, 0.f};
    #pragma unroll
    for (int ks = 0; ks < 4; ++ks) {
      bf16x8 b0 = *(const bf16x8*)&Wt1[(col0 + m) * 128 + ks * 32 + q * 8];
      bf16x8 bb = *(const bf16x8*)&Wt1[(col0 + 16 + m) * 128 + ks * 32 + q * 8];
      #pragma unroll
      for (int rt = 0; rt < 4; ++rt) {
        bf16x8 a = *(const bf16x8*)&As[(rowbase + rt * 16 + m) * 136 + ks * 32 + q * 8];
        acc[rt][0] = __builtin_amdgcn_mfma_f32_16x16x32_bf16(a, b0, acc[rt][0], 0, 0, 0);
        acc[rt][1] = __builtin_amdgcn_mfma_f32_16x16x32_bf16(a, bb, acc[rt][1], 0, 0, 0);
      }
    }
    // C/D layout: col = lane&15, row = (lane>>4)*4 + reg
    #pragma unroll
    for (int ct = 0; ct < 2; ++ct) {
      int col = col0 + ct * 16 + m;
      float bv = (col >= 64) ? b1[col - 64] : 0.f;
      #pragma unroll
      for (int rt = 0; rt < 4; ++rt) {
        #pragma unroll
        for (int i = 0; i < 4; ++i) {
          int row = node0 + rowbase + rt * 16 + q * 4 + i;
          if (row >= M) continue;
          ZB1[(long)row * 128 + col] = f2bf(acc[rt][ct][i] + bv);
        }
      }
    }
    return;
  }

  // ---------------- partition role (round-8 structure) ----------------
  int2* sorted = (int2*)smem;                         // 4096 * 8B
  int* hist  = (int*)(smem + 32768);                  // 782
  int* scan_ = hist + NBUCK;                          // 782
  int* gbase = scan_ + NBUCK;                         // 782
  int* tmp   = gbase + NBUCK;                         // 512
  long e0 = (long)blockIdx.x * P1TILE;
  int n = (int)min((long)P1TILE, (long)n_edges - e0);

  for (int b = t; b < NBUCK; b += 512) hist[b] = 0;
  __syncthreads();
  for (int i = t; i < n; i += 512) atomicAdd(&hist[dst[e0 + i] >> 7], 1);
  __syncthreads();

  int loc[2];
  int s = 0;
  #pragma unroll
  for (int j = 0; j < 2; ++j) {
    int idx = 2 * t + j;
    loc[j] = s;
    s += (idx < NBUCK) ? hist[idx] : 0;
  }
  tmp[t] = s;
  __syncthreads();
  for (int off = 1; off < 512; off <<= 1) {
    int u = (t >= off) ? tmp[t - off] : 0;
    __syncthreads();
    tmp[t] += u;
    __syncthreads();
  }
  int excl = tmp[t] - s;
  #pragma unroll
  for (int j = 0; j < 2; ++j) {
    int idx = 2 * t + j;
    if (idx < NBUCK) scan_[idx] = excl + loc[j];
  }
  __syncthreads();

  for (int b = t; b < NBUCK; b += 512) {
    int c = hist[b];
    gbase[b] = c ? atomicAdd(&bucket_cursor[b], c) : 0;   // slab-local base
    hist[b] = scan_[b];
  }
  __syncthreads();

  for (int i = t; i < n; i += 512) {
    int sv = src[e0 + i];
    int dv = dst[e0 + i];
    int r = atomicAdd(&hist[dv >> 7], 1);   // LDS atomic
    sorted[r] = make_int2(sv, dv);
  }
  __syncthreads();

  for (int i = t; i < n; i += 512) {
    int2 p = sorted[i];
    int b = p.y >> 7;
    int pos = gbase[b] + (i - scan_[b]);
    if (pos < SLAB) {   // statistically never exceeded (+45 sigma)
      unsigned pk = (unsigned)p.x | ((unsigned)(p.y & 127) << 17);
      pairs[(long)b * SLAB + pos] = pk;
    }
  }
}

// ===========================================================================
// Step 2: per bucket, node-level CSR {beg,end} (absolute slab positions) and
// node-sorted src stream-out into the bucket's own slab (512 threads).
// ===========================================================================
__global__ __launch_bounds__(512) void bucket_csr_kernel(
    const unsigned* __restrict__ pairs, const int* __restrict__ bucket_cnt,
    int2* __restrict__ offsets2, int* __restrict__ src_sorted, int n_nodes) {
  __shared__ unsigned sp[SLAB];
  __shared__ int lout[SLAB];
  __shared__ int ndeg[128];
  __shared__ int nsc[128];
  int b = blockIdx.x;
  int node0 = b << 7;
  int t = threadIdx.x;
  long sbeg = (long)b * SLAB;          // slab base (read and write)
  int m = min(bucket_cnt[b], SLAB);    // always fits LDS (SLAB entries)
  if (t < 128) ndeg[t] = 0;
  __syncthreads();

  for (int i = t; i < m; i += 512) {
    unsigned p = pairs[sbeg + i];
    sp[i] = p;
    atomicAdd(&ndeg[p >> 17], 1);   // LDS atomic
  }
  __syncthreads();

  // exclusive scan of 128 node degrees
  if (t < 128) nsc[t] = ndeg[t];
  __syncthreads();
  for (int off = 1; off < 128; off <<= 1) {
    int u = 0;
    if (t < 128 && t >= off) u = nsc[t - off];
    __syncthreads();
    if (t < 128) nsc[t] += u;
    __syncthreads();
  }
  if (t < 128) {
    int excl = nsc[t] - ndeg[t];
    int node = node0 + t;
    if (node < n_nodes)
      offsets2[node] = make_int2((int)sbeg + excl, (int)sbeg + nsc[t]);
    ndeg[t] = excl;   // repurpose as placement cursor
  }
  __syncthreads();

  // place src values grouped by node, stream out coalesced
  for (int i = t; i < m; i += 512) {
    unsigned p = sp[i];
    int r = atomicAdd(&ndeg[p >> 17], 1);  // LDS atomic
    lout[r] = (int)(p & 0x1FFFFu);
  }
  __syncthreads();
  for (int i = t; i < m; i += 512) src_sorted[sbeg + i] = lout[i];
}

// ===========================================================================
// MFMA GEMM (layer 2): Y[M][128] fp32 = A[M][128] bf16 @ Wt^T + b2.
// Block: 256 thr = 4 waves, tile 64 rows x 128 cols (round-6 structure).
// ===========================================================================
__global__ __launch_bounds__(256) void mfma_gemm2_kernel(
    const unsigned short* __restrict__ A, const unsigned short* __restrict__ Wt,
    const float* __restrict__ bias, float* __restrict__ Y, int M) {
  __shared__ unsigned short As[64 * 136];
  int node0 = blockIdx.x * 64;
  int t = threadIdx.x;
  #pragma unroll
  for (int i = 0; i < 4; ++i) {
    int c = t + i * 256;           // 1024 x 16B bf16 chunks
    int row = c >> 4, c8 = (c & 15) * 8;
    uint4 v = make_uint4(0u, 0u, 0u, 0u);
    if (node0 + row < M) v = *(const uint4*)&A[(long)(node0 + row) * 128 + c8];
    *(uint4*)&As[row * 136 + c8] = v;
  }
  __syncthreads();
  int w = t >> 6, lane = t & 63;
  int m = lane & 15, q = lane >> 4;
  int col0 = w * 32;
  floatx4 acc[4][2];
  #pragma unroll
  for (int rt = 0; rt < 4; ++rt)
    #pragma unroll
    for (int ct = 0; ct < 2; ++ct) acc[rt][ct] = (floatx4){0.f, 0.f, 0.f, 0.f};

  #pragma unroll
  for (int ks = 0; ks < 4; ++ks) {
    bf16x8 b0 = *(const bf16x8*)&Wt[(col0 + m) * 128 + ks * 32 + q * 8];
    bf16x8 b1 = *(const bf16x8*)&Wt[(col0 + 16 + m) * 128 + ks * 32 + q * 8];
    #pragma unroll
    for (int rt = 0; rt < 4; ++rt) {
      bf16x8 a = *(const bf16x8*)&As[(rt * 16 + m) * 136 + ks * 32 + q * 8];
      acc[rt][0] = __builtin_amdgcn_mfma_f32_16x16x32_bf16(a, b0, acc[rt][0], 0, 0, 0);
      acc[rt][1] = __builtin_amdgcn_mfma_f32_16x16x32_bf16(a, b1, acc[rt][1], 0, 0, 0);
    }
  }
  #pragma unroll
  for (int ct = 0; ct < 2; ++ct) {
    int col = col0 + ct * 16 + m;
    float bv = bias[col];
    #pragma unroll
    for (int rt = 0; rt < 4; ++rt) {
      #pragma unroll
      for (int i = 0; i < 4; ++i) {
        int row = node0 + rt * 16 + q * 4 + i;
        if (row >= M) continue;
        Y[(long)row * 128 + col] = acc[rt][ct][i] + bv;
      }
    }
  }
}

#define ACC_P(A, v)                                                            \
  do {                                                                         \
    A[0] += (floatx2){__uint_as_float((v).x << 16),                            \
                      __uint_as_float((v).x & 0xffff0000u)};                   \
    A[1] += (floatx2){__uint_as_float((v).y << 16),                            \
                      __uint_as_float((v).y & 0xffff0000u)};                   \
    A[2] += (floatx2){__uint_as_float((v).z << 16),                            \
                      __uint_as_float((v).z & 0xffff0000u)};                   \
    A[3] += (floatx2){__uint_as_float((v).w << 16),                            \
                      __uint_as_float((v).w & 0xffff0000u)};                   \
  } while (0)

// ===========================================================================
// Gather-mean over bf16 rows (64 feats = 128 B).  8 nodes/wave, 8 lanes/node
// (sub=lane>>3), each lane owns 16B of its node's output -> no cross-lane
// reduction.  Wave's contiguous slab index range staged in LDS once; 8-deep
// gather pipeline folding into 4 accumulator chains (bit-identical to the
// 4-wide order).  At the composite memory wall -- kept as-is.
// FUSE_RELU: out = relu(mean + zadd_row) (layer-1 epilogue), bf16 out.
// ===========================================================================
template <bool FUSE_RELU>
__global__ __launch_bounds__(256) void aggregate_bf16_kernel(
    const unsigned short* __restrict__ gsrc, const unsigned short* __restrict__ zadd,
    unsigned short* __restrict__ outp, const int2* __restrict__ offsets2,
    const int* __restrict__ src_sorted, int n_nodes) {
  __shared__ int stage[4 * AGG_CAP];
  int wv = threadIdx.x >> 6;             // wave in block 0..3
  int lane = threadIdx.x & 63;
  int wid = (blockIdx.x << 2) | wv;
  int node8 = wid << 3;
  int sub = lane >> 3;    // node slot 0..7
  int sl  = lane & 7;     // 16B chunk within row
  int node = node8 + sub;
  bool wvalid = (node8 < n_nodes);
  bool nvalid = wvalid && (node < n_nodes);

  int wbeg = 0, wend = 0, beg = 0, end = 0;
  if (wvalid) {
    wbeg = offsets2[node8].x;
    wend = offsets2[min(node8 + 8, n_nodes) - 1].y;
  }
  if (nvalid) {
    int2 o = offsets2[node];
    beg = o.x; end = o.y;
  }
  int deg = end - beg;
  int cnt = wend - wbeg;                 // wave-uniform
  int* my = &stage[wv * AGG_CAP];
  bool staged = wvalid && (cnt <= AGG_CAP);
  if (staged) {
    for (int i = lane; i < cnt; i += 64) my[i] = src_sorted[wbeg + i];
  }
  __syncthreads();   // executed by ALL threads (no early returns above)

  const unsigned short* base = gsrc + sl * 8;
  floatx2 A0[4], A1[4], A2[4], A3[4];
  #pragma unroll
  for (int i = 0; i < 4; ++i) {
    A0[i] = (floatx2){0.f, 0.f}; A1[i] = (floatx2){0.f, 0.f};
    A2[i] = (floatx2){0.f, 0.f}; A3[i] = (floatx2){0.f, 0.f};
  }

  if (staged) {
    int lb = beg - wbeg;                 // local base in staged indices
    int e = 0;
    for (; e + 8 <= deg; e += 8) {       // 8 loads in flight
      int s0 = my[lb + e];
      int s1 = my[lb + e + 1];
      int s2 = my[lb + e + 2];
      int s3 = my[lb + e + 3];
      int s4 = my[lb + e + 4];
      int s5 = my[lb + e + 5];
      int s6 = my[lb + e + 6];
      int s7 = my[lb + e + 7];
      uint4 v0 = *(const uint4*)(base + (long)s0 * 128);
      uint4 v1 = *(const uint4*)(base + (long)s1 * 128);
      uint4 v2 = *(const uint4*)(base + (long)s2 * 128);
      uint4 v3 = *(const uint4*)(base + (long)s3 * 128);
      uint4 v4 = *(const uint4*)(base + (long)s4 * 128);
      uint4 v5 = *(const uint4*)(base + (long)s5 * 128);
      uint4 v6 = *(const uint4*)(base + (long)s6 * 128);
      uint4 v7 = *(const uint4*)(base + (long)s7 * 128);
      ACC_P(A0, v0); ACC_P(A1, v1); ACC_P(A2, v2); ACC_P(A3, v3);
      ACC_P(A0, v4); ACC_P(A1, v5); ACC_P(A2, v6); ACC_P(A3, v7);
    }
    if (e + 4 <= deg) {
      int s0 = my[lb + e];
      int s1 = my[lb + e + 1];
      int s2 = my[lb + e + 2];
      int s3 = my[lb + e + 3];
      uint4 v0 = *(const uint4*)(base + (long)s0 * 128);
      uint4 v1 = *(const uint4*)(base + (long)s1 * 128);
      uint4 v2 = *(const uint4*)(base + (long)s2 * 128);
      uint4 v3 = *(const uint4*)(base + (long)s3 * 128);
      ACC_P(A0, v0); ACC_P(A1, v1); ACC_P(A2, v2); ACC_P(A3, v3);
      e += 4;
    }
    for (; e < deg; ++e) {
      int s0 = my[lb + e];
      uint4 v0 = *(const uint4*)(base + (long)s0 * 128);
      ACC_P(A0, v0);
    }
  } else if (nvalid) {  // overflow fallback (statistically never)
    for (int e = beg; e < end; ++e) {
      int s0 = src_sorted[e];
      uint4 v0 = *(const uint4*)(base + (long)s0 * 128);
      ACC_P(A0, v0);
    }
  }
  #pragma unroll
  for (int i = 0; i < 4; ++i) A0[i] = (A0[i] + A1[i]) + (A2[i] + A3[i]);

  if (nvalid) {
    float inv = 1.f / fmaxf((float)deg, 1.f);
    float r[8];
    r[0] = A0[0].x * inv; r[1] = A0[0].y * inv;
    r[2] = A0[1].x * inv; r[3] = A0[1].y * inv;
    r[4] = A0[2].x * inv; r[5] = A0[2].y * inv;
    r[6] = A0[3].x * inv; r[7] = A0[3].y * inv;
    if (FUSE_RELU) {
      uint4 z = *(const uint4*)&zadd[(long)node * 128 + sl * 8];
      r[0] = fmaxf(r[0] + __uint_as_float(z.x << 16), 0.f);
      r[1] = fmaxf(r[1] + __uint_as_float(z.x & 0xffff0000u), 0.f);
      r[2] = fmaxf(r[2] + __uint_as_float(z.y << 16), 0.f);
      r[3] = fmaxf(r[3] + __uint_as_float(z.y & 0xffff0000u), 0.f);
      r[4] = fmaxf(r[4] + __uint_as_float(z.z << 16), 0.f);
      r[5] = fmaxf(r[5] + __uint_as_float(z.z & 0xffff0000u), 0.f);
      r[6] = fmaxf(r[6] + __uint_as_float(z.w << 16), 0.f);
      r[7] = fmaxf(r[7] + __uint_as_float(z.w & 0xffff0000u), 0.f);
    }
    uint4 ov;
    ov.x = (unsigned)f2bf(r[0]) | ((unsigned)f2bf(r[1]) << 16);
    ov.y = (unsigned)f2bf(r[2]) | ((unsigned)f2bf(r[3]) << 16);
    ov.z = (unsigned)f2bf(r[4]) | ((unsigned)f2bf(r[5]) << 16);
    ov.w = (unsigned)f2bf(r[6]) | ((unsigned)f2bf(r[7]) << 16);
    *(uint4*)&outp[(long)node * 128 + sl * 8] = ov;
  }
}
#undef ACC_P

extern "C" void kernel_launch(void* const* d_in, const int* in_sizes, int n_in,
                              void* d_out, int out_size, void* d_ws, size_t ws_size,
                              hipStream_t stream) {
  const float* x    = (const float*)d_in[0];
  const int*   ei   = (const int*)d_in[1];
  const float* w1_l = (const float*)d_in[2];
  const float* b1   = (const float*)d_in[3];
  const float* w1_r = (const float*)d_in[4];
  const float* w2_l = (const float*)d_in[5];
  const float* b2   = (const float*)d_in[6];
  const float* w2_r = (const float*)d_in[7];
  float* out = (float*)d_out;

  const int E = in_sizes[1] / 2;
  const int* src = ei;
  const int* dst = ei + E;

  // ---- workspace layout (~78 MB; pairs NOT aliased -- written while gemm1
  //      writes ZB1 in the same launch) ----
  unsigned short* ZB1 = (unsigned short*)d_ws;          // [N][128] bf16: y1|z1
  unsigned short* ZB2 = ZB1 + (long)N_NODES * 128;      // [N][128] bf16: mean2|h
  unsigned short* Wt1 = ZB2 + (long)N_NODES * 128;      // 128x128 bf16
  unsigned short* Wt2 = Wt1 + 16384;                    // 128x128 bf16
  int* bucket_cursor = (int*)(Wt2 + 16384);             // 782 (+pad, even)
  int2* offsets2     = (int2*)(bucket_cursor + NBUCK + 2);  // N int2
  int* src_sorted    = (int*)(offsets2 + N_NODES);      // NBUCK*SLAB slab-strided
  unsigned* pairs    = (unsigned*)(src_sorted + (long)NBUCK * SLAB);  // NBUCK*SLAB

  int nb_part = (E + P1TILE - 1) / P1TILE;              // 391
  int gemm1_blocks = (N_NODES + 127) / 128;             // 782

  // ---- L1: init (cursors + weights) ----
  init_kernel<<<64, 256, 0, stream>>>(bucket_cursor, w1_l, w1_r, w2_l, w2_r,
                                      Wt1, Wt2);
  // ---- L2: partition || gemm1 (independent; role-split single launch) ----
  part_gemm1_kernel<<<nb_part + gemm1_blocks, 512, 0, stream>>>(
      src, dst, bucket_cursor, pairs, E, nb_part, x, Wt1, b1, ZB1, N_NODES);
  // ---- L3: per-bucket CSR ----
  bucket_csr_kernel<<<NBUCK, 512, 0, stream>>>(pairs, bucket_cursor,
                                               offsets2, src_sorted, N_NODES);

  int agg_blocks = (N_NODES + 31) / 32;   // 8 nodes/wave, 4 waves/block
  // ---- L4: h = relu(mean(y1) + z1) -> ZB2[:,64:128] ----
  aggregate_bf16_kernel<true><<<agg_blocks, 256, 0, stream>>>(
      ZB1, ZB1 + 64, ZB2 + 64, offsets2, src_sorted, N_NODES);
  // ---- L5: mean2 -> ZB2[:,0:64] ----
  aggregate_bf16_kernel<false><<<agg_blocks, 256, 0, stream>>>(
      ZB2 + 64, nullptr, ZB2, offsets2, src_sorted, N_NODES);
  // ---- L6: out = [mean2|h] @ Wt2^T + b2 ----
  mfma_gemm2_kernel<<<(N_NODES + 63) / 64, 256, 0, stream>>>(
      ZB2, Wt2, b2, out, N_NODES);
}

// Round 10
// 230.740 us; speedup vs baseline: 1.3541x; 1.0301x over previous
//
#include <hip/hip_runtime.h>

#define N_NODES 100000
#define NBUCK   782      // ceil(100000/128) buckets of 128 nodes
#define NBUCK2  784      // padded stride for cursor copies
#define NGRP    8        // cursor privatization degree (blockIdx & 7)
#define P1TILE  4096     // edges per partition block
#define SLAB    4096     // bucket slab capacity = NGRP * SUBSLAB
#define SUBSLAB 512      // per-group sub-slab (avg 262, +15 sigma)
#define AGG_CAP 512      // staged edge indices per agg wave (mean 128)

typedef __bf16 bf16x8 __attribute__((ext_vector_type(8)));
typedef float floatx4 __attribute__((ext_vector_type(4)));
typedef float floatx2 __attribute__((ext_vector_type(2)));

static __device__ __forceinline__ unsigned short f2bf(float f) {
  unsigned u = __float_as_uint(f);
  u += 0x7fff + ((u >> 16) & 1);   // round-to-nearest-even
  return (unsigned short)(u >> 16);
}

// ===========================================================================
// Step 0: init -- zero the 8 privatized cursor copies + weight transpose.
//   Wt1[n][k] = n<64 ? w1_l[k][n] : w1_r[k][n-64]
//   Wt2[n][k] = k<64 ? w2_l[k][n] : w2_r[k-64][n]
// ===========================================================================
__global__ __launch_bounds__(256) void init_kernel(
    int* __restrict__ bucket_cursor,
    const float* __restrict__ w1_l, const float* __restrict__ w1_r,
    const float* __restrict__ w2_l, const float* __restrict__ w2_r,
    unsigned short* __restrict__ Wt1, unsigned short* __restrict__ Wt2) {
  int gid = blockIdx.x * 256 + threadIdx.x;   // 64*256 = 16384 threads
  if (gid < NGRP * NBUCK2 + 2) bucket_cursor[gid] = 0;
  int n = gid >> 7, k = gid & 127;            // covers all 128x128
  float v1 = (n < 64) ? w1_l[k * 64 + n] : w1_r[k * 64 + (n - 64)];
  Wt1[n * 128 + k] = f2bf(v1);
  float v2 = (k < 64) ? w2_l[k * 128 + n] : w2_r[(k - 64) * 128 + n];
  Wt2[n * 128 + k] = f2bf(v2);
}

// ===========================================================================
// Step 1 (combined): blocks < nb_part partition (src,dst) into per-bucket
// sub-slabs; remaining 782 blocks run layer-1 GEMM on a 128-row tile
// (bit-identical ZB1 vs the 256-thr version).
//
// Round-10: slab reservation uses PRIVATIZED cursors -- group g =
// blockIdx&7 owns cursor copy g and sub-slab [g*512, g*512+512) of each
// bucket.  Round-9 PMC (VALUBusy 10%, MfmaUtil 2%, 40us) exposed the
// device-atomic RMW chains on 782 shared addresses (391 serialized
// RMWs/address ~= 39us) as the pole; 8-way split cuts chains to ~49.
// ===========================================================================
__global__ __launch_bounds__(512) void part_gemm1_kernel(
    const int* __restrict__ src, const int* __restrict__ dst,
    int* __restrict__ bucket_cursor, unsigned* __restrict__ pairs,
    int n_edges, int nb_part,
    const float* __restrict__ x, const unsigned short* __restrict__ Wt1,
    const float* __restrict__ b1, unsigned short* __restrict__ ZB1, int M) {
  __shared__ __align__(16) char smem[44224];
  int t = threadIdx.x;

  if ((int)blockIdx.x >= nb_part) {
    // ---------------- gemm1 role: 128-row tile ----------------
    unsigned short* As = (unsigned short*)smem;    // [128][136] bf16
    int node0 = ((int)blockIdx.x - nb_part) * 128;
    #pragma unroll
    for (int i = 0; i < 8; ++i) {
      int c = t + i * 512;           // 4096 x 16B fp32 chunks (4 floats)
      int row = c >> 5, c4 = (c & 31) * 4;
      float4 v = make_float4(0.f, 0.f, 0.f, 0.f);
      if (node0 + row < M) v = *(const float4*)&x[(long)(node0 + row) * 128 + c4];
      ushort4 o;
      o.x = f2bf(v.x); o.y = f2bf(v.y); o.z = f2bf(v.z); o.w = f2bf(v.w);
      *(ushort4*)&As[row * 136 + c4] = o;
    }
    __syncthreads();
    int w8 = t >> 6, lane = t & 63;
    int m = lane & 15, q = lane >> 4;
    int w = w8 & 3, half = w8 >> 2;
    int col0 = w * 32, rowbase = half * 64;
    floatx4 acc[4][2];
    #pragma unroll
    for (int rt = 0; rt < 4; ++rt)
      #pragma unroll
      for (int ct = 0; ct < 2; ++ct) acc[rt][ct] = (floatx4){0.f, 0.f, 0.f, 0.f};
    #pragma unroll
    for (int ks = 0; ks < 4; ++ks) {
      bf16x8 b0 = *(const bf16x8*)&Wt1[(col0 + m) * 128 + ks * 32 + q * 8];
      bf16x8 bb = *(const bf16x8*)&Wt1[(col0 + 16 + m) * 128 + ks * 32 + q * 8];
      #pragma unroll
      for (int rt = 0; rt < 4; ++rt) {
        bf16x8 a = *(const bf16x8*)&As[(rowbase + rt * 16 + m) * 136 + ks * 32 + q * 8];
        acc[rt][0] = __builtin_amdgcn_mfma_f32_16x16x32_bf16(a, b0, acc[rt][0], 0, 0, 0);
        acc[rt][1] = __builtin_amdgcn_mfma_f32_16x16x32_bf16(a, bb, acc[rt][1], 0, 0, 0);
      }
    }
    // C/D layout: col = lane&15, row = (lane>>4)*4 + reg
    #pragma unroll
    for (int ct = 0; ct < 2; ++ct) {
      int col = col0 + ct * 16 + m;
      float bv = (col >= 64) ? b1[col - 64] : 0.f;
      #pragma unroll
      for (int rt = 0; rt < 4; ++rt) {
        #pragma unroll
        for (int i = 0; i < 4; ++i) {
          int row = node0 + rowbase + rt * 16 + q * 4 + i;
          if (row >= M) continue;
          ZB1[(long)row * 128 + col] = f2bf(acc[rt][ct][i] + bv);
        }
      }
    }
    return;
  }

  // ---------------- partition role ----------------
  int2* sorted = (int2*)smem;                         // 4096 * 8B
  int* hist  = (int*)(smem + 32768);                  // 782
  int* scan_ = hist + NBUCK;                          // 782
  int* gbase = scan_ + NBUCK;                         // 782
  int* tmp   = gbase + NBUCK;                         // 512
  int g = (int)blockIdx.x & (NGRP - 1);               // cursor group
  long e0 = (long)blockIdx.x * P1TILE;
  int n = (int)min((long)P1TILE, (long)n_edges - e0);

  for (int b = t; b < NBUCK; b += 512) hist[b] = 0;
  __syncthreads();
  for (int i = t; i < n; i += 512) atomicAdd(&hist[dst[e0 + i] >> 7], 1);
  __syncthreads();

  int loc[2];
  int s = 0;
  #pragma unroll
  for (int j = 0; j < 2; ++j) {
    int idx = 2 * t + j;
    loc[j] = s;
    s += (idx < NBUCK) ? hist[idx] : 0;
  }
  tmp[t] = s;
  __syncthreads();
  for (int off = 1; off < 512; off <<= 1) {
    int u = (t >= off) ? tmp[t - off] : 0;
    __syncthreads();
    tmp[t] += u;
    __syncthreads();
  }
  int excl = tmp[t] - s;
  #pragma unroll
  for (int j = 0; j < 2; ++j) {
    int idx = 2 * t + j;
    if (idx < NBUCK) scan_[idx] = excl + loc[j];
  }
  __syncthreads();

  for (int b = t; b < NBUCK; b += 512) {
    int c = hist[b];
    gbase[b] = c ? atomicAdd(&bucket_cursor[g * NBUCK2 + b], c) : 0;
    hist[b] = scan_[b];
  }
  __syncthreads();

  for (int i = t; i < n; i += 512) {
    int sv = src[e0 + i];
    int dv = dst[e0 + i];
    int r = atomicAdd(&hist[dv >> 7], 1);   // LDS atomic
    sorted[r] = make_int2(sv, dv);
  }
  __syncthreads();

  for (int i = t; i < n; i += 512) {
    int2 p = sorted[i];
    int b = p.y >> 7;
    int pos = gbase[b] + (i - scan_[b]);
    if (pos < SUBSLAB) {   // +15 sigma: statistically never exceeded
      unsigned pk = (unsigned)p.x | ((unsigned)(p.y & 127) << 17);
      pairs[(long)b * SLAB + (g << 9) + pos] = pk;
    }
  }
}

// ===========================================================================
// Step 2: per bucket, merge the 8 sub-slabs (tiny 8-entry prefix), build
// node-level CSR {beg,end} (absolute positions in src_sorted's compact
// per-bucket region) and node-sorted src stream-out.  512 threads.
// ===========================================================================
__global__ __launch_bounds__(512) void bucket_csr_kernel(
    const unsigned* __restrict__ pairs, const int* __restrict__ bucket_cnt,
    int2* __restrict__ offsets2, int* __restrict__ src_sorted, int n_nodes) {
  __shared__ unsigned sp[SLAB];
  __shared__ int lout[SLAB];
  __shared__ int ndeg[128];
  __shared__ int nsc[128];
  __shared__ int cnt8[NGRP];
  __shared__ int pref8[NGRP + 1];
  int b = blockIdx.x;
  int node0 = b << 7;
  int t = threadIdx.x;
  long sbeg = (long)b * SLAB;          // slab base (read and write)
  if (t < NGRP) cnt8[t] = min(bucket_cnt[t * NBUCK2 + b], SUBSLAB);
  if (t < 128) ndeg[t] = 0;
  __syncthreads();
  if (t == 0) {
    int s = 0;
    #pragma unroll
    for (int gi = 0; gi < NGRP; ++gi) { pref8[gi] = s; s += cnt8[gi]; }
    pref8[NGRP] = s;
  }
  __syncthreads();
  int m = pref8[NGRP];

  // stage the 8 sub-segments compactly + histogram
  for (int gi = 0; gi < NGRP; ++gi) {
    int c = cnt8[gi], p0 = pref8[gi];
    for (int i = t; i < c; i += 512) {
      unsigned p = pairs[sbeg + (gi << 9) + i];
      sp[p0 + i] = p;
      atomicAdd(&ndeg[p >> 17], 1);   // LDS atomic
    }
  }
  __syncthreads();

  // exclusive scan of 128 node degrees
  if (t < 128) nsc[t] = ndeg[t];
  __syncthreads();
  for (int off = 1; off < 128; off <<= 1) {
    int u = 0;
    if (t < 128 && t >= off) u = nsc[t - off];
    __syncthreads();
    if (t < 128) nsc[t] += u;
    __syncthreads();
  }
  if (t < 128) {
    int excl = nsc[t] - ndeg[t];
    int node = node0 + t;
    if (node < n_nodes)
      offsets2[node] = make_int2((int)sbeg + excl, (int)sbeg + nsc[t]);
    ndeg[t] = excl;   // repurpose as placement cursor
  }
  __syncthreads();

  // place src values grouped by node, stream out coalesced
  for (int i = t; i < m; i += 512) {
    unsigned p = sp[i];
    int r = atomicAdd(&ndeg[p >> 17], 1);  // LDS atomic
    lout[r] = (int)(p & 0x1FFFFu);
  }
  __syncthreads();
  for (int i = t; i < m; i += 512) src_sorted[sbeg + i] = lout[i];
}

// ===========================================================================
// MFMA GEMM (layer 2): Y[M][128] fp32 = A[M][128] bf16 @ Wt^T + b2.
// Block: 256 thr = 4 waves, tile 64 rows x 128 cols.
// ===========================================================================
__global__ __launch_bounds__(256) void mfma_gemm2_kernel(
    const unsigned short* __restrict__ A, const unsigned short* __restrict__ Wt,
    const float* __restrict__ bias, float* __restrict__ Y, int M) {
  __shared__ unsigned short As[64 * 136];
  int node0 = blockIdx.x * 64;
  int t = threadIdx.x;
  #pragma unroll
  for (int i = 0; i < 4; ++i) {
    int c = t + i * 256;           // 1024 x 16B bf16 chunks
    int row = c >> 4, c8 = (c & 15) * 8;
    uint4 v = make_uint4(0u, 0u, 0u, 0u);
    if (node0 + row < M) v = *(const uint4*)&A[(long)(node0 + row) * 128 + c8];
    *(uint4*)&As[row * 136 + c8] = v;
  }
  __syncthreads();
  int w = t >> 6, lane = t & 63;
  int m = lane & 15, q = lane >> 4;
  int col0 = w * 32;
  floatx4 acc[4][2];
  #pragma unroll
  for (int rt = 0; rt < 4; ++rt)
    #pragma unroll
    for (int ct = 0; ct < 2; ++ct) acc[rt][ct] = (floatx4){0.f, 0.f, 0.f, 0.f};

  #pragma unroll
  for (int ks = 0; ks < 4; ++ks) {
    bf16x8 b0 = *(const bf16x8*)&Wt[(col0 + m) * 128 + ks * 32 + q * 8];
    bf16x8 b1 = *(const bf16x8*)&Wt[(col0 + 16 + m) * 128 + ks * 32 + q * 8];
    #pragma unroll
    for (int rt = 0; rt < 4; ++rt) {
      bf16x8 a = *(const bf16x8*)&As[(rt * 16 + m) * 136 + ks * 32 + q * 8];
      acc[rt][0] = __builtin_amdgcn_mfma_f32_16x16x32_bf16(a, b0, acc[rt][0], 0, 0, 0);
      acc[rt][1] = __builtin_amdgcn_mfma_f32_16x16x32_bf16(a, b1, acc[rt][1], 0, 0, 0);
    }
  }
  #pragma unroll
  for (int ct = 0; ct < 2; ++ct) {
    int col = col0 + ct * 16 + m;
    float bv = bias[col];
    #pragma unroll
    for (int rt = 0; rt < 4; ++rt) {
      #pragma unroll
      for (int i = 0; i < 4; ++i) {
        int row = node0 + rt * 16 + q * 4 + i;
        if (row >= M) continue;
        Y[(long)row * 128 + col] = acc[rt][ct][i] + bv;
      }
    }
  }
}

#define ACC_P(A, v)                                                            \
  do {                                                                         \
    A[0] += (floatx2){__uint_as_float((v).x << 16),                            \
                      __uint_as_float((v).x & 0xffff0000u)};                   \
    A[1] += (floatx2){__uint_as_float((v).y << 16),                            \
                      __uint_as_float((v).y & 0xffff0000u)};                   \
    A[2] += (floatx2){__uint_as_float((v).z << 16),                            \
                      __uint_as_float((v).z & 0xffff0000u)};                   \
    A[3] += (floatx2){__uint_as_float((v).w << 16),                            \
                      __uint_as_float((v).w & 0xffff0000u)};                   \
  } while (0)

// ===========================================================================
// Gather-mean over bf16 rows (64 feats = 128 B).  8 nodes/wave, 8 lanes/node
// (sub=lane>>3), each lane owns 16B of its node's output -> no cross-lane
// reduction.  Wave's contiguous slab index range staged in LDS once; 8-deep
// gather pipeline folding into 4 accumulator chains.  At the composite
// memory wall -- kept as-is.
// FUSE_RELU: out = relu(mean + zadd_row) (layer-1 epilogue), bf16 out.
// ===========================================================================
template <bool FUSE_RELU>
__global__ __launch_bounds__(256) void aggregate_bf16_kernel(
    const unsigned short* __restrict__ gsrc, const unsigned short* __restrict__ zadd,
    unsigned short* __restrict__ outp, const int2* __restrict__ offsets2,
    const int* __restrict__ src_sorted, int n_nodes) {
  __shared__ int stage[4 * AGG_CAP];
  int wv = threadIdx.x >> 6;             // wave in block 0..3
  int lane = threadIdx.x & 63;
  int wid = (blockIdx.x << 2) | wv;
  int node8 = wid << 3;
  int sub = lane >> 3;    // node slot 0..7
  int sl  = lane & 7;     // 16B chunk within row
  int node = node8 + sub;
  bool wvalid = (node8 < n_nodes);
  bool nvalid = wvalid && (node < n_nodes);

  int wbeg = 0, wend = 0, beg = 0, end = 0;
  if (wvalid) {
    wbeg = offsets2[node8].x;
    wend = offsets2[min(node8 + 8, n_nodes) - 1].y;
  }
  if (nvalid) {
    int2 o = offsets2[node];
    beg = o.x; end = o.y;
  }
  int deg = end - beg;
  int cnt = wend - wbeg;                 // wave-uniform
  int* my = &stage[wv * AGG_CAP];
  bool staged = wvalid && (cnt <= AGG_CAP);
  if (staged) {
    for (int i = lane; i < cnt; i += 64) my[i] = src_sorted[wbeg + i];
  }
  __syncthreads();   // executed by ALL threads (no early returns above)

  const unsigned short* base = gsrc + sl * 8;
  floatx2 A0[4], A1[4], A2[4], A3[4];
  #pragma unroll
  for (int i = 0; i < 4; ++i) {
    A0[i] = (floatx2){0.f, 0.f}; A1[i] = (floatx2){0.f, 0.f};
    A2[i] = (floatx2){0.f, 0.f}; A3[i] = (floatx2){0.f, 0.f};
  }

  if (staged) {
    int lb = beg - wbeg;                 // local base in staged indices
    int e = 0;
    for (; e + 8 <= deg; e += 8) {       // 8 loads in flight
      int s0 = my[lb + e];
      int s1 = my[lb + e + 1];
      int s2 = my[lb + e + 2];
      int s3 = my[lb + e + 3];
      int s4 = my[lb + e + 4];
      int s5 = my[lb + e + 5];
      int s6 = my[lb + e + 6];
      int s7 = my[lb + e + 7];
      uint4 v0 = *(const uint4*)(base + (long)s0 * 128);
      uint4 v1 = *(const uint4*)(base + (long)s1 * 128);
      uint4 v2 = *(const uint4*)(base + (long)s2 * 128);
      uint4 v3 = *(const uint4*)(base + (long)s3 * 128);
      uint4 v4 = *(const uint4*)(base + (long)s4 * 128);
      uint4 v5 = *(const uint4*)(base + (long)s5 * 128);
      uint4 v6 = *(const uint4*)(base + (long)s6 * 128);
      uint4 v7 = *(const uint4*)(base + (long)s7 * 128);
      ACC_P(A0, v0); ACC_P(A1, v1); ACC_P(A2, v2); ACC_P(A3, v3);
      ACC_P(A0, v4); ACC_P(A1, v5); ACC_P(A2, v6); ACC_P(A3, v7);
    }
    if (e + 4 <= deg) {
      int s0 = my[lb + e];
      int s1 = my[lb + e + 1];
      int s2 = my[lb + e + 2];
      int s3 = my[lb + e + 3];
      uint4 v0 = *(const uint4*)(base + (long)s0 * 128);
      uint4 v1 = *(const uint4*)(base + (long)s1 * 128);
      uint4 v2 = *(const uint4*)(base + (long)s2 * 128);
      uint4 v3 = *(const uint4*)(base + (long)s3 * 128);
      ACC_P(A0, v0); ACC_P(A1, v1); ACC_P(A2, v2); ACC_P(A3, v3);
      e += 4;
    }
    for (; e < deg; ++e) {
      int s0 = my[lb + e];
      uint4 v0 = *(const uint4*)(base + (long)s0 * 128);
      ACC_P(A0, v0);
    }
  } else if (nvalid) {  // overflow fallback (statistically never)
    for (int e = beg; e < end; ++e) {
      int s0 = src_sorted[e];
      uint4 v0 = *(const uint4*)(base + (long)s0 * 128);
      ACC_P(A0, v0);
    }
  }
  #pragma unroll
  for (int i = 0; i < 4; ++i) A0[i] = (A0[i] + A1[i]) + (A2[i] + A3[i]);

  if (nvalid) {
    float inv = 1.f / fmaxf((float)deg, 1.f);
    float r[8];
    r[0] = A0[0].x * inv; r[1] = A0[0].y * inv;
    r[2] = A0[1].x * inv; r[3] = A0[1].y * inv;
    r[4] = A0[2].x * inv; r[5] = A0[2].y * inv;
    r[6] = A0[3].x * inv; r[7] = A0[3].y * inv;
    if (FUSE_RELU) {
      uint4 z = *(const uint4*)&zadd[(long)node * 128 + sl * 8];
      r[0] = fmaxf(r[0] + __uint_as_float(z.x << 16), 0.f);
      r[1] = fmaxf(r[1] + __uint_as_float(z.x & 0xffff0000u), 0.f);
      r[2] = fmaxf(r[2] + __uint_as_float(z.y << 16), 0.f);
      r[3] = fmaxf(r[3] + __uint_as_float(z.y & 0xffff0000u), 0.f);
      r[4] = fmaxf(r[4] + __uint_as_float(z.z << 16), 0.f);
      r[5] = fmaxf(r[5] + __uint_as_float(z.z & 0xffff0000u), 0.f);
      r[6] = fmaxf(r[6] + __uint_as_float(z.w << 16), 0.f);
      r[7] = fmaxf(r[7] + __uint_as_float(z.w & 0xffff0000u), 0.f);
    }
    uint4 ov;
    ov.x = (unsigned)f2bf(r[0]) | ((unsigned)f2bf(r[1]) << 16);
    ov.y = (unsigned)f2bf(r[2]) | ((unsigned)f2bf(r[3]) << 16);
    ov.z = (unsigned)f2bf(r[4]) | ((unsigned)f2bf(r[5]) << 16);
    ov.w = (unsigned)f2bf(r[6]) | ((unsigned)f2bf(r[7]) << 16);
    *(uint4*)&outp[(long)node * 128 + sl * 8] = ov;
  }
}
#undef ACC_P

extern "C" void kernel_launch(void* const* d_in, const int* in_sizes, int n_in,
                              void* d_out, int out_size, void* d_ws, size_t ws_size,
                              hipStream_t stream) {
  const float* x    = (const float*)d_in[0];
  const int*   ei   = (const int*)d_in[1];
  const float* w1_l = (const float*)d_in[2];
  const float* b1   = (const float*)d_in[3];
  const float* w1_r = (const float*)d_in[4];
  const float* w2_l = (const float*)d_in[5];
  const float* b2   = (const float*)d_in[6];
  const float* w2_r = (const float*)d_in[7];
  float* out = (float*)d_out;

  const int E = in_sizes[1] / 2;
  const int* src = ei;
  const int* dst = ei + E;

  // ---- workspace layout (~78 MB) ----
  unsigned short* ZB1 = (unsigned short*)d_ws;          // [N][128] bf16: y1|z1
  unsigned short* ZB2 = ZB1 + (long)N_NODES * 128;      // [N][128] bf16: mean2|h
  unsigned short* Wt1 = ZB2 + (long)N_NODES * 128;      // 128x128 bf16
  unsigned short* Wt2 = Wt1 + 16384;                    // 128x128 bf16
  int* bucket_cursor = (int*)(Wt2 + 16384);             // 8 x 784 (+pad)
  int2* offsets2     = (int2*)(bucket_cursor + NGRP * NBUCK2 + 2);  // N int2
  int* src_sorted    = (int*)(offsets2 + N_NODES);      // NBUCK*SLAB slab-strided
  unsigned* pairs    = (unsigned*)(src_sorted + (long)NBUCK * SLAB);  // NBUCK*SLAB

  int nb_part = (E + P1TILE - 1) / P1TILE;              // 391
  int gemm1_blocks = (N_NODES + 127) / 128;             // 782

  // ---- L1: init (privatized cursors + weights) ----
  init_kernel<<<64, 256, 0, stream>>>(bucket_cursor, w1_l, w1_r, w2_l, w2_r,
                                      Wt1, Wt2);
  // ---- L2: partition || gemm1 (independent; role-split single launch) ----
  part_gemm1_kernel<<<nb_part + gemm1_blocks, 512, 0, stream>>>(
      src, dst, bucket_cursor, pairs, E, nb_part, x, Wt1, b1, ZB1, N_NODES);
  // ---- L3: per-bucket CSR (merges the 8 sub-slabs) ----
  bucket_csr_kernel<<<NBUCK, 512, 0, stream>>>(pairs, bucket_cursor,
                                               offsets2, src_sorted, N_NODES);

  int agg_blocks = (N_NODES + 31) / 32;   // 8 nodes/wave, 4 waves/block
  // ---- L4: h = relu(mean(y1) + z1) -> ZB2[:,64:128] ----
  aggregate_bf16_kernel<true><<<agg_blocks, 256, 0, stream>>>(
      ZB1, ZB1 + 64, ZB2 + 64, offsets2, src_sorted, N_NODES);
  // ---- L5: mean2 -> ZB2[:,0:64] ----
  aggregate_bf16_kernel<false><<<agg_blocks, 256, 0, stream>>>(
      ZB2 + 64, nullptr, ZB2, offsets2, src_sorted, N_NODES);
  // ---- L6: out = [mean2|h] @ Wt2^T + b2 ----
  mfma_gemm2_kernel<<<(N_NODES + 63) / 64, 256, 0, stream>>>(
      ZB2, Wt2, b2, out, N_NODES);
}